// Round 1
// baseline (3238.151 us; speedup 1.0000x reference)
//
#include <hip/hip_runtime.h>
#include <hip/hip_bf16.h>

// Problem constants
#define BB   16
#define CIN  512
#define COUT 512
#define KS   3
#define KK   9
#define HH   32
#define WW   32
#define HW   1024
#define SDIM 512
#define RR   512
#define MM   4608               // KK*CIN, SVD "m" dim; m = kk*512 + ci
#define SCALE_F 0.014731391274719738f  // 1/sqrt(4608)

// ---------------------------------------------------------------------------
// K1: s[b,ci] = style[b,:] . modulation_w[ci,:] + modulation_b[ci]
// ---------------------------------------------------------------------------
__global__ __launch_bounds__(256) void k_mod(const float* __restrict__ style,
                                             const float* __restrict__ mw,
                                             const float* __restrict__ mb,
                                             float* __restrict__ s) {
    int idx = blockIdx.x * 256 + threadIdx.x;   // b*CIN + ci
    int b = idx >> 9, ci = idx & 511;
    const float* st = style + (size_t)b * SDIM;
    const float* w  = mw + (size_t)ci * SDIM;
    float acc = 0.f;
    for (int d = 0; d < SDIM; d += 4) {
        acc += st[d] * w[d] + st[d+1] * w[d+1] + st[d+2] * w[d+2] + st[d+3] * w[d+3];
    }
    s[idx] = acc + mb[ci];
}

// ---------------------------------------------------------------------------
// K2a: Gu = u^T u   (u is [MM, RR], reduce over rows)
// tile 32x32, 256 threads, 2x2 micro, chunk 16
// ---------------------------------------------------------------------------
__global__ __launch_bounds__(256) void k_gram_u(const float* __restrict__ u,
                                                float* __restrict__ G) {
    const int r0 = blockIdx.x * 32, r1 = blockIdx.y * 32;
    __shared__ float As[16][33], Bs[16][33];
    int t = threadIdx.x, ty = t >> 4, tx = t & 15;
    float acc[2][2] = {};
    for (int l0 = 0; l0 < MM; l0 += 16) {
        for (int e = t; e < 512; e += 256) {
            int k = e >> 5, i = e & 31;
            As[k][i] = u[(size_t)(l0 + k) * RR + r0 + i];
            Bs[k][i] = u[(size_t)(l0 + k) * RR + r1 + i];
        }
        __syncthreads();
        #pragma unroll
        for (int k = 0; k < 16; ++k) {
            float a0 = As[k][ty*2], a1 = As[k][ty*2+1];
            float b0 = Bs[k][tx*2], b1 = Bs[k][tx*2+1];
            acc[0][0] += a0*b0; acc[0][1] += a0*b1;
            acc[1][0] += a1*b0; acc[1][1] += a1*b1;
        }
        __syncthreads();
    }
    for (int i = 0; i < 2; ++i)
        for (int j = 0; j < 2; ++j)
            G[(size_t)(r0 + ty*2 + i) * RR + r1 + tx*2 + j] = acc[i][j];
}

// ---------------------------------------------------------------------------
// K2b: Gv = vh vh^T   (vh is [RR, COUT], reduce over cols)
// ---------------------------------------------------------------------------
__global__ __launch_bounds__(256) void k_gram_v(const float* __restrict__ vh,
                                                float* __restrict__ G) {
    const int r0 = blockIdx.x * 32, r1 = blockIdx.y * 32;
    __shared__ float As[32][17], Bs[32][17];
    int t = threadIdx.x, ty = t >> 4, tx = t & 15;
    float acc[2][2] = {};
    for (int n0 = 0; n0 < COUT; n0 += 16) {
        for (int e = t; e < 512; e += 256) {
            int r = e >> 4, k = e & 15;
            As[r][k] = vh[(size_t)(r0 + r) * COUT + n0 + k];
            Bs[r][k] = vh[(size_t)(r1 + r) * COUT + n0 + k];
        }
        __syncthreads();
        #pragma unroll
        for (int k = 0; k < 16; ++k) {
            float a0 = As[ty*2][k], a1 = As[ty*2+1][k];
            float b0 = Bs[tx*2][k], b1 = Bs[tx*2+1][k];
            acc[0][0] += a0*b0; acc[0][1] += a0*b1;
            acc[1][0] += a1*b0; acc[1][1] += a1*b1;
        }
        __syncthreads();
    }
    for (int i = 0; i < 2; ++i)
        for (int j = 0; j < 2; ++j)
            G[(size_t)(r0 + ty*2 + i) * RR + r1 + tx*2 + j] = acc[i][j];
}

// ---------------------------------------------------------------------------
// K3: normsq_b = sum_{r,r'} ev[r] ev[r'] Gu[r,r'] Gv[r,r'];  coef_b = shift/max(norm,1e-12)
// one block per b
// ---------------------------------------------------------------------------
__global__ __launch_bounds__(256) void k_coef(const float* __restrict__ Gu,
                                              const float* __restrict__ Gv,
                                              const float* __restrict__ dir_delta,
                                              const int* __restrict__ dirs,
                                              const float* __restrict__ shifts,
                                              float* __restrict__ coef) {
    int b = blockIdx.x;
    __shared__ float evs[RR];
    __shared__ float red[256];
    int t = threadIdx.x;
    const float* ev = dir_delta + (size_t)dirs[b] * RR;
    for (int i = t; i < RR; i += 256) evs[i] = ev[i];
    __syncthreads();
    float acc = 0.f;
    for (int p = t; p < RR * RR; p += 256) {
        int r = p >> 9, r2 = p & 511;
        acc += Gu[p] * Gv[p] * evs[r] * evs[r2];
    }
    red[t] = acc;
    __syncthreads();
    for (int o = 128; o > 0; o >>= 1) {
        if (t < o) red[t] += red[t + o];
        __syncthreads();
    }
    if (t == 0) {
        float norm = fmaxf(sqrtf(red[0]), 1e-12f);
        coef[b] = shifts[b] / norm;
    }
}

// ---------------------------------------------------------------------------
// K4: fused delta GEMM + modulated weight build + demod partial sums.
//   delta[b,m,co] = sum_r u[m,r] * ev_b[r] * vh[r,co]
//   v = SCALE * (weight[co,ci,kk] + coef_b * delta) * s[b,ci],  m = kk*512+ci
//   Wf[b][co][m] = bf16(v);  demodsq[b,co] += v^2
// grid (m-tile 72, co-tile 8, b 16); tile 64x64, 256 threads, 4x4 micro
// ---------------------------------------------------------------------------
__global__ __launch_bounds__(256) void k_build(const float* __restrict__ u,
                                               const float* __restrict__ vh,
                                               const float* __restrict__ dir_delta,
                                               const int* __restrict__ dirs,
                                               const float* __restrict__ weight,
                                               const float* __restrict__ s,
                                               const float* __restrict__ coef,
                                               __hip_bfloat16* __restrict__ Wf,
                                               float* __restrict__ demodsq) {
    const int m0  = blockIdx.x * 64;
    const int co0 = blockIdx.y * 64;
    const int b   = blockIdx.z;
    __shared__ float As[64][17];   // [m_local][r_local]
    __shared__ float Bs[16][65];   // [r_local][co_local]
    __shared__ float evs[RR];
    __shared__ float red[16][65];  // [tx][co_local]
    int t = threadIdx.x, ty = t >> 4, tx = t & 15;
    const float* ev = dir_delta + (size_t)dirs[b] * RR;
    for (int i = t; i < RR; i += 256) evs[i] = ev[i];
    __syncthreads();
    float acc[4][4] = {};          // [i: co][j: m]
    for (int r0 = 0; r0 < RR; r0 += 16) {
        for (int e = t; e < 1024; e += 256) {
            int ml = e >> 4, rl = e & 15;
            As[ml][rl] = u[(size_t)(m0 + ml) * RR + r0 + rl];
        }
        for (int e = t; e < 1024; e += 256) {
            int rl = e >> 6, nl = e & 63;
            Bs[rl][nl] = vh[(size_t)(r0 + rl) * COUT + co0 + nl] * evs[r0 + rl];
        }
        __syncthreads();
        #pragma unroll
        for (int k = 0; k < 16; ++k) {
            float a[4], bb[4];
            #pragma unroll
            for (int j = 0; j < 4; ++j) a[j] = As[tx*4 + j][k];
            #pragma unroll
            for (int i = 0; i < 4; ++i) bb[i] = Bs[k][ty*4 + i];
            #pragma unroll
            for (int i = 0; i < 4; ++i)
                #pragma unroll
                for (int j = 0; j < 4; ++j) acc[i][j] += a[j] * bb[i];
        }
        __syncthreads();
    }
    // epilogue: build weights
    const float cf = coef[b];
    const int kk = m0 >> 9;
    float partial[4] = {0.f, 0.f, 0.f, 0.f};
    #pragma unroll
    for (int i = 0; i < 4; ++i) {
        int co = co0 + ty*4 + i;
        #pragma unroll
        for (int j = 0; j < 4; ++j) {
            int m = m0 + tx*4 + j;
            int ci = m & 511;
            float v = SCALE_F * (weight[(size_t)co * MM + ci * KK + kk] + cf * acc[i][j])
                              * s[b * CIN + ci];
            Wf[((size_t)b * COUT + co) * MM + m] = __float2bfloat16(v);
            partial[i] += v * v;
        }
    }
    #pragma unroll
    for (int i = 0; i < 4; ++i) red[tx][ty*4 + i] = partial[i];
    __syncthreads();
    if (t < 64) {
        float sum = 0.f;
        #pragma unroll
        for (int k = 0; k < 16; ++k) sum += red[k][t];
        atomicAdd(&demodsq[b * COUT + co0 + t], sum);
    }
}

// ---------------------------------------------------------------------------
// K5: grouped conv as implicit GEMM + demod epilogue.
//   out[b,co,p] = rsqrt(demodsq[b,co]+1e-8) * sum_m Wf[b,co,m] * patch[m,p]
//   patch[m=(kk,ci), p=(y,x)] = x[b,ci,y+dy,x+dx], dy=kk/3-1, dx=kk%3-1
// grid (p-tile 16, co-tile 8, b); tile 64x64, 256 threads, 4x4 micro
// ---------------------------------------------------------------------------
__global__ __launch_bounds__(256) void k_conv(const float* __restrict__ x,
                                              const __hip_bfloat16* __restrict__ Wf,
                                              const float* __restrict__ demodsq,
                                              float* __restrict__ out) {
    const int p0  = blockIdx.x * 64;
    const int co0 = blockIdx.y * 64;
    const int b   = blockIdx.z;
    const int y0  = p0 >> 5;            // pixel tile = rows y0, y0+1
    __shared__ float Ws[64][65];        // [co_local][m_local]
    __shared__ float Ps[64][65];        // [m_local(ci)][px_local]
    int t = threadIdx.x, ty = t >> 4, tx = t & 15;
    float acc[4][4] = {};               // [i: co][j: px]
    const float* xb = x + (size_t)b * CIN * HW;
    const __hip_bfloat16* wb = Wf + (size_t)b * COUT * MM;
    for (int c = 0; c < 72; ++c) {
        const int m0  = c * 64;
        const int kk  = m0 >> 9;
        const int ci0 = m0 & 511;
        const int dy  = kk / 3 - 1, dx = kk % 3 - 1;
        for (int e = t; e < 4096; e += 256) {
            int cl = e >> 6, ml = e & 63;
            Ws[cl][ml] = __bfloat162float(wb[(size_t)(co0 + cl) * MM + m0 + ml]);
        }
        for (int e = t; e < 4096; e += 256) {
            int cl = e >> 6, px = e & 63;
            int yy = y0 + (px >> 5) + dy;
            int xx = (px & 31) + dx;
            float v = 0.f;
            if (yy >= 0 && yy < HH && xx >= 0 && xx < WW)
                v = xb[(size_t)(ci0 + cl) * HW + yy * WW + xx];
            Ps[cl][px] = v;
        }
        __syncthreads();
        #pragma unroll 8
        for (int k = 0; k < 64; ++k) {
            float a[4], p[4];
            #pragma unroll
            for (int i = 0; i < 4; ++i) a[i] = Ws[ty*4 + i][k];
            #pragma unroll
            for (int j = 0; j < 4; ++j) p[j] = Ps[k][tx*4 + j];
            #pragma unroll
            for (int i = 0; i < 4; ++i)
                #pragma unroll
                for (int j = 0; j < 4; ++j) acc[i][j] += a[i] * p[j];
        }
        __syncthreads();
    }
    #pragma unroll
    for (int i = 0; i < 4; ++i) {
        int co = co0 + ty*4 + i;
        float dm = rsqrtf(demodsq[b * COUT + co] + 1e-8f);
        #pragma unroll
        for (int j = 0; j < 4; ++j) {
            out[((size_t)b * COUT + co) * HW + p0 + tx*4 + j] = acc[i][j] * dm;
        }
    }
}

// ---------------------------------------------------------------------------
extern "C" void kernel_launch(void* const* d_in, const int* in_sizes, int n_in,
                              void* d_out, int out_size, void* d_ws, size_t ws_size,
                              hipStream_t stream) {
    const float* x         = (const float*)d_in[0];
    const float* style     = (const float*)d_in[1];
    const float* mw        = (const float*)d_in[2];
    const float* mb        = (const float*)d_in[3];
    const float* weight    = (const float*)d_in[4];
    const float* u         = (const float*)d_in[5];
    const float* vh        = (const float*)d_in[6];
    const float* dir_delta = (const float*)d_in[7];
    const float* shifts    = (const float*)d_in[8];
    const int*   dirs      = (const int*)d_in[9];
    float* out = (float*)d_out;

    // workspace layout
    float* ws      = (float*)d_ws;
    float* s       = ws;                     // B*CIN        = 8192
    float* Gu      = s + BB * CIN;           // R*R          = 262144
    float* Gv      = Gu + RR * RR;           // R*R          = 262144
    float* coef    = Gv + RR * RR;           // 16
    float* demodsq = coef + 16;              // B*COUT       = 8192
    __hip_bfloat16* Wf = (__hip_bfloat16*)(demodsq + BB * COUT);  // B*COUT*M bf16

    hipMemsetAsync(demodsq, 0, BB * COUT * sizeof(float), stream);
    k_mod   <<<dim3(32),        256, 0, stream>>>(style, mw, mb, s);
    k_gram_u<<<dim3(16, 16),    256, 0, stream>>>(u, Gu);
    k_gram_v<<<dim3(16, 16),    256, 0, stream>>>(vh, Gv);
    k_coef  <<<dim3(BB),        256, 0, stream>>>(Gu, Gv, dir_delta, dirs, shifts, coef);
    k_build <<<dim3(72, 8, BB), 256, 0, stream>>>(u, vh, dir_delta, dirs, weight, s, coef, Wf, demodsq);
    k_conv  <<<dim3(16, 8, BB), 256, 0, stream>>>(x, Wf, demodsq, out);
}

// Round 2
// 1665.446 us; speedup vs baseline: 1.9443x; 1.9443x over previous
//
#include <hip/hip_runtime.h>
#include <hip/hip_bf16.h>

// Problem constants
#define BB   16
#define CIN  512
#define COUT 512
#define KS   3
#define KK   9
#define HH   32
#define WW   32
#define HW   1024
#define SDIM 512
#define RR   512
#define MM   4608               // KK*CIN; m = kk*512 + ci
#define MT   144                // MM/32 k-tiles
#define SCALE_F 0.014731391274719738f  // 1/sqrt(4608)

typedef __attribute__((ext_vector_type(8))) short bf16x8;
typedef __attribute__((ext_vector_type(4))) float f32x4;

__device__ __forceinline__ void gload_lds16(const void* g, void* l) {
    __builtin_amdgcn_global_load_lds(
        (const __attribute__((address_space(1))) unsigned int*)g,
        (__attribute__((address_space(3))) unsigned int*)l,
        16, 0, 0);
}

// ---------------------------------------------------------------------------
// K1: s[b,ci] = style[b,:] . modulation_w[ci,:] + modulation_b[ci]
// ---------------------------------------------------------------------------
__global__ __launch_bounds__(256) void k_mod(const float* __restrict__ style,
                                             const float* __restrict__ mw,
                                             const float* __restrict__ mb,
                                             float* __restrict__ s) {
    int idx = blockIdx.x * 256 + threadIdx.x;   // b*CIN + ci
    int b = idx >> 9, ci = idx & 511;
    const float* st = style + (size_t)b * SDIM;
    const float* w  = mw + (size_t)ci * SDIM;
    float acc = 0.f;
    for (int d = 0; d < SDIM; d += 4) {
        acc += st[d] * w[d] + st[d+1] * w[d+1] + st[d+2] * w[d+2] + st[d+3] * w[d+3];
    }
    s[idx] = acc + mb[ci];
}

// ---------------------------------------------------------------------------
// K2a: Gu = u^T u
// ---------------------------------------------------------------------------
__global__ __launch_bounds__(256) void k_gram_u(const float* __restrict__ u,
                                                float* __restrict__ G) {
    const int r0 = blockIdx.x * 32, r1 = blockIdx.y * 32;
    __shared__ float As[16][33], Bs[16][33];
    int t = threadIdx.x, ty = t >> 4, tx = t & 15;
    float acc[2][2] = {};
    for (int l0 = 0; l0 < MM; l0 += 16) {
        for (int e = t; e < 512; e += 256) {
            int k = e >> 5, i = e & 31;
            As[k][i] = u[(size_t)(l0 + k) * RR + r0 + i];
            Bs[k][i] = u[(size_t)(l0 + k) * RR + r1 + i];
        }
        __syncthreads();
        #pragma unroll
        for (int k = 0; k < 16; ++k) {
            float a0 = As[k][ty*2], a1 = As[k][ty*2+1];
            float b0 = Bs[k][tx*2], b1 = Bs[k][tx*2+1];
            acc[0][0] += a0*b0; acc[0][1] += a0*b1;
            acc[1][0] += a1*b0; acc[1][1] += a1*b1;
        }
        __syncthreads();
    }
    for (int i = 0; i < 2; ++i)
        for (int j = 0; j < 2; ++j)
            G[(size_t)(r0 + ty*2 + i) * RR + r1 + tx*2 + j] = acc[i][j];
}

// ---------------------------------------------------------------------------
// K2b: Gv = vh vh^T
// ---------------------------------------------------------------------------
__global__ __launch_bounds__(256) void k_gram_v(const float* __restrict__ vh,
                                                float* __restrict__ G) {
    const int r0 = blockIdx.x * 32, r1 = blockIdx.y * 32;
    __shared__ float As[32][17], Bs[32][17];
    int t = threadIdx.x, ty = t >> 4, tx = t & 15;
    float acc[2][2] = {};
    for (int n0 = 0; n0 < COUT; n0 += 16) {
        for (int e = t; e < 512; e += 256) {
            int r = e >> 4, k = e & 15;
            As[r][k] = vh[(size_t)(r0 + r) * COUT + n0 + k];
            Bs[r][k] = vh[(size_t)(r1 + r) * COUT + n0 + k];
        }
        __syncthreads();
        #pragma unroll
        for (int k = 0; k < 16; ++k) {
            float a0 = As[ty*2][k], a1 = As[ty*2+1][k];
            float b0 = Bs[tx*2][k], b1 = Bs[tx*2+1][k];
            acc[0][0] += a0*b0; acc[0][1] += a0*b1;
            acc[1][0] += a1*b0; acc[1][1] += a1*b1;
        }
        __syncthreads();
    }
    for (int i = 0; i < 2; ++i)
        for (int j = 0; j < 2; ++j)
            G[(size_t)(r0 + ty*2 + i) * RR + r1 + tx*2 + j] = acc[i][j];
}

// ---------------------------------------------------------------------------
// K3: coef_b = shift_b / max(||delta_b||_F, 1e-12) via Gram trick
// ---------------------------------------------------------------------------
__global__ __launch_bounds__(256) void k_coef(const float* __restrict__ Gu,
                                              const float* __restrict__ Gv,
                                              const float* __restrict__ dir_delta,
                                              const int* __restrict__ dirs,
                                              const float* __restrict__ shifts,
                                              float* __restrict__ coef) {
    int b = blockIdx.x;
    __shared__ float evs[RR];
    __shared__ float red[256];
    int t = threadIdx.x;
    const float* ev = dir_delta + (size_t)dirs[b] * RR;
    for (int i = t; i < RR; i += 256) evs[i] = ev[i];
    __syncthreads();
    float acc = 0.f;
    for (int p = t; p < RR * RR; p += 256) {
        int r = p >> 9, r2 = p & 511;
        acc += Gu[p] * Gv[p] * evs[r] * evs[r2];
    }
    red[t] = acc;
    __syncthreads();
    for (int o = 128; o > 0; o >>= 1) {
        if (t < o) red[t] += red[t + o];
        __syncthreads();
    }
    if (t == 0) {
        float norm = fmaxf(sqrtf(red[0]), 1e-12f);
        coef[b] = shifts[b] / norm;
    }
}

// ---------------------------------------------------------------------------
// K4: fused delta GEMM + modulated weight build + demod partial sums.
// Writes Wf in MFMA-tile layout: [b][mt][co(512)][32], with the element
// position XOR-swizzled (mk ^ ((co>>1)&3)<<3) so k_conv_mfma can
// global_load_lds linearly and ds_read_b128 conflict-free.
// ---------------------------------------------------------------------------
__global__ __launch_bounds__(256) void k_build(const float* __restrict__ u,
                                               const float* __restrict__ vh,
                                               const float* __restrict__ dir_delta,
                                               const int* __restrict__ dirs,
                                               const float* __restrict__ weight,
                                               const float* __restrict__ s,
                                               const float* __restrict__ coef,
                                               __hip_bfloat16* __restrict__ Wf,
                                               float* __restrict__ demodsq) {
    const int m0  = blockIdx.x * 64;
    const int co0 = blockIdx.y * 64;
    const int b   = blockIdx.z;
    __shared__ float As[64][17];   // [m_local][r_local]
    __shared__ float Bs[16][65];   // [r_local][co_local]
    __shared__ float evs[RR];
    __shared__ float red[16][65];  // [tx][co_local]
    int t = threadIdx.x, ty = t >> 4, tx = t & 15;
    const float* ev = dir_delta + (size_t)dirs[b] * RR;
    for (int i = t; i < RR; i += 256) evs[i] = ev[i];
    __syncthreads();
    float acc[4][4] = {};          // [i: co][j: m]
    for (int r0 = 0; r0 < RR; r0 += 16) {
        for (int e = t; e < 1024; e += 256) {
            int ml = e >> 4, rl = e & 15;
            As[ml][rl] = u[(size_t)(m0 + ml) * RR + r0 + rl];
        }
        for (int e = t; e < 1024; e += 256) {
            int rl = e >> 6, nl = e & 63;
            Bs[rl][nl] = vh[(size_t)(r0 + rl) * COUT + co0 + nl] * evs[r0 + rl];
        }
        __syncthreads();
        #pragma unroll
        for (int k = 0; k < 16; ++k) {
            float a[4], bb[4];
            #pragma unroll
            for (int j = 0; j < 4; ++j) a[j] = As[tx*4 + j][k];
            #pragma unroll
            for (int i = 0; i < 4; ++i) bb[i] = Bs[k][ty*4 + i];
            #pragma unroll
            for (int i = 0; i < 4; ++i)
                #pragma unroll
                for (int j = 0; j < 4; ++j) acc[i][j] += a[j] * bb[i];
        }
        __syncthreads();
    }
    // epilogue: build weights into swizzled tile layout
    const float cf = coef[b];
    const int kk = m0 >> 9;        // constant per block (m0 multiple of 64, 512%64==0)
    float partial[4] = {0.f, 0.f, 0.f, 0.f};
    #pragma unroll
    for (int i = 0; i < 4; ++i) {
        int co = co0 + ty*4 + i;
        int swz = ((co >> 1) & 3) << 3;
        #pragma unroll
        for (int j = 0; j < 4; ++j) {
            int m = m0 + tx*4 + j;
            int ci = m & 511;
            float v = SCALE_F * (weight[(size_t)co * MM + ci * KK + kk] + cf * acc[i][j])
                              * s[b * CIN + ci];
            int mt = m >> 5, mk = m & 31;
            Wf[(((size_t)b * MT + mt) * COUT + co) * 32 + (mk ^ swz)] = __float2bfloat16(v);
            partial[i] += v * v;
        }
    }
    #pragma unroll
    for (int i = 0; i < 4; ++i) red[tx][ty*4 + i] = partial[i];
    __syncthreads();
    if (t < 64) {
        float sum = 0.f;
        #pragma unroll
        for (int k = 0; k < 16; ++k) sum += red[k][t];
        atomicAdd(&demodsq[b * COUT + co0 + t], sum);
    }
}

// ---------------------------------------------------------------------------
// K_xpose: x [b][ci][y][x] fp32  ->  xhwc [b][y+1][x+1][ci] bf16 (NHWC, halo
// pre-zeroed by memset). Grid: 512 blocks = (b,y), 256 threads.
// ---------------------------------------------------------------------------
__global__ __launch_bounds__(256) void k_xpose(const float* __restrict__ x,
                                               __hip_bfloat16* __restrict__ xh) {
    const int b = blockIdx.x >> 5;
    const int y = blockIdx.x & 31;
    __shared__ __hip_bfloat16 tileT[32][72];   // [x][ci_chunk(64)] (+pad)
    const int t = threadIdx.x;
    for (int c0 = 0; c0 < CIN; c0 += 64) {
        // load 64 ci x 32 x, coalesced over x
        int ci_l = t >> 2, xq = (t & 3) * 8;
        const float* src = x + (((size_t)(b * CIN + c0 + ci_l)) * HH + y) * WW + xq;
        float4 v0 = *(const float4*)src;
        float4 v1 = *(const float4*)(src + 4);
        __syncthreads();   // prev iteration's tileT reads complete
        tileT[xq+0][ci_l] = __float2bfloat16(v0.x);
        tileT[xq+1][ci_l] = __float2bfloat16(v0.y);
        tileT[xq+2][ci_l] = __float2bfloat16(v0.z);
        tileT[xq+3][ci_l] = __float2bfloat16(v0.w);
        tileT[xq+4][ci_l] = __float2bfloat16(v1.x);
        tileT[xq+5][ci_l] = __float2bfloat16(v1.y);
        tileT[xq+6][ci_l] = __float2bfloat16(v1.z);
        tileT[xq+7][ci_l] = __float2bfloat16(v1.w);
        __syncthreads();
        // store contiguous over ci
        int x_l = t >> 3, cg = (t & 7) * 8;
        bf16x8 o = *(const bf16x8*)&tileT[x_l][cg];
        *(bf16x8*)&xh[(((size_t)b * 34 + y + 1) * 34 + (x_l + 1)) * CIN + c0 + cg] = o;
    }
}

// ---------------------------------------------------------------------------
// K5: grouped conv as MFMA implicit GEMM + demod epilogue.
//   out[b,co,p] = rsqrt(demodsq+1e-8) * sum_m W[b,co,m] * P[m,p]
// 128(co) x 128(p) tile, BK=32, 4 waves (2x2), 16x mfma_f32_16x16x32_bf16
// per wave per K-step. A and B staged via global_load_lds (linear dest,
// pre-swizzled source); ds_read_b128 conflict-free via slot XOR swizzle.
// ---------------------------------------------------------------------------
__global__ __launch_bounds__(256) void k_conv_mfma(
        const __hip_bfloat16* __restrict__ Wf,     // [b][mt][co][32] swizzled
        const __hip_bfloat16* __restrict__ xh,     // [b][34][34][512]
        const float* __restrict__ demodsq,
        float* __restrict__ out) {
    const int p0  = blockIdx.x * 128;
    const int co0 = blockIdx.y * 128;
    const int b   = blockIdx.z;
    __shared__ __align__(16) __hip_bfloat16 As[128 * 32];   // 8 KB
    __shared__ __align__(16) __hip_bfloat16 Bs[128 * 32];   // 8 KB
    const int t = threadIdx.x;
    const int w = t >> 6, l = t & 63;

    const char* wsrc0 = (const char*)(Wf + (((size_t)b * MT) * COUT + co0) * 32);
    const int lq = l >> 2;          // 0..15  (row within 16-row stripe)
    const int ls = l & 3;           // slot 0..3

    f32x4 acc[4][4];
    #pragma unroll
    for (int i = 0; i < 4; ++i)
        #pragma unroll
        for (int j = 0; j < 4; ++j) acc[i][j] = (f32x4){0.f, 0.f, 0.f, 0.f};

    for (int mt = 0; mt < MT; ++mt) {
        // ---- stage A (linear copy; source already tile-ordered + swizzled)
        const char* wa = wsrc0 + (size_t)mt * (COUT * 32 * 2);
        {
            int off0 = w * 1024 + l * 16;
            gload_lds16(wa + off0,        (char*)As + off0);
            gload_lds16(wa + off0 + 4096, (char*)As + off0 + 4096);
        }
        // ---- stage B (per-lane source from NHWC-halo image, pre-swizzled)
        const int kk  = mt >> 4;
        const int ci0 = (mt & 15) << 5;
        const int dy  = kk / 3 - 1, dx = kk % 3 - 1;
        #pragma unroll
        for (int i = 0; i < 2; ++i) {
            int p_l = i * 64 + w * 16 + lq;
            int P   = p0 + p_l;
            int yy  = (P >> 5) + dy + 1;
            int xx  = (P & 31) + dx + 1;
            int sg  = ls ^ ((p_l >> 1) & 3);
            const __hip_bfloat16* src =
                xh + (((size_t)b * 34 + yy) * 34 + xx) * CIN + ci0 + sg * 8;
            gload_lds16(src, (char*)Bs + i * 4096 + w * 1024 + l * 16);
        }
        __syncthreads();   // vmcnt(0) drain + barrier: tiles ready

        // ---- fragments + MFMA
        bf16x8 fa[4], fb[4];
        const int sl = (l >> 4) << 4;          // byte slot base
        const int ar = (w >> 1) * 64 + (l & 15);
        const int br = (w & 1) * 64 + (l & 15);
        #pragma unroll
        for (int i = 0; i < 4; ++i) {
            int r = ar + i * 16;
            fa[i] = *(const bf16x8*)((const char*)As + r * 64 + (sl ^ (((r >> 1) & 3) << 4)));
            int q = br + i * 16;
            fb[i] = *(const bf16x8*)((const char*)Bs + q * 64 + (sl ^ (((q >> 1) & 3) << 4)));
        }
        #pragma unroll
        for (int i = 0; i < 4; ++i)
            #pragma unroll
            for (int j = 0; j < 4; ++j)
                acc[i][j] = __builtin_amdgcn_mfma_f32_16x16x32_bf16(fa[i], fb[j], acc[i][j], 0, 0, 0);
        __syncthreads();   // LDS reads complete before next stage overwrites
    }

    // ---- epilogue: demod + store
    const float* dmrow = demodsq + b * COUT;
    #pragma unroll
    for (int i = 0; i < 4; ++i) {
        int co = co0 + (w >> 1) * 64 + i * 16 + (l >> 4) * 4;
        #pragma unroll
        for (int r = 0; r < 4; ++r) {
            float dm = rsqrtf(dmrow[co + r] + 1e-8f);
            #pragma unroll
            for (int j = 0; j < 4; ++j) {
                int p = p0 + (w & 1) * 64 + j * 16 + (l & 15);
                out[((size_t)b * COUT + co + r) * HW + p] = acc[i][j][r] * dm;
            }
        }
    }
}

// ---------------------------------------------------------------------------
extern "C" void kernel_launch(void* const* d_in, const int* in_sizes, int n_in,
                              void* d_out, int out_size, void* d_ws, size_t ws_size,
                              hipStream_t stream) {
    const float* x         = (const float*)d_in[0];
    const float* style     = (const float*)d_in[1];
    const float* mw        = (const float*)d_in[2];
    const float* mb        = (const float*)d_in[3];
    const float* weight    = (const float*)d_in[4];
    const float* u         = (const float*)d_in[5];
    const float* vh        = (const float*)d_in[6];
    const float* dir_delta = (const float*)d_in[7];
    const float* shifts    = (const float*)d_in[8];
    const int*   dirs      = (const int*)d_in[9];
    float* out = (float*)d_out;

    // workspace layout
    float* ws      = (float*)d_ws;
    float* s       = ws;                     // 8192
    float* Gu      = s + BB * CIN;           // 262144
    float* Gv      = Gu + RR * RR;           // 262144
    float* coef    = Gv + RR * RR;           // 16
    float* demodsq = coef + 16;              // 8192
    __hip_bfloat16* Wf = (__hip_bfloat16*)(demodsq + BB * COUT);       // 75.5 MB
    __hip_bfloat16* xh = Wf + (size_t)BB * MT * COUT * 32;             // 18.9 MB

    hipMemsetAsync(demodsq, 0, BB * COUT * sizeof(float), stream);
    hipMemsetAsync(xh, 0, (size_t)BB * 34 * 34 * CIN * sizeof(__hip_bfloat16), stream);
    k_mod      <<<dim3(32),        256, 0, stream>>>(style, mw, mb, s);
    k_gram_u   <<<dim3(16, 16),    256, 0, stream>>>(u, Gu);
    k_gram_v   <<<dim3(16, 16),    256, 0, stream>>>(vh, Gv);
    k_coef     <<<dim3(BB),        256, 0, stream>>>(Gu, Gv, dir_delta, dirs, shifts, coef);
    k_xpose    <<<dim3(512),       256, 0, stream>>>(x, xh);
    k_build    <<<dim3(72, 8, BB), 256, 0, stream>>>(u, vh, dir_delta, dirs, weight, s, coef, Wf, demodsq);
    k_conv_mfma<<<dim3(8, 4, BB),  256, 0, stream>>>(Wf, xh, demodsq, out);
}

// Round 4
// 914.174 us; speedup vs baseline: 3.5422x; 1.8218x over previous
//
#include <hip/hip_runtime.h>
#include <hip/hip_bf16.h>

// Problem constants
#define BB   16
#define CIN  512
#define COUT 512
#define KS   3
#define KK   9
#define HH   32
#define WW   32
#define HW   1024
#define SDIM 512
#define RR   512
#define MM   4608               // KK*CIN; m = kk*512 + ci
#define MT   144                // MM/32 k-tiles
#define SCALE_F 0.014731391274719738f  // 1/sqrt(4608)

typedef __attribute__((ext_vector_type(8))) short bf16x8;
typedef __attribute__((ext_vector_type(4))) float f32x4;

__device__ __forceinline__ void gload_lds16(const void* g, void* l) {
    __builtin_amdgcn_global_load_lds(
        (const __attribute__((address_space(1))) unsigned int*)g,
        (__attribute__((address_space(3))) unsigned int*)l,
        16, 0, 0);
}

// ---------------------------------------------------------------------------
// K1: s[b,ci] = style[b,:] . modulation_w[ci,:] + modulation_b[ci]
// ---------------------------------------------------------------------------
__global__ __launch_bounds__(256) void k_mod(const float* __restrict__ style,
                                             const float* __restrict__ mw,
                                             const float* __restrict__ mb,
                                             float* __restrict__ s) {
    int idx = blockIdx.x * 256 + threadIdx.x;   // b*CIN + ci
    int b = idx >> 9, ci = idx & 511;
    const float* st = style + (size_t)b * SDIM;
    const float* w  = mw + (size_t)ci * SDIM;
    float acc = 0.f;
    for (int d = 0; d < SDIM; d += 4) {
        acc += st[d] * w[d] + st[d+1] * w[d+1] + st[d+2] * w[d+2] + st[d+3] * w[d+3];
    }
    s[idx] = acc + mb[ci];
}

// ---------------------------------------------------------------------------
// K2a: Gu = u^T u   (fp32, feeds the exact-norm Gram trick)
// ---------------------------------------------------------------------------
__global__ __launch_bounds__(256) void k_gram_u(const float* __restrict__ u,
                                                float* __restrict__ G) {
    const int r0 = blockIdx.x * 32, r1 = blockIdx.y * 32;
    __shared__ float As[16][33], Bs[16][33];
    int t = threadIdx.x, ty = t >> 4, tx = t & 15;
    float acc[2][2] = {};
    for (int l0 = 0; l0 < MM; l0 += 16) {
        for (int e = t; e < 512; e += 256) {
            int k = e >> 5, i = e & 31;
            As[k][i] = u[(size_t)(l0 + k) * RR + r0 + i];
            Bs[k][i] = u[(size_t)(l0 + k) * RR + r1 + i];
        }
        __syncthreads();
        #pragma unroll
        for (int k = 0; k < 16; ++k) {
            float a0 = As[k][ty*2], a1 = As[k][ty*2+1];
            float b0 = Bs[k][tx*2], b1 = Bs[k][tx*2+1];
            acc[0][0] += a0*b0; acc[0][1] += a0*b1;
            acc[1][0] += a1*b0; acc[1][1] += a1*b1;
        }
        __syncthreads();
    }
    for (int i = 0; i < 2; ++i)
        for (int j = 0; j < 2; ++j)
            G[(size_t)(r0 + ty*2 + i) * RR + r1 + tx*2 + j] = acc[i][j];
}

// ---------------------------------------------------------------------------
// K2b: Gv = vh vh^T
// ---------------------------------------------------------------------------
__global__ __launch_bounds__(256) void k_gram_v(const float* __restrict__ vh,
                                                float* __restrict__ G) {
    const int r0 = blockIdx.x * 32, r1 = blockIdx.y * 32;
    __shared__ float As[32][17], Bs[32][17];
    int t = threadIdx.x, ty = t >> 4, tx = t & 15;
    float acc[2][2] = {};
    for (int n0 = 0; n0 < COUT; n0 += 16) {
        for (int e = t; e < 512; e += 256) {
            int r = e >> 4, k = e & 15;
            As[r][k] = vh[(size_t)(r0 + r) * COUT + n0 + k];
            Bs[r][k] = vh[(size_t)(r1 + r) * COUT + n0 + k];
        }
        __syncthreads();
        #pragma unroll
        for (int k = 0; k < 16; ++k) {
            float a0 = As[ty*2][k], a1 = As[ty*2+1][k];
            float b0 = Bs[tx*2][k], b1 = Bs[tx*2+1][k];
            acc[0][0] += a0*b0; acc[0][1] += a0*b1;
            acc[1][0] += a1*b0; acc[1][1] += a1*b1;
        }
        __syncthreads();
    }
    for (int i = 0; i < 2; ++i)
        for (int j = 0; j < 2; ++j)
            G[(size_t)(r0 + ty*2 + i) * RR + r1 + tx*2 + j] = acc[i][j];
}

// ---------------------------------------------------------------------------
// K3: coef_b = shift_b / max(||delta_b||_F, 1e-12) via Gram trick
// ---------------------------------------------------------------------------
__global__ __launch_bounds__(256) void k_coef(const float* __restrict__ Gu,
                                              const float* __restrict__ Gv,
                                              const float* __restrict__ dir_delta,
                                              const int* __restrict__ dirs,
                                              const float* __restrict__ shifts,
                                              float* __restrict__ coef) {
    int b = blockIdx.x;
    __shared__ float evs[RR];
    __shared__ float red[256];
    int t = threadIdx.x;
    const float* ev = dir_delta + (size_t)dirs[b] * RR;
    for (int i = t; i < RR; i += 256) evs[i] = ev[i];
    __syncthreads();
    float acc = 0.f;
    for (int p = t; p < RR * RR; p += 256) {
        int r = p >> 9, r2 = p & 511;
        acc += Gu[p] * Gv[p] * evs[r] * evs[r2];
    }
    red[t] = acc;
    __syncthreads();
    for (int o = 128; o > 0; o >>= 1) {
        if (t < o) red[t] += red[t + o];
        __syncthreads();
    }
    if (t == 0) {
        float norm = fmaxf(sqrtf(red[0]), 1e-12f);
        coef[b] = shifts[b] / norm;
    }
}

// ---------------------------------------------------------------------------
// Prep A: ubf = bf16(u), same [m][r] layout (contiguous in K=r).
// ---------------------------------------------------------------------------
__global__ __launch_bounds__(256) void k_prep_u(const float* __restrict__ u,
                                                __hip_bfloat16* __restrict__ ub) {
    size_t i = ((size_t)blockIdx.x * 256 + threadIdx.x) * 8;
    float4 a = *(const float4*)(u + i);
    float4 b = *(const float4*)(u + i + 4);
    __hip_bfloat16 o[8] = {
        __float2bfloat16(a.x), __float2bfloat16(a.y),
        __float2bfloat16(a.z), __float2bfloat16(a.w),
        __float2bfloat16(b.x), __float2bfloat16(b.y),
        __float2bfloat16(b.z), __float2bfloat16(b.w)};
    *(bf16x8*)(ub + i) = *(const bf16x8*)o;
}

// ---------------------------------------------------------------------------
// Prep B: vt[b][co][r] = bf16(ev_b[r] * vh[r][co])  (transpose + diag fold)
// ---------------------------------------------------------------------------
__global__ __launch_bounds__(256) void k_prep_vt(const float* __restrict__ vh,
                                                 const float* __restrict__ dd,
                                                 const int* __restrict__ dirs,
                                                 __hip_bfloat16* __restrict__ vt) {
    const int co0 = blockIdx.x * 64, r0 = blockIdx.y * 64, b = blockIdx.z;
    const float* ev = dd + (size_t)dirs[b] * RR;
    __shared__ __hip_bfloat16 tile[64][80];   // [co][r], stride 160B
    int t = threadIdx.x;
    int tc4 = (t & 15) * 4, tr = t >> 4;
    #pragma unroll
    for (int pass = 0; pass < 4; ++pass) {
        int r = tr + pass * 16;
        float e = ev[r0 + r];
        float4 v = *(const float4*)&vh[(size_t)(r0 + r) * COUT + co0 + tc4];
        tile[tc4+0][r] = __float2bfloat16(v.x * e);
        tile[tc4+1][r] = __float2bfloat16(v.y * e);
        tile[tc4+2][r] = __float2bfloat16(v.z * e);
        tile[tc4+3][r] = __float2bfloat16(v.w * e);
    }
    __syncthreads();
    int cl = t >> 2, rg = (t & 3) * 16;
    __hip_bfloat16* dst = vt + ((size_t)b * COUT + co0 + cl) * RR + r0 + rg;
    *(bf16x8*)dst       = *(const bf16x8*)&tile[cl][rg];
    *(bf16x8*)(dst + 8) = *(const bf16x8*)&tile[cl][rg + 8];
}

// ---------------------------------------------------------------------------
// K4: MFMA delta-GEMM + weight build + demod partials.
//   acc[m][co] = sum_r ubf[m][r] * vt[b][co][r]
//   v = SCALE*(weight[co][ci][kk] + cf*acc)*s[b,ci];  Wf swizzled; demodsq += v^2
// 128(m) x 128(co) tile, BK=32, 4 waves (2x2), 16 K-steps
// ---------------------------------------------------------------------------
__global__ __launch_bounds__(256) void k_build_mfma(
        const __hip_bfloat16* __restrict__ ubf,   // [MM][RR]
        const __hip_bfloat16* __restrict__ vt,    // [B][COUT][RR]
        const float* __restrict__ wgt,            // [COUT][CIN][9] original
        const float* __restrict__ s,              // [B][CIN]
        const float* __restrict__ coef,
        __hip_bfloat16* __restrict__ Wf,          // [B][MT][COUT][32] swizzled
        float* __restrict__ demodsq) {
    const int m0  = blockIdx.x * 128;
    const int co0 = blockIdx.y * 128;
    const int b   = blockIdx.z;
    __shared__ __align__(16) __hip_bfloat16 As[128 * 32];   // 8 KB  [m][32]
    __shared__ __align__(16) __hip_bfloat16 Bs[128 * 32];   // 8 KB  [co][32]
    __shared__ float red[128];
    const int t = threadIdx.x;
    const int w = t >> 6, l = t & 63;
    const int row = t >> 2;          // dest row 0..63 (first half)
    const int ls  = t & 3;
    const int sg  = ls ^ ((row >> 1) & 3);  // same for row and row+64

    const char* ua = (const char*)(ubf + (size_t)(m0 + row) * RR) + sg * 16;
    const char* ua2 = ua + (size_t)64 * RR * 2;
    const char* va = (const char*)(vt + ((size_t)b * COUT + co0 + row) * RR) + sg * 16;
    const char* va2 = va + (size_t)64 * RR * 2;
    const int dst0 = w * 1024 + l * 16;

    f32x4 acc[4][4];
    #pragma unroll
    for (int i = 0; i < 4; ++i)
        #pragma unroll
        for (int j = 0; j < 4; ++j) acc[i][j] = (f32x4){0.f, 0.f, 0.f, 0.f};

    for (int kt = 0; kt < 16; ++kt) {
        const int rb = kt * 64;      // byte offset along r
        gload_lds16(ua  + rb, (char*)As + dst0);
        gload_lds16(ua2 + rb, (char*)As + dst0 + 4096);
        gload_lds16(va  + rb, (char*)Bs + dst0);
        gload_lds16(va2 + rb, (char*)Bs + dst0 + 4096);
        __syncthreads();

        bf16x8 fa[4], fb[4];
        const int sl = (l >> 4) << 4;
        const int ar = (w >> 1) * 64 + (l & 15);
        const int br = (w & 1) * 64 + (l & 15);
        #pragma unroll
        for (int i = 0; i < 4; ++i) {
            int r = ar + i * 16;
            fa[i] = *(const bf16x8*)((const char*)As + r * 64 + (sl ^ (((r >> 1) & 3) << 4)));
            int q = br + i * 16;
            fb[i] = *(const bf16x8*)((const char*)Bs + q * 64 + (sl ^ (((q >> 1) & 3) << 4)));
        }
        #pragma unroll
        for (int i = 0; i < 4; ++i)
            #pragma unroll
            for (int j = 0; j < 4; ++j)
                acc[i][j] = __builtin_amdgcn_mfma_f32_16x16x32_bf16(fa[i], fb[j], acc[i][j], 0, 0, 0);
        __syncthreads();
    }

    // ---- epilogue
    if (t < 128) red[t] = 0.f;
    __syncthreads();
    const float cf = coef[b];
    const int kkc = m0 >> 9;                 // constant per block
    float partial[4] = {0.f, 0.f, 0.f, 0.f};
    #pragma unroll
    for (int i = 0; i < 4; ++i) {
        const int m_base = m0 + (w >> 1) * 64 + i * 16 + (l >> 4) * 4;   // 4 consecutive m
        const int ci = m_base & 511;
        const int mt = m_base >> 5, mk = m_base & 31;
        float4 sv = *(const float4*)&s[b * CIN + ci];
        #pragma unroll
        for (int j = 0; j < 4; ++j) {
            const int co = co0 + (w & 1) * 64 + j * 16 + (l & 15);
            const size_t wb = (size_t)co * MM + (size_t)ci * KK + kkc;
            float w0 = wgt[wb];
            float w1 = wgt[wb + KK];
            float w2 = wgt[wb + 2 * KK];
            float w3 = wgt[wb + 3 * KK];
            float v0 = SCALE_F * (w0 + cf * acc[i][j][0]) * sv.x;
            float v1 = SCALE_F * (w1 + cf * acc[i][j][1]) * sv.y;
            float v2 = SCALE_F * (w2 + cf * acc[i][j][2]) * sv.z;
            float v3 = SCALE_F * (w3 + cf * acc[i][j][3]) * sv.w;
            __hip_bfloat16 vb[4] = {__float2bfloat16(v0), __float2bfloat16(v1),
                                    __float2bfloat16(v2), __float2bfloat16(v3)};
            const int swz = ((co >> 1) & 3) << 3;
            __hip_bfloat16* dst = Wf + (((size_t)b * MT + mt) * COUT + co) * 32 + (mk ^ swz);
            *(ushort4*)dst = *(const ushort4*)vb;
            partial[j] += v0*v0 + v1*v1 + v2*v2 + v3*v3;
        }
    }
    #pragma unroll
    for (int j = 0; j < 4; ++j)
        atomicAdd(&red[(w & 1) * 64 + j * 16 + (l & 15)], partial[j]);
    __syncthreads();
    if (t < 128) atomicAdd(&demodsq[b * COUT + co0 + t], red[t]);
}

// ---------------------------------------------------------------------------
// K_xpose: x [b][ci][y][x] fp32 -> xhwc [b][y+1][x+1][ci] bf16 (halo zeroed)
// ---------------------------------------------------------------------------
__global__ __launch_bounds__(256) void k_xpose(const float* __restrict__ x,
                                               __hip_bfloat16* __restrict__ xh) {
    const int b = blockIdx.x >> 5;
    const int y = blockIdx.x & 31;
    __shared__ __hip_bfloat16 tileT[32][72];
    const int t = threadIdx.x;
    for (int c0 = 0; c0 < CIN; c0 += 64) {
        int ci_l = t >> 2, xq = (t & 3) * 8;
        const float* src = x + (((size_t)(b * CIN + c0 + ci_l)) * HH + y) * WW + xq;
        float4 v0 = *(const float4*)src;
        float4 v1 = *(const float4*)(src + 4);
        __syncthreads();
        tileT[xq+0][ci_l] = __float2bfloat16(v0.x);
        tileT[xq+1][ci_l] = __float2bfloat16(v0.y);
        tileT[xq+2][ci_l] = __float2bfloat16(v0.z);
        tileT[xq+3][ci_l] = __float2bfloat16(v0.w);
        tileT[xq+4][ci_l] = __float2bfloat16(v1.x);
        tileT[xq+5][ci_l] = __float2bfloat16(v1.y);
        tileT[xq+6][ci_l] = __float2bfloat16(v1.z);
        tileT[xq+7][ci_l] = __float2bfloat16(v1.w);
        __syncthreads();
        int x_l = t >> 3, cg = (t & 7) * 8;
        bf16x8 o = *(const bf16x8*)&tileT[x_l][cg];
        *(bf16x8*)&xh[(((size_t)b * 34 + y + 1) * 34 + (x_l + 1)) * CIN + c0 + cg] = o;
    }
}

// ---------------------------------------------------------------------------
// K5: grouped conv as MFMA implicit GEMM + demod epilogue
// ---------------------------------------------------------------------------
__global__ __launch_bounds__(256) void k_conv_mfma(
        const __hip_bfloat16* __restrict__ Wf,     // [b][mt][co][32] swizzled
        const __hip_bfloat16* __restrict__ xh,     // [b][34][34][512]
        const float* __restrict__ demodsq,
        float* __restrict__ out) {
    const int p0  = blockIdx.x * 128;
    const int co0 = blockIdx.y * 128;
    const int b   = blockIdx.z;
    __shared__ __align__(16) __hip_bfloat16 As[128 * 32];
    __shared__ __align__(16) __hip_bfloat16 Bs[128 * 32];
    const int t = threadIdx.x;
    const int w = t >> 6, l = t & 63;

    const char* wsrc0 = (const char*)(Wf + (((size_t)b * MT) * COUT + co0) * 32);
    const int lq = l >> 2;
    const int ls = l & 3;

    f32x4 acc[4][4];
    #pragma unroll
    for (int i = 0; i < 4; ++i)
        #pragma unroll
        for (int j = 0; j < 4; ++j) acc[i][j] = (f32x4){0.f, 0.f, 0.f, 0.f};

    for (int mt = 0; mt < MT; ++mt) {
        const char* wa = wsrc0 + (size_t)mt * (COUT * 32 * 2);
        {
            int off0 = w * 1024 + l * 16;
            gload_lds16(wa + off0,        (char*)As + off0);
            gload_lds16(wa + off0 + 4096, (char*)As + off0 + 4096);
        }
        const int kk  = mt >> 4;
        const int ci0 = (mt & 15) << 5;
        const int dy  = kk / 3 - 1, dx = kk % 3 - 1;
        #pragma unroll
        for (int i = 0; i < 2; ++i) {
            int p_l = i * 64 + w * 16 + lq;
            int P   = p0 + p_l;
            int yy  = (P >> 5) + dy + 1;
            int xx  = (P & 31) + dx + 1;
            int sg  = ls ^ ((p_l >> 1) & 3);
            const __hip_bfloat16* src =
                xh + (((size_t)b * 34 + yy) * 34 + xx) * CIN + ci0 + sg * 8;
            gload_lds16(src, (char*)Bs + i * 4096 + w * 1024 + l * 16);
        }
        __syncthreads();

        bf16x8 fa[4], fb[4];
        const int sl = (l >> 4) << 4;
        const int ar = (w >> 1) * 64 + (l & 15);
        const int br = (w & 1) * 64 + (l & 15);
        #pragma unroll
        for (int i = 0; i < 4; ++i) {
            int r = ar + i * 16;
            fa[i] = *(const bf16x8*)((const char*)As + r * 64 + (sl ^ (((r >> 1) & 3) << 4)));
            int q = br + i * 16;
            fb[i] = *(const bf16x8*)((const char*)Bs + q * 64 + (sl ^ (((q >> 1) & 3) << 4)));
        }
        #pragma unroll
        for (int i = 0; i < 4; ++i)
            #pragma unroll
            for (int j = 0; j < 4; ++j)
                acc[i][j] = __builtin_amdgcn_mfma_f32_16x16x32_bf16(fa[i], fb[j], acc[i][j], 0, 0, 0);
        __syncthreads();
    }

    const float* dmrow = demodsq + b * COUT;
    #pragma unroll
    for (int i = 0; i < 4; ++i) {
        int co = co0 + (w >> 1) * 64 + i * 16 + (l >> 4) * 4;
        #pragma unroll
        for (int r = 0; r < 4; ++r) {
            float dm = rsqrtf(dmrow[co + r] + 1e-8f);
            #pragma unroll
            for (int j = 0; j < 4; ++j) {
                int p = p0 + (w & 1) * 64 + j * 16 + (l & 15);
                out[((size_t)b * COUT + co + r) * HW + p] = acc[i][j][r] * dm;
            }
        }
    }
}

// ---------------------------------------------------------------------------
extern "C" void kernel_launch(void* const* d_in, const int* in_sizes, int n_in,
                              void* d_out, int out_size, void* d_ws, size_t ws_size,
                              hipStream_t stream) {
    const float* x         = (const float*)d_in[0];
    const float* style     = (const float*)d_in[1];
    const float* mw        = (const float*)d_in[2];
    const float* mb        = (const float*)d_in[3];
    const float* weight    = (const float*)d_in[4];
    const float* u         = (const float*)d_in[5];
    const float* vh        = (const float*)d_in[6];
    const float* dir_delta = (const float*)d_in[7];
    const float* shifts    = (const float*)d_in[8];
    const int*   dirs      = (const int*)d_in[9];
    float* out = (float*)d_out;

    // ---- compact workspace layout (high-water 94.57e6 B, < round-2-proven 96.6e6)
    char* base = (char*)d_ws;
    float* s       = (float*)(base);                    // 32 KB
    float* coef    = (float*)(base + 32768);            // 64 B
    float* demodsq = (float*)(base + 33024);            // 32 KB
    // union region X @128KB, size 18,939,904 B:
    //   phase 1: Gu (1 MB) @X+0, Gv (1 MB) @X+1MB          (dead after k_coef)
    //   phase 2: ubf (4.72 MB) @X+0, vt (8.39 MB) @X+4.72MB (dead after k_build)
    //   phase 3: xh (18.94 MB) @X+0
    char* X = base + 131072;
    float* Gu = (float*)(X);
    float* Gv = (float*)(X + 1048576);
    __hip_bfloat16* ubf = (__hip_bfloat16*)(X);
    __hip_bfloat16* vt  = (__hip_bfloat16*)(X + 4718592);
    __hip_bfloat16* xh  = (__hip_bfloat16*)(X);
    __hip_bfloat16* Wf  = (__hip_bfloat16*)(X + 18939904);   // 75.5 MB

    hipMemsetAsync(demodsq, 0, BB * COUT * sizeof(float), stream);
    k_mod      <<<dim3(32),         256, 0, stream>>>(style, mw, mb, s);
    k_gram_u   <<<dim3(16, 16),     256, 0, stream>>>(u, Gu);
    k_gram_v   <<<dim3(16, 16),     256, 0, stream>>>(vh, Gv);
    k_coef     <<<dim3(BB),         256, 0, stream>>>(Gu, Gv, dir_delta, dirs, shifts, coef);
    // Gu/Gv dead; preps overwrite region X
    k_prep_u   <<<dim3(1152),       256, 0, stream>>>(u, ubf);
    k_prep_vt  <<<dim3(8, 8, BB),   256, 0, stream>>>(vh, dir_delta, dirs, vt);
    k_build_mfma<<<dim3(36, 4, BB), 256, 0, stream>>>(ubf, vt, weight, s, coef, Wf, demodsq);
    // ubf/vt dead; xh overwrites region X
    hipMemsetAsync(xh, 0, (size_t)BB * 34 * 34 * CIN * sizeof(__hip_bfloat16), stream);
    k_xpose    <<<dim3(512),        256, 0, stream>>>(x, xh);
    k_conv_mfma<<<dim3(8, 4, BB),   256, 0, stream>>>(Wf, xh, demodsq, out);
}

// Round 5
// 480.457 us; speedup vs baseline: 6.7397x; 1.9027x over previous
//
#include <hip/hip_runtime.h>
#include <hip/hip_bf16.h>

// Problem constants
#define BB   16
#define CIN  512
#define COUT 512
#define KS   3
#define KK   9
#define HH   32
#define WW   32
#define HW   1024
#define SDIM 512
#define RR   512
#define MM   4608               // KK*CIN; m = kk*512 + ci
#define MT   144                // MM/32 k-tiles
#define SCALE_F 0.014731391274719738f  // 1/sqrt(4608)

typedef __attribute__((ext_vector_type(8))) short bf16x8;
typedef __attribute__((ext_vector_type(4))) float f32x4;

__device__ __forceinline__ void gload_lds16(const void* g, void* l) {
    __builtin_amdgcn_global_load_lds(
        (const __attribute__((address_space(1))) unsigned int*)g,
        (__attribute__((address_space(3))) unsigned int*)l,
        16, 0, 0);
}

// ---------------------------------------------------------------------------
// K1: s[b,ci] = style[b,:] . modulation_w[ci,:] + modulation_b[ci]
// ---------------------------------------------------------------------------
__global__ __launch_bounds__(256) void k_mod(const float* __restrict__ style,
                                             const float* __restrict__ mw,
                                             const float* __restrict__ mb,
                                             float* __restrict__ s) {
    int idx = blockIdx.x * 256 + threadIdx.x;   // b*CIN + ci
    int b = idx >> 9, ci = idx & 511;
    const float* st = style + (size_t)b * SDIM;
    const float* w  = mw + (size_t)ci * SDIM;
    float acc = 0.f;
    for (int d = 0; d < SDIM; d += 4) {
        acc += st[d] * w[d] + st[d+1] * w[d+1] + st[d+2] * w[d+2] + st[d+3] * w[d+3];
    }
    s[idx] = acc + mb[ci];
}

// ---------------------------------------------------------------------------
// K2a: Gu += u_slice^T u_slice   (split-K over 9 slices of 512 rows)
// 64x64 tile, 256 threads, 4x4 micro, atomicAdd epilogue (9 colliders/addr)
// ---------------------------------------------------------------------------
__global__ __launch_bounds__(256) void k_gram_u(const float* __restrict__ u,
                                                float* __restrict__ G) {
    const int r0 = blockIdx.x * 64, r1 = blockIdx.y * 64;
    const int l0base = blockIdx.z * 512;
    __shared__ float As[16][72], Bs[16][72];
    const int t = threadIdx.x, ty = t >> 4, tx = t & 15;
    const int lk = t >> 4, li4 = (t & 15) * 4;   // load map: 16 rows x 16 float4
    float acc[4][4] = {};
    for (int c = 0; c < 32; ++c) {
        const int l0 = l0base + c * 16;
        const float* row = u + (size_t)(l0 + lk) * RR;
        float4 av = *(const float4*)(row + r0 + li4);
        float4 bv = *(const float4*)(row + r1 + li4);
        __syncthreads();
        *(float4*)&As[lk][li4] = av;
        *(float4*)&Bs[lk][li4] = bv;
        __syncthreads();
        #pragma unroll
        for (int k = 0; k < 16; ++k) {
            float4 a = *(const float4*)&As[k][ty * 4];
            float4 b = *(const float4*)&Bs[k][tx * 4];
            acc[0][0] += a.x*b.x; acc[0][1] += a.x*b.y; acc[0][2] += a.x*b.z; acc[0][3] += a.x*b.w;
            acc[1][0] += a.y*b.x; acc[1][1] += a.y*b.y; acc[1][2] += a.y*b.z; acc[1][3] += a.y*b.w;
            acc[2][0] += a.z*b.x; acc[2][1] += a.z*b.y; acc[2][2] += a.z*b.z; acc[2][3] += a.z*b.w;
            acc[3][0] += a.w*b.x; acc[3][1] += a.w*b.y; acc[3][2] += a.w*b.z; acc[3][3] += a.w*b.w;
        }
    }
    #pragma unroll
    for (int i = 0; i < 4; ++i)
        #pragma unroll
        for (int j = 0; j < 4; ++j)
            atomicAdd(&G[(size_t)(r0 + ty*4 + i) * RR + r1 + tx*4 + j], acc[i][j]);
}

// ---------------------------------------------------------------------------
// K2b: Gv += vh_slice vh_slice^T  (split-K over 8 slices of 64 cols)
// 64x64 tile, 256 threads, 4x4 micro
// ---------------------------------------------------------------------------
__global__ __launch_bounds__(256) void k_gram_v(const float* __restrict__ vh,
                                                float* __restrict__ G) {
    const int r0 = blockIdx.x * 64, r1 = blockIdx.y * 64;
    const int n0base = blockIdx.z * 64;
    __shared__ float As[64][20], Bs[64][20];
    const int t = threadIdx.x, ty = t >> 4, tx = t & 15;
    const int lr = t >> 2, lk4 = (t & 3) * 4;    // load map: 64 rows x 4 float4
    float acc[4][4] = {};
    for (int c = 0; c < 4; ++c) {
        const int n0 = n0base + c * 16;
        float4 av = *(const float4*)&vh[(size_t)(r0 + lr) * COUT + n0 + lk4];
        float4 bv = *(const float4*)&vh[(size_t)(r1 + lr) * COUT + n0 + lk4];
        __syncthreads();
        *(float4*)&As[lr][lk4] = av;
        *(float4*)&Bs[lr][lk4] = bv;
        __syncthreads();
        #pragma unroll
        for (int k = 0; k < 16; ++k) {
            float a0 = As[ty*4+0][k], a1 = As[ty*4+1][k], a2 = As[ty*4+2][k], a3 = As[ty*4+3][k];
            float b0 = Bs[tx*4+0][k], b1 = Bs[tx*4+1][k], b2 = Bs[tx*4+2][k], b3 = Bs[tx*4+3][k];
            acc[0][0] += a0*b0; acc[0][1] += a0*b1; acc[0][2] += a0*b2; acc[0][3] += a0*b3;
            acc[1][0] += a1*b0; acc[1][1] += a1*b1; acc[1][2] += a1*b2; acc[1][3] += a1*b3;
            acc[2][0] += a2*b0; acc[2][1] += a2*b1; acc[2][2] += a2*b2; acc[2][3] += a2*b3;
            acc[3][0] += a3*b0; acc[3][1] += a3*b1; acc[3][2] += a3*b2; acc[3][3] += a3*b3;
        }
    }
    #pragma unroll
    for (int i = 0; i < 4; ++i)
        #pragma unroll
        for (int j = 0; j < 4; ++j)
            atomicAdd(&G[(size_t)(r0 + ty*4 + i) * RR + r1 + tx*4 + j], acc[i][j]);
}

// ---------------------------------------------------------------------------
// K3a: normsq[b] += sum over slice of ev_r ev_r' Gu[r,r'] Gv[r,r']
// grid (16 b, 8 slices of 64 rows)
// ---------------------------------------------------------------------------
__global__ __launch_bounds__(256) void k_norm(const float* __restrict__ Gu,
                                              const float* __restrict__ Gv,
                                              const float* __restrict__ dd,
                                              const int* __restrict__ dirs,
                                              float* __restrict__ normsq) {
    const int b = blockIdx.x, sl = blockIdx.y;
    __shared__ float evs[RR];
    __shared__ float red[256];
    const int t = threadIdx.x;
    const float* ev = dd + (size_t)dirs[b] * RR;
    for (int i = t; i < RR; i += 256) evs[i] = ev[i];
    __syncthreads();
    float acc = 0.f;
    const int base = sl * (RR * RR / 8);
    for (int p = base + t; p < base + RR * RR / 8; p += 256) {
        int r = p >> 9, r2 = p & 511;
        acc += Gu[p] * Gv[p] * evs[r] * evs[r2];
    }
    red[t] = acc;
    __syncthreads();
    for (int o = 128; o > 0; o >>= 1) {
        if (t < o) red[t] += red[t + o];
        __syncthreads();
    }
    if (t == 0) atomicAdd(&normsq[b], red[0]);
}

// K3b: coef_b = shift_b / max(sqrt(normsq_b), 1e-12)
__global__ __launch_bounds__(64) void k_fin(const float* __restrict__ normsq,
                                            const float* __restrict__ shifts,
                                            float* __restrict__ coef) {
    int t = threadIdx.x;
    if (t < BB) coef[t] = shifts[t] / fmaxf(sqrtf(normsq[t]), 1e-12f);
}

// ---------------------------------------------------------------------------
// Prep A: ubf = bf16(u), same [m][r] layout (contiguous in K=r).
// ---------------------------------------------------------------------------
__global__ __launch_bounds__(256) void k_prep_u(const float* __restrict__ u,
                                                __hip_bfloat16* __restrict__ ub) {
    size_t i = ((size_t)blockIdx.x * 256 + threadIdx.x) * 8;
    float4 a = *(const float4*)(u + i);
    float4 b = *(const float4*)(u + i + 4);
    __hip_bfloat16 o[8] = {
        __float2bfloat16(a.x), __float2bfloat16(a.y),
        __float2bfloat16(a.z), __float2bfloat16(a.w),
        __float2bfloat16(b.x), __float2bfloat16(b.y),
        __float2bfloat16(b.z), __float2bfloat16(b.w)};
    *(bf16x8*)(ub + i) = *(const bf16x8*)o;
}

// ---------------------------------------------------------------------------
// Prep B: vt[b][co][r] = bf16(ev_b[r] * vh[r][co])  (transpose + diag fold)
// ---------------------------------------------------------------------------
__global__ __launch_bounds__(256) void k_prep_vt(const float* __restrict__ vh,
                                                 const float* __restrict__ dd,
                                                 const int* __restrict__ dirs,
                                                 __hip_bfloat16* __restrict__ vt) {
    const int co0 = blockIdx.x * 64, r0 = blockIdx.y * 64, b = blockIdx.z;
    const float* ev = dd + (size_t)dirs[b] * RR;
    __shared__ __hip_bfloat16 tile[64][80];   // [co][r], stride 160B
    int t = threadIdx.x;
    int tc4 = (t & 15) * 4, tr = t >> 4;
    #pragma unroll
    for (int pass = 0; pass < 4; ++pass) {
        int r = tr + pass * 16;
        float e = ev[r0 + r];
        float4 v = *(const float4*)&vh[(size_t)(r0 + r) * COUT + co0 + tc4];
        tile[tc4+0][r] = __float2bfloat16(v.x * e);
        tile[tc4+1][r] = __float2bfloat16(v.y * e);
        tile[tc4+2][r] = __float2bfloat16(v.z * e);
        tile[tc4+3][r] = __float2bfloat16(v.w * e);
    }
    __syncthreads();
    int cl = t >> 2, rg = (t & 3) * 16;
    __hip_bfloat16* dst = vt + ((size_t)b * COUT + co0 + cl) * RR + r0 + rg;
    *(bf16x8*)dst       = *(const bf16x8*)&tile[cl][rg];
    *(bf16x8*)(dst + 8) = *(const bf16x8*)&tile[cl][rg + 8];
}

// ---------------------------------------------------------------------------
// K4: MFMA delta-GEMM + weight build + demod partials.
// ---------------------------------------------------------------------------
__global__ __launch_bounds__(256) void k_build_mfma(
        const __hip_bfloat16* __restrict__ ubf,   // [MM][RR]
        const __hip_bfloat16* __restrict__ vt,    // [B][COUT][RR]
        const float* __restrict__ wgt,            // [COUT][CIN][9] original
        const float* __restrict__ s,              // [B][CIN]
        const float* __restrict__ coef,
        __hip_bfloat16* __restrict__ Wf,          // [B][MT][COUT][32] swizzled
        float* __restrict__ demodsq) {
    const int m0  = blockIdx.x * 128;
    const int co0 = blockIdx.y * 128;
    const int b   = blockIdx.z;
    __shared__ __align__(16) __hip_bfloat16 As[128 * 32];   // 8 KB  [m][32]
    __shared__ __align__(16) __hip_bfloat16 Bs[128 * 32];   // 8 KB  [co][32]
    __shared__ float red[128];
    const int t = threadIdx.x;
    const int w = t >> 6, l = t & 63;
    const int row = t >> 2;
    const int ls  = t & 3;
    const int sg  = ls ^ ((row >> 1) & 3);

    const char* ua = (const char*)(ubf + (size_t)(m0 + row) * RR) + sg * 16;
    const char* ua2 = ua + (size_t)64 * RR * 2;
    const char* va = (const char*)(vt + ((size_t)b * COUT + co0 + row) * RR) + sg * 16;
    const char* va2 = va + (size_t)64 * RR * 2;
    const int dst0 = w * 1024 + l * 16;

    f32x4 acc[4][4];
    #pragma unroll
    for (int i = 0; i < 4; ++i)
        #pragma unroll
        for (int j = 0; j < 4; ++j) acc[i][j] = (f32x4){0.f, 0.f, 0.f, 0.f};

    for (int kt = 0; kt < 16; ++kt) {
        const int rb = kt * 64;
        gload_lds16(ua  + rb, (char*)As + dst0);
        gload_lds16(ua2 + rb, (char*)As + dst0 + 4096);
        gload_lds16(va  + rb, (char*)Bs + dst0);
        gload_lds16(va2 + rb, (char*)Bs + dst0 + 4096);
        __syncthreads();

        bf16x8 fa[4], fb[4];
        const int sl = (l >> 4) << 4;
        const int ar = (w >> 1) * 64 + (l & 15);
        const int br = (w & 1) * 64 + (l & 15);
        #pragma unroll
        for (int i = 0; i < 4; ++i) {
            int r = ar + i * 16;
            fa[i] = *(const bf16x8*)((const char*)As + r * 64 + (sl ^ (((r >> 1) & 3) << 4)));
            int q = br + i * 16;
            fb[i] = *(const bf16x8*)((const char*)Bs + q * 64 + (sl ^ (((q >> 1) & 3) << 4)));
        }
        #pragma unroll
        for (int i = 0; i < 4; ++i)
            #pragma unroll
            for (int j = 0; j < 4; ++j)
                acc[i][j] = __builtin_amdgcn_mfma_f32_16x16x32_bf16(fa[i], fb[j], acc[i][j], 0, 0, 0);
        __syncthreads();
    }

    // ---- epilogue
    if (t < 128) red[t] = 0.f;
    __syncthreads();
    const float cf = coef[b];
    const int kkc = m0 >> 9;
    float partial[4] = {0.f, 0.f, 0.f, 0.f};
    #pragma unroll
    for (int i = 0; i < 4; ++i) {
        const int m_base = m0 + (w >> 1) * 64 + i * 16 + (l >> 4) * 4;
        const int ci = m_base & 511;
        const int mt = m_base >> 5, mk = m_base & 31;
        float4 sv = *(const float4*)&s[b * CIN + ci];
        #pragma unroll
        for (int j = 0; j < 4; ++j) {
            const int co = co0 + (w & 1) * 64 + j * 16 + (l & 15);
            const size_t wb = (size_t)co * MM + (size_t)ci * KK + kkc;
            float w0 = wgt[wb];
            float w1 = wgt[wb + KK];
            float w2 = wgt[wb + 2 * KK];
            float w3 = wgt[wb + 3 * KK];
            float v0 = SCALE_F * (w0 + cf * acc[i][j][0]) * sv.x;
            float v1 = SCALE_F * (w1 + cf * acc[i][j][1]) * sv.y;
            float v2 = SCALE_F * (w2 + cf * acc[i][j][2]) * sv.z;
            float v3 = SCALE_F * (w3 + cf * acc[i][j][3]) * sv.w;
            __hip_bfloat16 vb[4] = {__float2bfloat16(v0), __float2bfloat16(v1),
                                    __float2bfloat16(v2), __float2bfloat16(v3)};
            const int swz = ((co >> 1) & 3) << 3;
            __hip_bfloat16* dst = Wf + (((size_t)b * MT + mt) * COUT + co) * 32 + (mk ^ swz);
            *(ushort4*)dst = *(const ushort4*)vb;
            partial[j] += v0*v0 + v1*v1 + v2*v2 + v3*v3;
        }
    }
    #pragma unroll
    for (int j = 0; j < 4; ++j)
        atomicAdd(&red[(w & 1) * 64 + j * 16 + (l & 15)], partial[j]);
    __syncthreads();
    if (t < 128) atomicAdd(&demodsq[b * COUT + co0 + t], red[t]);
}

// ---------------------------------------------------------------------------
// K_xpose: x [b][ci][y][x] fp32 -> xhwc [b][y+1][x+1][ci] bf16 (halo zeroed)
// ---------------------------------------------------------------------------
__global__ __launch_bounds__(256) void k_xpose(const float* __restrict__ x,
                                               __hip_bfloat16* __restrict__ xh) {
    const int b = blockIdx.x >> 5;
    const int y = blockIdx.x & 31;
    __shared__ __hip_bfloat16 tileT[32][72];
    const int t = threadIdx.x;
    for (int c0 = 0; c0 < CIN; c0 += 64) {
        int ci_l = t >> 2, xq = (t & 3) * 8;
        const float* src = x + (((size_t)(b * CIN + c0 + ci_l)) * HH + y) * WW + xq;
        float4 v0 = *(const float4*)src;
        float4 v1 = *(const float4*)(src + 4);
        __syncthreads();
        tileT[xq+0][ci_l] = __float2bfloat16(v0.x);
        tileT[xq+1][ci_l] = __float2bfloat16(v0.y);
        tileT[xq+2][ci_l] = __float2bfloat16(v0.z);
        tileT[xq+3][ci_l] = __float2bfloat16(v0.w);
        tileT[xq+4][ci_l] = __float2bfloat16(v1.x);
        tileT[xq+5][ci_l] = __float2bfloat16(v1.y);
        tileT[xq+6][ci_l] = __float2bfloat16(v1.z);
        tileT[xq+7][ci_l] = __float2bfloat16(v1.w);
        __syncthreads();
        int x_l = t >> 3, cg = (t & 7) * 8;
        bf16x8 o = *(const bf16x8*)&tileT[x_l][cg];
        *(bf16x8*)&xh[(((size_t)b * 34 + y + 1) * 34 + (x_l + 1)) * CIN + c0 + cg] = o;
    }
}

// ---------------------------------------------------------------------------
// K5: grouped conv as MFMA implicit GEMM + demod epilogue
// ---------------------------------------------------------------------------
__global__ __launch_bounds__(256) void k_conv_mfma(
        const __hip_bfloat16* __restrict__ Wf,     // [b][mt][co][32] swizzled
        const __hip_bfloat16* __restrict__ xh,     // [b][34][34][512]
        const float* __restrict__ demodsq,
        float* __restrict__ out) {
    const int p0  = blockIdx.x * 128;
    const int co0 = blockIdx.y * 128;
    const int b   = blockIdx.z;
    __shared__ __align__(16) __hip_bfloat16 As[128 * 32];
    __shared__ __align__(16) __hip_bfloat16 Bs[128 * 32];
    const int t = threadIdx.x;
    const int w = t >> 6, l = t & 63;

    const char* wsrc0 = (const char*)(Wf + (((size_t)b * MT) * COUT + co0) * 32);
    const int lq = l >> 2;
    const int ls = l & 3;

    f32x4 acc[4][4];
    #pragma unroll
    for (int i = 0; i < 4; ++i)
        #pragma unroll
        for (int j = 0; j < 4; ++j) acc[i][j] = (f32x4){0.f, 0.f, 0.f, 0.f};

    for (int mt = 0; mt < MT; ++mt) {
        const char* wa = wsrc0 + (size_t)mt * (COUT * 32 * 2);
        {
            int off0 = w * 1024 + l * 16;
            gload_lds16(wa + off0,        (char*)As + off0);
            gload_lds16(wa + off0 + 4096, (char*)As + off0 + 4096);
        }
        const int kk  = mt >> 4;
        const int ci0 = (mt & 15) << 5;
        const int dy  = kk / 3 - 1, dx = kk % 3 - 1;
        #pragma unroll
        for (int i = 0; i < 2; ++i) {
            int p_l = i * 64 + w * 16 + lq;
            int P   = p0 + p_l;
            int yy  = (P >> 5) + dy + 1;
            int xx  = (P & 31) + dx + 1;
            int sg  = ls ^ ((p_l >> 1) & 3);
            const __hip_bfloat16* src =
                xh + (((size_t)b * 34 + yy) * 34 + xx) * CIN + ci0 + sg * 8;
            gload_lds16(src, (char*)Bs + i * 4096 + w * 1024 + l * 16);
        }
        __syncthreads();

        bf16x8 fa[4], fb[4];
        const int sl = (l >> 4) << 4;
        const int ar = (w >> 1) * 64 + (l & 15);
        const int br = (w & 1) * 64 + (l & 15);
        #pragma unroll
        for (int i = 0; i < 4; ++i) {
            int r = ar + i * 16;
            fa[i] = *(const bf16x8*)((const char*)As + r * 64 + (sl ^ (((r >> 1) & 3) << 4)));
            int q = br + i * 16;
            fb[i] = *(const bf16x8*)((const char*)Bs + q * 64 + (sl ^ (((q >> 1) & 3) << 4)));
        }
        #pragma unroll
        for (int i = 0; i < 4; ++i)
            #pragma unroll
            for (int j = 0; j < 4; ++j)
                acc[i][j] = __builtin_amdgcn_mfma_f32_16x16x32_bf16(fa[i], fb[j], acc[i][j], 0, 0, 0);
        __syncthreads();
    }

    const float* dmrow = demodsq + b * COUT;
    #pragma unroll
    for (int i = 0; i < 4; ++i) {
        int co = co0 + (w >> 1) * 64 + i * 16 + (l >> 4) * 4;
        #pragma unroll
        for (int r = 0; r < 4; ++r) {
            float dm = rsqrtf(dmrow[co + r] + 1e-8f);
            #pragma unroll
            for (int j = 0; j < 4; ++j) {
                int p = p0 + (w & 1) * 64 + j * 16 + (l & 15);
                out[((size_t)b * COUT + co + r) * HW + p] = acc[i][j][r] * dm;
            }
        }
    }
}

// ---------------------------------------------------------------------------
extern "C" void kernel_launch(void* const* d_in, const int* in_sizes, int n_in,
                              void* d_out, int out_size, void* d_ws, size_t ws_size,
                              hipStream_t stream) {
    const float* x         = (const float*)d_in[0];
    const float* style     = (const float*)d_in[1];
    const float* mw        = (const float*)d_in[2];
    const float* mb        = (const float*)d_in[3];
    const float* weight    = (const float*)d_in[4];
    const float* u         = (const float*)d_in[5];
    const float* vh        = (const float*)d_in[6];
    const float* dir_delta = (const float*)d_in[7];
    const float* shifts    = (const float*)d_in[8];
    const int*   dirs      = (const int*)d_in[9];
    float* out = (float*)d_out;

    // ---- compact workspace layout (high-water 94.57e6 B, proven in round 4)
    char* base = (char*)d_ws;
    float* s       = (float*)(base);                    // 32 KB
    float* coef    = (float*)(base + 32768);            // 64 B
    float* normsq  = (float*)(base + 32832);            // 64 B
    float* demodsq = (float*)(base + 33024);            // 32 KB
    // union region X @128KB:
    //   phase 1: Gu (1 MB) @X+0, Gv (1 MB) @X+1MB          (dead after k_norm)
    //   phase 2: ubf (4.72 MB) @X+0, vt (8.39 MB) @X+4.72MB (dead after k_build)
    //   phase 3: xh (18.94 MB) @X+0
    char* X = base + 131072;
    float* Gu = (float*)(X);
    float* Gv = (float*)(X + 1048576);
    __hip_bfloat16* ubf = (__hip_bfloat16*)(X);
    __hip_bfloat16* vt  = (__hip_bfloat16*)(X + 4718592);
    __hip_bfloat16* xh  = (__hip_bfloat16*)(X);
    __hip_bfloat16* Wf  = (__hip_bfloat16*)(X + 18939904);   // 75.5 MB

    hipMemsetAsync(demodsq, 0, BB * COUT * sizeof(float), stream);
    hipMemsetAsync(normsq, 0, BB * sizeof(float), stream);
    hipMemsetAsync(X, 0, 2097152, stream);               // Gu+Gv (atomic targets)
    k_mod      <<<dim3(32),         256, 0, stream>>>(style, mw, mb, s);
    k_gram_u   <<<dim3(8, 8, 9),    256, 0, stream>>>(u, Gu);
    k_gram_v   <<<dim3(8, 8, 8),    256, 0, stream>>>(vh, Gv);
    k_norm     <<<dim3(BB, 8),      256, 0, stream>>>(Gu, Gv, dir_delta, dirs, normsq);
    k_fin      <<<dim3(1),          64,  0, stream>>>(normsq, shifts, coef);
    // Gu/Gv dead; preps overwrite region X
    k_prep_u   <<<dim3(1152),       256, 0, stream>>>(u, ubf);
    k_prep_vt  <<<dim3(8, 8, BB),   256, 0, stream>>>(vh, dir_delta, dirs, vt);
    k_build_mfma<<<dim3(36, 4, BB), 256, 0, stream>>>(ubf, vt, weight, s, coef, Wf, demodsq);
    // ubf/vt dead; xh overwrites region X
    hipMemsetAsync(xh, 0, (size_t)BB * 34 * 34 * CIN * sizeof(__hip_bfloat16), stream);
    k_xpose    <<<dim3(512),        256, 0, stream>>>(x, xh);
    k_conv_mfma<<<dim3(8, 4, BB),   256, 0, stream>>>(Wf, xh, demodsq, out);
}

// Round 6
// 374.247 us; speedup vs baseline: 8.6524x; 1.2838x over previous
//
#include <hip/hip_runtime.h>
#include <hip/hip_bf16.h>

// Problem constants
#define BB   16
#define CIN  512
#define COUT 512
#define KS   3
#define KK   9
#define HH   32
#define WW   32
#define HW   1024
#define SDIM 512
#define RR   512
#define MM   4608               // KK*CIN; m = kk*512 + ci
#define MT   144                // MM/32 k-tiles
#define SCALE_F 0.014731391274719738f  // 1/sqrt(4608)

typedef __attribute__((ext_vector_type(8))) short bf16x8;
typedef __attribute__((ext_vector_type(4))) float f32x4;

__device__ __forceinline__ void gload_lds16(const void* g, void* l) {
    __builtin_amdgcn_global_load_lds(
        (const __attribute__((address_space(1))) unsigned int*)g,
        (__attribute__((address_space(3))) unsigned int*)l,
        16, 0, 0);
}

// ---------------------------------------------------------------------------
// K1: s[b,ci] = style[b,:] . modulation_w[ci,:] + modulation_b[ci]
// ---------------------------------------------------------------------------
__global__ __launch_bounds__(256) void k_mod(const float* __restrict__ style,
                                             const float* __restrict__ mw,
                                             const float* __restrict__ mb,
                                             float* __restrict__ s) {
    int idx = blockIdx.x * 256 + threadIdx.x;   // b*CIN + ci
    int b = idx >> 9, ci = idx & 511;
    const float* st = style + (size_t)b * SDIM;
    const float* w  = mw + (size_t)ci * SDIM;
    float acc = 0.f;
    for (int d = 0; d < SDIM; d += 4) {
        acc += st[d] * w[d] + st[d+1] * w[d+1] + st[d+2] * w[d+2] + st[d+3] * w[d+3];
    }
    s[idx] = acc + mb[ci];
}

// ---------------------------------------------------------------------------
// Prep A: ubf = bf16(u), same [m][r] layout (contiguous in K=r).
// ---------------------------------------------------------------------------
__global__ __launch_bounds__(256) void k_prep_u(const float* __restrict__ u,
                                                __hip_bfloat16* __restrict__ ub) {
    size_t i = ((size_t)blockIdx.x * 256 + threadIdx.x) * 8;
    float4 a = *(const float4*)(u + i);
    float4 b = *(const float4*)(u + i + 4);
    __hip_bfloat16 o[8] = {
        __float2bfloat16(a.x), __float2bfloat16(a.y),
        __float2bfloat16(a.z), __float2bfloat16(a.w),
        __float2bfloat16(b.x), __float2bfloat16(b.y),
        __float2bfloat16(b.z), __float2bfloat16(b.w)};
    *(bf16x8*)(ub + i) = *(const bf16x8*)o;
}

// ---------------------------------------------------------------------------
// Prep A^T: ubfT[r][m] = bf16(u[m][r])  (for the Gram MFMA GEMM)
// grid (72 m-tiles, 8 r-tiles), 64x64 tiles
// ---------------------------------------------------------------------------
__global__ __launch_bounds__(256) void k_prep_uT(const float* __restrict__ u,
                                                 __hip_bfloat16* __restrict__ uT) {
    const int m0 = blockIdx.x * 64, r0 = blockIdx.y * 64;
    __shared__ __hip_bfloat16 tile[64][80];   // [r_local][m_local], pad
    const int t = threadIdx.x;
    const int ml = t >> 4, rl4 = (t & 15) * 4;
    #pragma unroll
    for (int p = 0; p < 4; ++p) {
        int m_l = ml + p * 16;
        float4 v = *(const float4*)&u[(size_t)(m0 + m_l) * RR + r0 + rl4];
        tile[rl4+0][m_l] = __float2bfloat16(v.x);
        tile[rl4+1][m_l] = __float2bfloat16(v.y);
        tile[rl4+2][m_l] = __float2bfloat16(v.z);
        tile[rl4+3][m_l] = __float2bfloat16(v.w);
    }
    __syncthreads();
    const int cl = t >> 2, rg = (t & 3) * 16;
    __hip_bfloat16* dst = uT + (size_t)(r0 + cl) * MM + m0 + rg;
    *(bf16x8*)dst       = *(const bf16x8*)&tile[cl][rg];
    *(bf16x8*)(dst + 8) = *(const bf16x8*)&tile[cl][rg + 8];
}

// ---------------------------------------------------------------------------
// K2a: Gu += ubfT_slice @ ubfT_slice^T  (MFMA NT, split-K over 9 slices)
// 64x64 tile, 4 waves (2x2, 32x32 each), BK=32, atomicAdd epilogue
// ---------------------------------------------------------------------------
__global__ __launch_bounds__(256) void k_gram_mfma(
        const __hip_bfloat16* __restrict__ uT,    // [RR][MM]
        float* __restrict__ G) {
    const int r0 = blockIdx.x * 64, r1 = blockIdx.y * 64;
    const int k0 = blockIdx.z * 512;
    __shared__ __align__(16) __hip_bfloat16 As[64 * 32];   // 4 KB
    __shared__ __align__(16) __hip_bfloat16 Bs[64 * 32];   // 4 KB
    const int t = threadIdx.x;
    const int w = t >> 6, l = t & 63;
    const int row = t >> 2, ls = t & 3;
    const int sg = ls ^ ((row >> 1) & 3);

    const char* sa = (const char*)(uT + (size_t)(r0 + row) * MM + k0) + sg * 16;
    const char* sb = (const char*)(uT + (size_t)(r1 + row) * MM + k0) + sg * 16;

    f32x4 acc[2][2];
    #pragma unroll
    for (int i = 0; i < 2; ++i)
        #pragma unroll
        for (int j = 0; j < 2; ++j) acc[i][j] = (f32x4){0.f, 0.f, 0.f, 0.f};

    for (int kt = 0; kt < 16; ++kt) {
        const int rb = kt * 64;
        gload_lds16(sa + rb, (char*)As + t * 16);
        gload_lds16(sb + rb, (char*)Bs + t * 16);
        __syncthreads();
        bf16x8 fa[2], fb[2];
        const int sl = (l >> 4) << 4;
        const int ar = (w >> 1) * 32 + (l & 15);
        const int br = (w & 1) * 32 + (l & 15);
        #pragma unroll
        for (int i = 0; i < 2; ++i) {
            int r = ar + i * 16;
            fa[i] = *(const bf16x8*)((const char*)As + r * 64 + (sl ^ (((r >> 1) & 3) << 4)));
            int q = br + i * 16;
            fb[i] = *(const bf16x8*)((const char*)Bs + q * 64 + (sl ^ (((q >> 1) & 3) << 4)));
        }
        #pragma unroll
        for (int i = 0; i < 2; ++i)
            #pragma unroll
            for (int j = 0; j < 2; ++j)
                acc[i][j] = __builtin_amdgcn_mfma_f32_16x16x32_bf16(fa[i], fb[j], acc[i][j], 0, 0, 0);
        __syncthreads();
    }
    #pragma unroll
    for (int i = 0; i < 2; ++i) {
        const int rA = r0 + (w >> 1) * 32 + i * 16 + (l >> 4) * 4;
        #pragma unroll
        for (int j = 0; j < 2; ++j) {
            const int rB = r1 + (w & 1) * 32 + j * 16 + (l & 15);
            #pragma unroll
            for (int rg = 0; rg < 4; ++rg)
                atomicAdd(&G[(size_t)(rA + rg) * RR + rB], acc[i][j][rg]);
        }
    }
}

// ---------------------------------------------------------------------------
// K2b: Gv += vh_slice vh_slice^T  (fp32 split-K over 8 slices of 64 cols)
// ---------------------------------------------------------------------------
__global__ __launch_bounds__(256) void k_gram_v(const float* __restrict__ vh,
                                                float* __restrict__ G) {
    const int r0 = blockIdx.x * 64, r1 = blockIdx.y * 64;
    const int n0base = blockIdx.z * 64;
    __shared__ float As[64][20], Bs[64][20];
    const int t = threadIdx.x, ty = t >> 4, tx = t & 15;
    const int lr = t >> 2, lk4 = (t & 3) * 4;
    float acc[4][4] = {};
    for (int c = 0; c < 4; ++c) {
        const int n0 = n0base + c * 16;
        float4 av = *(const float4*)&vh[(size_t)(r0 + lr) * COUT + n0 + lk4];
        float4 bv = *(const float4*)&vh[(size_t)(r1 + lr) * COUT + n0 + lk4];
        __syncthreads();
        *(float4*)&As[lr][lk4] = av;
        *(float4*)&Bs[lr][lk4] = bv;
        __syncthreads();
        #pragma unroll
        for (int k = 0; k < 16; ++k) {
            float a0 = As[ty*4+0][k], a1 = As[ty*4+1][k], a2 = As[ty*4+2][k], a3 = As[ty*4+3][k];
            float b0 = Bs[tx*4+0][k], b1 = Bs[tx*4+1][k], b2 = Bs[tx*4+2][k], b3 = Bs[tx*4+3][k];
            acc[0][0] += a0*b0; acc[0][1] += a0*b1; acc[0][2] += a0*b2; acc[0][3] += a0*b3;
            acc[1][0] += a1*b0; acc[1][1] += a1*b1; acc[1][2] += a1*b2; acc[1][3] += a1*b3;
            acc[2][0] += a2*b0; acc[2][1] += a2*b1; acc[2][2] += a2*b2; acc[2][3] += a2*b3;
            acc[3][0] += a3*b0; acc[3][1] += a3*b1; acc[3][2] += a3*b2; acc[3][3] += a3*b3;
        }
    }
    #pragma unroll
    for (int i = 0; i < 4; ++i)
        #pragma unroll
        for (int j = 0; j < 4; ++j)
            atomicAdd(&G[(size_t)(r0 + ty*4 + i) * RR + r1 + tx*4 + j], acc[i][j]);
}

// ---------------------------------------------------------------------------
// K3a: normsq[b] += slice-sum of ev_r ev_r' Gu[r,r'] Gv[r,r']
// ---------------------------------------------------------------------------
__global__ __launch_bounds__(256) void k_norm(const float* __restrict__ Gu,
                                              const float* __restrict__ Gv,
                                              const float* __restrict__ dd,
                                              const int* __restrict__ dirs,
                                              float* __restrict__ normsq) {
    const int b = blockIdx.x, sl = blockIdx.y;
    __shared__ float evs[RR];
    __shared__ float red[256];
    const int t = threadIdx.x;
    const float* ev = dd + (size_t)dirs[b] * RR;
    for (int i = t; i < RR; i += 256) evs[i] = ev[i];
    __syncthreads();
    float acc = 0.f;
    const int base = sl * (RR * RR / 8);
    for (int p = base + t; p < base + RR * RR / 8; p += 256) {
        int r = p >> 9, r2 = p & 511;
        acc += Gu[p] * Gv[p] * evs[r] * evs[r2];
    }
    red[t] = acc;
    __syncthreads();
    for (int o = 128; o > 0; o >>= 1) {
        if (t < o) red[t] += red[t + o];
        __syncthreads();
    }
    if (t == 0) atomicAdd(&normsq[b], red[0]);
}

// K3b: coef_b = shift_b / max(sqrt(normsq_b), 1e-12)
__global__ __launch_bounds__(64) void k_fin(const float* __restrict__ normsq,
                                            const float* __restrict__ shifts,
                                            float* __restrict__ coef) {
    int t = threadIdx.x;
    if (t < BB) coef[t] = shifts[t] / fmaxf(sqrtf(normsq[t]), 1e-12f);
}

// ---------------------------------------------------------------------------
// Prep B: vt[b][co][r] = bf16(ev_b[r] * vh[r][co])  (transpose + diag fold)
// ---------------------------------------------------------------------------
__global__ __launch_bounds__(256) void k_prep_vt(const float* __restrict__ vh,
                                                 const float* __restrict__ dd,
                                                 const int* __restrict__ dirs,
                                                 __hip_bfloat16* __restrict__ vt) {
    const int co0 = blockIdx.x * 64, r0 = blockIdx.y * 64, b = blockIdx.z;
    const float* ev = dd + (size_t)dirs[b] * RR;
    __shared__ __hip_bfloat16 tile[64][80];
    int t = threadIdx.x;
    int tc4 = (t & 15) * 4, tr = t >> 4;
    #pragma unroll
    for (int pass = 0; pass < 4; ++pass) {
        int r = tr + pass * 16;
        float e = ev[r0 + r];
        float4 v = *(const float4*)&vh[(size_t)(r0 + r) * COUT + co0 + tc4];
        tile[tc4+0][r] = __float2bfloat16(v.x * e);
        tile[tc4+1][r] = __float2bfloat16(v.y * e);
        tile[tc4+2][r] = __float2bfloat16(v.z * e);
        tile[tc4+3][r] = __float2bfloat16(v.w * e);
    }
    __syncthreads();
    int cl = t >> 2, rg = (t & 3) * 16;
    __hip_bfloat16* dst = vt + ((size_t)b * COUT + co0 + cl) * RR + r0 + rg;
    *(bf16x8*)dst       = *(const bf16x8*)&tile[cl][rg];
    *(bf16x8*)(dst + 8) = *(const bf16x8*)&tile[cl][rg + 8];
}

// ---------------------------------------------------------------------------
// Prep W: wgtb[co][kk][ci] = bf16(weight[co][ci][kk])
// ---------------------------------------------------------------------------
__global__ __launch_bounds__(256) void k_prep_w(const float* __restrict__ wgt,
                                                __hip_bfloat16* __restrict__ wgtb) {
    const int co = blockIdx.x;
    __shared__ float lw[MM];
    const int t = threadIdx.x;
    for (int e = t; e < MM; e += 256) lw[e] = wgt[(size_t)co * MM + e];
    __syncthreads();
    for (int e = t; e < MM; e += 256) {
        int kk = e >> 9, ci = e & 511;
        wgtb[(size_t)co * MM + e] = __float2bfloat16(lw[ci * KK + kk]);
    }
}

// ---------------------------------------------------------------------------
// K4: MFMA delta-GEMM + weight build + demod partials. 2-phase prefetch.
// 128(m) x 128(co) tile, BK=32, 4 waves, double-buffered LDS
// ---------------------------------------------------------------------------
__global__ __launch_bounds__(256) void k_build_mfma(
        const __hip_bfloat16* __restrict__ ubf,   // [MM][RR]
        const __hip_bfloat16* __restrict__ vt,    // [B][COUT][RR]
        const __hip_bfloat16* __restrict__ wgtb,  // [COUT][9][512] bf16
        const float* __restrict__ s,              // [B][CIN]
        const float* __restrict__ coef,
        __hip_bfloat16* __restrict__ Wf,          // [B][MT][COUT][32] swizzled
        float* __restrict__ demodsq) {
    const int m0  = blockIdx.x * 128;
    const int co0 = blockIdx.y * 128;
    const int b   = blockIdx.z;
    __shared__ __align__(16) __hip_bfloat16 As[2][128 * 32];   // 2x8 KB
    __shared__ __align__(16) __hip_bfloat16 Bs[2][128 * 32];   // 2x8 KB
    __shared__ float red[128];
    const int t = threadIdx.x;
    const int w = t >> 6, l = t & 63;
    const int row = t >> 2, ls = t & 3;
    const int sg  = ls ^ ((row >> 1) & 3);

    const char* ua  = (const char*)(ubf + (size_t)(m0 + row) * RR) + sg * 16;
    const char* ua2 = ua + (size_t)64 * RR * 2;
    const char* va  = (const char*)(vt + ((size_t)b * COUT + co0 + row) * RR) + sg * 16;
    const char* va2 = va + (size_t)64 * RR * 2;
    const int dst0 = t * 16;

    f32x4 acc[4][4];
    #pragma unroll
    for (int i = 0; i < 4; ++i)
        #pragma unroll
        for (int j = 0; j < 4; ++j) acc[i][j] = (f32x4){0.f, 0.f, 0.f, 0.f};

#define BSTAGE(buf, kt) { const int rb = (kt) * 64;                          \
    gload_lds16(ua  + rb, (char*)As[buf] + dst0);                            \
    gload_lds16(ua2 + rb, (char*)As[buf] + dst0 + 4096);                     \
    gload_lds16(va  + rb, (char*)Bs[buf] + dst0);                            \
    gload_lds16(va2 + rb, (char*)Bs[buf] + dst0 + 4096); }

#define BCOMPUTE(buf) {                                                      \
    bf16x8 fa[4], fb[4];                                                     \
    const int sl = (l >> 4) << 4;                                            \
    const int ar = (w >> 1) * 64 + (l & 15);                                 \
    const int br = (w & 1) * 64 + (l & 15);                                  \
    _Pragma("unroll") for (int i = 0; i < 4; ++i) {                          \
        int r = ar + i * 16;                                                 \
        fa[i] = *(const bf16x8*)((const char*)As[buf] + r * 64 + (sl ^ (((r >> 1) & 3) << 4))); \
        int q = br + i * 16;                                                 \
        fb[i] = *(const bf16x8*)((const char*)Bs[buf] + q * 64 + (sl ^ (((q >> 1) & 3) << 4))); } \
    _Pragma("unroll") for (int i = 0; i < 4; ++i)                            \
        _Pragma("unroll") for (int j = 0; j < 4; ++j)                        \
            acc[i][j] = __builtin_amdgcn_mfma_f32_16x16x32_bf16(fa[i], fb[j], acc[i][j], 0, 0, 0); }

    BSTAGE(0, 0);
    int cur = 0;
    for (int kt = 0; kt < 15; ++kt) {
        BSTAGE(cur ^ 1, kt + 1);
        asm volatile("s_waitcnt vmcnt(4)" ::: "memory");
        __builtin_amdgcn_s_barrier();
        __builtin_amdgcn_sched_barrier(0);
        BCOMPUTE(cur);
        __builtin_amdgcn_sched_barrier(0);
        __builtin_amdgcn_s_barrier();
        cur ^= 1;
    }
    asm volatile("s_waitcnt vmcnt(0)" ::: "memory");
    __builtin_amdgcn_s_barrier();
    __builtin_amdgcn_sched_barrier(0);
    BCOMPUTE(cur);

    // ---- epilogue
    __syncthreads();
    if (t < 128) red[t] = 0.f;
    __syncthreads();
    const float cf = coef[b];
    const int kkc = m0 >> 9;
    float partial[4] = {0.f, 0.f, 0.f, 0.f};
    #pragma unroll
    for (int i = 0; i < 4; ++i) {
        const int m_base = m0 + (w >> 1) * 64 + i * 16 + (l >> 4) * 4;
        const int ci = m_base & 511;
        const int mt = m_base >> 5, mk = m_base & 31;
        float4 sv = *(const float4*)&s[b * CIN + ci];
        #pragma unroll
        for (int j = 0; j < 4; ++j) {
            const int co = co0 + (w & 1) * 64 + j * 16 + (l & 15);
            ushort4 wv = *(const ushort4*)(wgtb + (size_t)co * MM + kkc * 512 + ci);
            float v0 = SCALE_F * (__bfloat162float(*(__hip_bfloat16*)&wv.x) + cf * acc[i][j][0]) * sv.x;
            float v1 = SCALE_F * (__bfloat162float(*(__hip_bfloat16*)&wv.y) + cf * acc[i][j][1]) * sv.y;
            float v2 = SCALE_F * (__bfloat162float(*(__hip_bfloat16*)&wv.z) + cf * acc[i][j][2]) * sv.z;
            float v3 = SCALE_F * (__bfloat162float(*(__hip_bfloat16*)&wv.w) + cf * acc[i][j][3]) * sv.w;
            __hip_bfloat16 vb[4] = {__float2bfloat16(v0), __float2bfloat16(v1),
                                    __float2bfloat16(v2), __float2bfloat16(v3)};
            const int swz = ((co >> 1) & 3) << 3;
            __hip_bfloat16* dst = Wf + (((size_t)b * MT + mt) * COUT + co) * 32 + (mk ^ swz);
            *(ushort4*)dst = *(const ushort4*)vb;
            partial[j] += v0*v0 + v1*v1 + v2*v2 + v3*v3;
        }
    }
    #pragma unroll
    for (int j = 0; j < 4; ++j)
        atomicAdd(&red[(w & 1) * 64 + j * 16 + (l & 15)], partial[j]);
    __syncthreads();
    if (t < 128) atomicAdd(&demodsq[b * COUT + co0 + t], red[t]);
}

// ---------------------------------------------------------------------------
// K_xpose: x [b][ci][y][x] fp32 -> xhwc [b][y+1][x+1][ci] bf16 (halo zeroed)
// ---------------------------------------------------------------------------
__global__ __launch_bounds__(256) void k_xpose(const float* __restrict__ x,
                                               __hip_bfloat16* __restrict__ xh) {
    const int b = blockIdx.x >> 5;
    const int y = blockIdx.x & 31;
    __shared__ __hip_bfloat16 tileT[32][72];
    const int t = threadIdx.x;
    for (int c0 = 0; c0 < CIN; c0 += 64) {
        int ci_l = t >> 2, xq = (t & 3) * 8;
        const float* src = x + (((size_t)(b * CIN + c0 + ci_l)) * HH + y) * WW + xq;
        float4 v0 = *(const float4*)src;
        float4 v1 = *(const float4*)(src + 4);
        __syncthreads();
        tileT[xq+0][ci_l] = __float2bfloat16(v0.x);
        tileT[xq+1][ci_l] = __float2bfloat16(v0.y);
        tileT[xq+2][ci_l] = __float2bfloat16(v0.z);
        tileT[xq+3][ci_l] = __float2bfloat16(v0.w);
        tileT[xq+4][ci_l] = __float2bfloat16(v1.x);
        tileT[xq+5][ci_l] = __float2bfloat16(v1.y);
        tileT[xq+6][ci_l] = __float2bfloat16(v1.z);
        tileT[xq+7][ci_l] = __float2bfloat16(v1.w);
        __syncthreads();
        int x_l = t >> 3, cg = (t & 7) * 8;
        bf16x8 o = *(const bf16x8*)&tileT[x_l][cg];
        *(bf16x8*)&xh[(((size_t)b * 34 + y + 1) * 34 + (x_l + 1)) * CIN + c0 + cg] = o;
    }
}

// ---------------------------------------------------------------------------
// K5: grouped conv as MFMA implicit GEMM. 2-phase prefetch + XCD swizzle.
// ---------------------------------------------------------------------------
__global__ __launch_bounds__(256) void k_conv_mfma(
        const __hip_bfloat16* __restrict__ Wf,     // [b][mt][co][32] swizzled
        const __hip_bfloat16* __restrict__ xh,     // [b][34][34][512]
        const float* __restrict__ demodsq,
        float* __restrict__ out) {
    // bijective XCD swizzle: 512 blocks = 8 XCDs x 64; same-XCD blocks sweep
    // all 8 p-tiles of one (co,b) Wf panel consecutively.
    const int id  = blockIdx.x;
    const int swb = (id & 7) * 64 + (id >> 3);
    const int p0  = (swb & 7) * 128;
    const int co0 = ((swb >> 3) & 3) * 128;
    const int b   = swb >> 5;
    __shared__ __align__(16) __hip_bfloat16 As[2][128 * 32];
    __shared__ __align__(16) __hip_bfloat16 Bs[2][128 * 32];
    const int t = threadIdx.x;
    const int w = t >> 6, l = t & 63;

    const char* wsrc0 = (const char*)(Wf + (((size_t)b * MT) * COUT + co0) * 32);
    const int lq = l >> 2;
    const int ls = l & 3;
    const int off0 = t * 16;

    f32x4 acc[4][4];
    #pragma unroll
    for (int i = 0; i < 4; ++i)
        #pragma unroll
        for (int j = 0; j < 4; ++j) acc[i][j] = (f32x4){0.f, 0.f, 0.f, 0.f};

#define CSTAGE(buf, mt) {                                                    \
    const char* wa_ = wsrc0 + (size_t)(mt) * (COUT * 32 * 2);                \
    gload_lds16(wa_ + off0,        (char*)As[buf] + off0);                   \
    gload_lds16(wa_ + off0 + 4096, (char*)As[buf] + off0 + 4096);            \
    const int kk_  = (mt) >> 4;                                              \
    const int ci0_ = ((mt) & 15) << 5;                                       \
    const int dy_  = kk_ / 3 - 1, dx_ = kk_ % 3 - 1;                         \
    _Pragma("unroll") for (int i_ = 0; i_ < 2; ++i_) {                       \
        int p_l_ = i_ * 64 + w * 16 + lq;                                    \
        int P_   = p0 + p_l_;                                                \
        int yy_  = (P_ >> 5) + dy_ + 1;                                      \
        int xx_  = (P_ & 31) + dx_ + 1;                                      \
        int sg_  = ls ^ ((p_l_ >> 1) & 3);                                   \
        const __hip_bfloat16* src_ =                                         \
            xh + (((size_t)b * 34 + yy_) * 34 + xx_) * CIN + ci0_ + sg_ * 8; \
        gload_lds16(src_, (char*)Bs[buf] + i_ * 4096 + w * 1024 + l * 16); } }

#define CCOMPUTE(buf) {                                                      \
    bf16x8 fa[4], fb[4];                                                     \
    const int sl = (l >> 4) << 4;                                            \
    const int ar = (w >> 1) * 64 + (l & 15);                                 \
    const int br = (w & 1) * 64 + (l & 15);                                  \
    _Pragma("unroll") for (int i = 0; i < 4; ++i) {                          \
        int r = ar + i * 16;                                                 \
        fa[i] = *(const bf16x8*)((const char*)As[buf] + r * 64 + (sl ^ (((r >> 1) & 3) << 4))); \
        int q = br + i * 16;                                                 \
        fb[i] = *(const bf16x8*)((const char*)Bs[buf] + q * 64 + (sl ^ (((q >> 1) & 3) << 4))); } \
    _Pragma("unroll") for (int i = 0; i < 4; ++i)                            \
        _Pragma("unroll") for (int j = 0; j < 4; ++j)                        \
            acc[i][j] = __builtin_amdgcn_mfma_f32_16x16x32_bf16(fa[i], fb[j], acc[i][j], 0, 0, 0); }

    CSTAGE(0, 0);
    int cur = 0;
    for (int mt = 0; mt < MT - 1; ++mt) {
        CSTAGE(cur ^ 1, mt + 1);
        asm volatile("s_waitcnt vmcnt(4)" ::: "memory");
        __builtin_amdgcn_s_barrier();
        __builtin_amdgcn_sched_barrier(0);
        CCOMPUTE(cur);
        __builtin_amdgcn_sched_barrier(0);
        __builtin_amdgcn_s_barrier();
        cur ^= 1;
    }
    asm volatile("s_waitcnt vmcnt(0)" ::: "memory");
    __builtin_amdgcn_s_barrier();
    __builtin_amdgcn_sched_barrier(0);
    CCOMPUTE(cur);

    const float* dmrow = demodsq + b * COUT;
    #pragma unroll
    for (int i = 0; i < 4; ++i) {
        int co = co0 + (w >> 1) * 64 + i * 16 + (l >> 4) * 4;
        #pragma unroll
        for (int r = 0; r < 4; ++r) {
            float dm = rsqrtf(dmrow[co + r] + 1e-8f);
            #pragma unroll
            for (int j = 0; j < 4; ++j) {
                int p = p0 + (w & 1) * 64 + j * 16 + (l & 15);
                out[((size_t)b * COUT + co + r) * HW + p] = acc[i][j][r] * dm;
            }
        }
    }
}

// ---------------------------------------------------------------------------
extern "C" void kernel_launch(void* const* d_in, const int* in_sizes, int n_in,
                              void* d_out, int out_size, void* d_ws, size_t ws_size,
                              hipStream_t stream) {
    const float* x         = (const float*)d_in[0];
    const float* style     = (const float*)d_in[1];
    const float* mw        = (const float*)d_in[2];
    const float* mb        = (const float*)d_in[3];
    const float* weight    = (const float*)d_in[4];
    const float* u         = (const float*)d_in[5];
    const float* vh        = (const float*)d_in[6];
    const float* dir_delta = (const float*)d_in[7];
    const float* shifts    = (const float*)d_in[8];
    const int*   dirs      = (const int*)d_in[9];
    float* out = (float*)d_out;

    // ---- compact workspace layout (high-water 94,568,448 B — round-4-proven)
    char* base = (char*)d_ws;
    float* s       = (float*)(base);                    // 32 KB
    float* coef    = (float*)(base + 32768);            // 64 B
    float* normsq  = (float*)(base + 32832);            // 64 B
    float* demodsq = (float*)(base + 33024);            // 32 KB
    // union region X @128KB (18,939,904 B):
    //  phase A: ubf@0 (4.72M) | ubfT@4.72M (4.72M) | Gu@9.44M (1M) | Gv@10.49M (1M)
    //  phase B: ubf@0         | vt@4.72M (8.39M)   | wgtb@13.11M (4.72M)
    //  phase C: xh@0 (18.94M)
    char* X = base + 131072;
    __hip_bfloat16* ubf  = (__hip_bfloat16*)(X);
    __hip_bfloat16* ubfT = (__hip_bfloat16*)(X + 4718592);
    float*          Gu   = (float*)(X + 9437184);
    float*          Gv   = (float*)(X + 10485760);
    __hip_bfloat16* vt   = (__hip_bfloat16*)(X + 4718592);
    __hip_bfloat16* wgtb = (__hip_bfloat16*)(X + 13107200);
    __hip_bfloat16* xh   = (__hip_bfloat16*)(X);
    __hip_bfloat16* Wf   = (__hip_bfloat16*)(X + 18939904);   // 75.5 MB

    hipMemsetAsync(demodsq, 0, BB * COUT * sizeof(float), stream);
    hipMemsetAsync(normsq, 0, BB * sizeof(float), stream);
    hipMemsetAsync(Gu, 0, 2097152, stream);              // Gu+Gv (atomic targets)
    k_mod       <<<dim3(32),         256, 0, stream>>>(style, mw, mb, s);
    k_prep_u    <<<dim3(1152),       256, 0, stream>>>(u, ubf);
    k_prep_uT   <<<dim3(72, 8),      256, 0, stream>>>(u, ubfT);
    k_gram_mfma <<<dim3(8, 8, 9),    256, 0, stream>>>(ubfT, Gu);
    k_gram_v    <<<dim3(8, 8, 8),    256, 0, stream>>>(vh, Gv);
    k_norm      <<<dim3(BB, 8),      256, 0, stream>>>(Gu, Gv, dir_delta, dirs, normsq);
    k_fin       <<<dim3(1),          64,  0, stream>>>(normsq, shifts, coef);
    // Gu/Gv/ubfT dead; vt+wgtb overwrite them
    k_prep_vt   <<<dim3(8, 8, BB),   256, 0, stream>>>(vh, dir_delta, dirs, vt);
    k_prep_w    <<<dim3(COUT),       256, 0, stream>>>(weight, wgtb);
    k_build_mfma<<<dim3(36, 4, BB),  256, 0, stream>>>(ubf, vt, wgtb, s, coef, Wf, demodsq);
    // ubf/vt/wgtb dead; xh overwrites region X
    hipMemsetAsync(xh, 0, (size_t)BB * 34 * 34 * CIN * sizeof(__hip_bfloat16), stream);
    k_xpose     <<<dim3(512),        256, 0, stream>>>(x, xh);
    k_conv_mfma <<<dim3(512),        256, 0, stream>>>(Wf, xh, demodsq, out);
}

// Round 7
// 295.426 us; speedup vs baseline: 10.9610x; 1.2668x over previous
//
#include <hip/hip_runtime.h>
#include <hip/hip_bf16.h>

// Problem constants
#define BB   16
#define CIN  512
#define COUT 512
#define KS   3
#define KK   9
#define HH   32
#define WW   32
#define HW   1024
#define SDIM 512
#define RR   512
#define MM   4608               // KK*CIN; m = kk*512 + ci
#define MT   144                // MM/32 k-tiles
#define SCALE_F 0.014731391274719738f  // 1/sqrt(4608)

typedef __attribute__((ext_vector_type(8))) short bf16x8;
typedef __attribute__((ext_vector_type(4))) float f32x4;

__device__ __forceinline__ void gload_lds16(const void* g, void* l) {
    __builtin_amdgcn_global_load_lds(
        (const __attribute__((address_space(1))) unsigned int*)g,
        (__attribute__((address_space(3))) unsigned int*)l,
        16, 0, 0);
}

#define PIPE_WAIT(N) do {                                            \
    asm volatile("s_waitcnt vmcnt(" #N ")" ::: "memory");            \
    __builtin_amdgcn_s_barrier();                                    \
    __builtin_amdgcn_sched_barrier(0); } while (0)
#define PIPE_END() do {                                              \
    __builtin_amdgcn_sched_barrier(0);                               \
    __builtin_amdgcn_s_barrier(); } while (0)

// ---------------------------------------------------------------------------
// K1: s[b,ci] = style[b,:] . modulation_w[ci,:] + modulation_b[ci]
// ---------------------------------------------------------------------------
__global__ __launch_bounds__(256) void k_mod(const float* __restrict__ style,
                                             const float* __restrict__ mw,
                                             const float* __restrict__ mb,
                                             float* __restrict__ s) {
    int idx = blockIdx.x * 256 + threadIdx.x;   // b*CIN + ci
    int b = idx >> 9, ci = idx & 511;
    const float* st = style + (size_t)b * SDIM;
    const float* w  = mw + (size_t)ci * SDIM;
    float acc = 0.f;
    for (int d = 0; d < SDIM; d += 4) {
        acc += st[d] * w[d] + st[d+1] * w[d+1] + st[d+2] * w[d+2] + st[d+3] * w[d+3];
    }
    s[idx] = acc + mb[ci];
}

// ---------------------------------------------------------------------------
// Prep (generic): out_bf16 = bf16(in_fp32), 2048 elements per block
// used for ubf (grid 1152) and vhb (grid 128)
// ---------------------------------------------------------------------------
__global__ __launch_bounds__(256) void k_prep_u(const float* __restrict__ u,
                                                __hip_bfloat16* __restrict__ ub) {
    size_t i = ((size_t)blockIdx.x * 256 + threadIdx.x) * 8;
    float4 a = *(const float4*)(u + i);
    float4 b = *(const float4*)(u + i + 4);
    __hip_bfloat16 o[8] = {
        __float2bfloat16(a.x), __float2bfloat16(a.y),
        __float2bfloat16(a.z), __float2bfloat16(a.w),
        __float2bfloat16(b.x), __float2bfloat16(b.y),
        __float2bfloat16(b.z), __float2bfloat16(b.w)};
    *(bf16x8*)(ub + i) = *(const bf16x8*)o;
}

// ---------------------------------------------------------------------------
// Prep A^T: ubfT[r][m] = bf16(u[m][r])  (for the Gram MFMA GEMM)
// ---------------------------------------------------------------------------
__global__ __launch_bounds__(256) void k_prep_uT(const float* __restrict__ u,
                                                 __hip_bfloat16* __restrict__ uT) {
    const int m0 = blockIdx.x * 64, r0 = blockIdx.y * 64;
    __shared__ __hip_bfloat16 tile[64][80];
    const int t = threadIdx.x;
    const int ml = t >> 4, rl4 = (t & 15) * 4;
    #pragma unroll
    for (int p = 0; p < 4; ++p) {
        int m_l = ml + p * 16;
        float4 v = *(const float4*)&u[(size_t)(m0 + m_l) * RR + r0 + rl4];
        tile[rl4+0][m_l] = __float2bfloat16(v.x);
        tile[rl4+1][m_l] = __float2bfloat16(v.y);
        tile[rl4+2][m_l] = __float2bfloat16(v.z);
        tile[rl4+3][m_l] = __float2bfloat16(v.w);
    }
    __syncthreads();
    const int cl = t >> 2, rg = (t & 3) * 16;
    __hip_bfloat16* dst = uT + (size_t)(r0 + cl) * MM + m0 + rg;
    *(bf16x8*)dst       = *(const bf16x8*)&tile[cl][rg];
    *(bf16x8*)(dst + 8) = *(const bf16x8*)&tile[cl][rg + 8];
}

// ---------------------------------------------------------------------------
// K2: merged Gram kernel. z<9: Gu += uT[:,z*512:+512] NT-GEMM slice.
//     z>=9: Gv += vhb[:,(z-9)*256:+256] slice.
// 64x64 tile, 4 waves (2x2 of 32x32), BK=32, 4-buffer pipeline, atomic epi.
// ---------------------------------------------------------------------------
__global__ __launch_bounds__(256) void k_gram2(
        const __hip_bfloat16* __restrict__ uT,    // [RR][MM]
        const __hip_bfloat16* __restrict__ vhb,   // [RR][COUT]
        float* __restrict__ Gu, float* __restrict__ Gv) {
    const int r0 = blockIdx.x * 64, r1 = blockIdx.y * 64;
    const int z  = blockIdx.z;
    const bool isGu = (z < 9);
    const __hip_bfloat16* src = isGu ? uT : vhb;
    const int ldb   = (isGu ? MM : COUT) * 2;          // row stride bytes
    const int koff  = isGu ? z * 1024 : (z - 9) * 512; // k offset bytes
    const int NT    = isGu ? 16 : 8;
    float* G = isGu ? Gu : Gv;

    __shared__ __align__(16) char gLDS[4 * 8192];      // 32 KB
    const int t = threadIdx.x;
    const int w = t >> 6, l = t & 63;
    const int row = t >> 2, ls = t & 3;
    const int sg = ls ^ ((row >> 1) & 3);

    const char* sa = (const char*)src + (size_t)(r0 + row) * ldb + koff + sg * 16;
    const char* sb = (const char*)src + (size_t)(r1 + row) * ldb + koff + sg * 16;

    f32x4 acc[2][2];
    #pragma unroll
    for (int i = 0; i < 2; ++i)
        #pragma unroll
        for (int j = 0; j < 2; ++j) acc[i][j] = (f32x4){0.f, 0.f, 0.f, 0.f};

#define GSTAGE(bn, kt) { char* Gb_ = gLDS + (bn) * 8192;                     \
    gload_lds16(sa + (kt) * 64, Gb_ + t * 16);                               \
    gload_lds16(sb + (kt) * 64, Gb_ + 4096 + t * 16); }

#define GCOMP(bn) { const char* Ab_ = gLDS + (bn) * 8192;                    \
    const char* Bb_ = Ab_ + 4096;                                            \
    bf16x8 fa[2], fb[2];                                                     \
    const int sl = (l >> 4) << 4;                                            \
    const int ar = (w >> 1) * 32 + (l & 15);                                 \
    const int br = (w & 1) * 32 + (l & 15);                                  \
    _Pragma("unroll") for (int i = 0; i < 2; ++i) {                          \
        int r = ar + i * 16;                                                 \
        fa[i] = *(const bf16x8*)(Ab_ + r * 64 + (sl ^ (((r >> 1) & 3) << 4))); \
        int q = br + i * 16;                                                 \
        fb[i] = *(const bf16x8*)(Bb_ + q * 64 + (sl ^ (((q >> 1) & 3) << 4))); } \
    _Pragma("unroll") for (int i = 0; i < 2; ++i)                            \
        _Pragma("unroll") for (int j = 0; j < 2; ++j)                        \
            acc[i][j] = __builtin_amdgcn_mfma_f32_16x16x32_bf16(fa[i], fb[j], acc[i][j], 0, 0, 0); }

    GSTAGE(0, 0); GSTAGE(1, 1); GSTAGE(2, 2);
    for (int kt = 0; kt < NT - 3; ++kt) {
        GSTAGE((kt + 3) & 3, kt + 3);
        PIPE_WAIT(6);
        GCOMP(kt & 3);
        PIPE_END();
    }
    PIPE_WAIT(4); GCOMP((NT - 3) & 3); PIPE_END();
    PIPE_WAIT(2); GCOMP((NT - 2) & 3); PIPE_END();
    PIPE_WAIT(0); GCOMP((NT - 1) & 3);

    #pragma unroll
    for (int i = 0; i < 2; ++i) {
        const int rA = r0 + (w >> 1) * 32 + i * 16 + (l >> 4) * 4;
        #pragma unroll
        for (int j = 0; j < 2; ++j) {
            const int rB = r1 + (w & 1) * 32 + j * 16 + (l & 15);
            #pragma unroll
            for (int rg = 0; rg < 4; ++rg)
                atomicAdd(&G[(size_t)(rA + rg) * RR + rB], acc[i][j][rg]);
        }
    }
}

// ---------------------------------------------------------------------------
// K3a: normsq[b] += slice-sum of ev_r ev_r' Gu[r,r'] Gv[r,r']
// ---------------------------------------------------------------------------
__global__ __launch_bounds__(256) void k_norm(const float* __restrict__ Gu,
                                              const float* __restrict__ Gv,
                                              const float* __restrict__ dd,
                                              const int* __restrict__ dirs,
                                              float* __restrict__ normsq) {
    const int b = blockIdx.x, sl = blockIdx.y;
    __shared__ float evs[RR];
    __shared__ float red[256];
    const int t = threadIdx.x;
    const float* ev = dd + (size_t)dirs[b] * RR;
    for (int i = t; i < RR; i += 256) evs[i] = ev[i];
    __syncthreads();
    float acc = 0.f;
    const int base = sl * (RR * RR / 8);
    for (int p = base + t; p < base + RR * RR / 8; p += 256) {
        int r = p >> 9, r2 = p & 511;
        acc += Gu[p] * Gv[p] * evs[r] * evs[r2];
    }
    red[t] = acc;
    __syncthreads();
    for (int o = 128; o > 0; o >>= 1) {
        if (t < o) red[t] += red[t + o];
        __syncthreads();
    }
    if (t == 0) atomicAdd(&normsq[b], red[0]);
}

// K3b: coef_b = shift_b / max(sqrt(normsq_b), 1e-12)
__global__ __launch_bounds__(64) void k_fin(const float* __restrict__ normsq,
                                            const float* __restrict__ shifts,
                                            float* __restrict__ coef) {
    int t = threadIdx.x;
    if (t < BB) coef[t] = shifts[t] / fmaxf(sqrtf(normsq[t]), 1e-12f);
}

// ---------------------------------------------------------------------------
// Prep B: vt[b][co][r] = bf16(ev_b[r] * vh[r][co])  (transpose + diag fold)
// ---------------------------------------------------------------------------
__global__ __launch_bounds__(256) void k_prep_vt(const float* __restrict__ vh,
                                                 const float* __restrict__ dd,
                                                 const int* __restrict__ dirs,
                                                 __hip_bfloat16* __restrict__ vt) {
    const int co0 = blockIdx.x * 64, r0 = blockIdx.y * 64, b = blockIdx.z;
    const float* ev = dd + (size_t)dirs[b] * RR;
    __shared__ __hip_bfloat16 tile[64][80];
    int t = threadIdx.x;
    int tc4 = (t & 15) * 4, tr = t >> 4;
    #pragma unroll
    for (int pass = 0; pass < 4; ++pass) {
        int r = tr + pass * 16;
        float e = ev[r0 + r];
        float4 v = *(const float4*)&vh[(size_t)(r0 + r) * COUT + co0 + tc4];
        tile[tc4+0][r] = __float2bfloat16(v.x * e);
        tile[tc4+1][r] = __float2bfloat16(v.y * e);
        tile[tc4+2][r] = __float2bfloat16(v.z * e);
        tile[tc4+3][r] = __float2bfloat16(v.w * e);
    }
    __syncthreads();
    int cl = t >> 2, rg = (t & 3) * 16;
    __hip_bfloat16* dst = vt + ((size_t)b * COUT + co0 + cl) * RR + r0 + rg;
    *(bf16x8*)dst       = *(const bf16x8*)&tile[cl][rg];
    *(bf16x8*)(dst + 8) = *(const bf16x8*)&tile[cl][rg + 8];
}

// ---------------------------------------------------------------------------
// Prep W: wgtb[co][kk][ci] = bf16(weight[co][ci][kk])
// ---------------------------------------------------------------------------
__global__ __launch_bounds__(256) void k_prep_w(const float* __restrict__ wgt,
                                                __hip_bfloat16* __restrict__ wgtb) {
    const int co = blockIdx.x;
    __shared__ float lw[MM];
    const int t = threadIdx.x;
    for (int e = t; e < MM; e += 256) lw[e] = wgt[(size_t)co * MM + e];
    __syncthreads();
    for (int e = t; e < MM; e += 256) {
        int kk = e >> 9, ci = e & 511;
        wgtb[(size_t)co * MM + e] = __float2bfloat16(lw[ci * KK + kk]);
    }
}

// ---------------------------------------------------------------------------
// K4: MFMA delta-GEMM + weight build + demod partials. 4-buffer pipeline.
// 128(m) x 128(co) tile, BK=32, 4 waves
// ---------------------------------------------------------------------------
__global__ __launch_bounds__(256) void k_build_mfma(
        const __hip_bfloat16* __restrict__ ubf,   // [MM][RR]
        const __hip_bfloat16* __restrict__ vt,    // [B][COUT][RR]
        const __hip_bfloat16* __restrict__ wgtb,  // [COUT][9][512] bf16
        const float* __restrict__ s,              // [B][CIN]
        const float* __restrict__ coef,
        __hip_bfloat16* __restrict__ Wf,          // [B][MT][COUT][32] swizzled
        float* __restrict__ demodsq) {
    const int m0  = blockIdx.x * 128;
    const int co0 = blockIdx.y * 128;
    const int b   = blockIdx.z;
    __shared__ __align__(16) char bLDS[4 * 16384];   // 64 KB: per buf A 8K | B 8K
    __shared__ float red[128];
    const int t = threadIdx.x;
    const int w = t >> 6, l = t & 63;
    const int row = t >> 2, ls = t & 3;
    const int sg  = ls ^ ((row >> 1) & 3);

    const char* ua  = (const char*)(ubf + (size_t)(m0 + row) * RR) + sg * 16;
    const char* ua2 = ua + (size_t)64 * RR * 2;
    const char* va  = (const char*)(vt + ((size_t)b * COUT + co0 + row) * RR) + sg * 16;
    const char* va2 = va + (size_t)64 * RR * 2;
    const int dst0 = t * 16;

    f32x4 acc[4][4];
    #pragma unroll
    for (int i = 0; i < 4; ++i)
        #pragma unroll
        for (int j = 0; j < 4; ++j) acc[i][j] = (f32x4){0.f, 0.f, 0.f, 0.f};

#define BSTAGE(bn, kt) { char* Ab_ = bLDS + (bn) * 16384;                    \
    const int rb = (kt) * 64;                                                \
    gload_lds16(ua  + rb, Ab_ + dst0);                                       \
    gload_lds16(ua2 + rb, Ab_ + dst0 + 4096);                                \
    gload_lds16(va  + rb, Ab_ + 8192 + dst0);                                \
    gload_lds16(va2 + rb, Ab_ + 8192 + dst0 + 4096); }

#define BCOMPUTE(bn) { const char* Ab_ = bLDS + (bn) * 16384;                \
    const char* Bb_ = Ab_ + 8192;                                            \
    bf16x8 fa[4], fb[4];                                                     \
    const int sl = (l >> 4) << 4;                                            \
    const int ar = (w >> 1) * 64 + (l & 15);                                 \
    const int br = (w & 1) * 64 + (l & 15);                                  \
    _Pragma("unroll") for (int i = 0; i < 4; ++i) {                          \
        int r = ar + i * 16;                                                 \
        fa[i] = *(const bf16x8*)(Ab_ + r * 64 + (sl ^ (((r >> 1) & 3) << 4))); \
        int q = br + i * 16;                                                 \
        fb[i] = *(const bf16x8*)(Bb_ + q * 64 + (sl ^ (((q >> 1) & 3) << 4))); } \
    _Pragma("unroll") for (int i = 0; i < 4; ++i)                            \
        _Pragma("unroll") for (int j = 0; j < 4; ++j)                        \
            acc[i][j] = __builtin_amdgcn_mfma_f32_16x16x32_bf16(fa[i], fb[j], acc[i][j], 0, 0, 0); }

    BSTAGE(0, 0); BSTAGE(1, 1); BSTAGE(2, 2);
    for (int kt = 0; kt < 13; ++kt) {
        BSTAGE((kt + 3) & 3, kt + 3);
        PIPE_WAIT(12);
        BCOMPUTE(kt & 3);
        PIPE_END();
    }
    PIPE_WAIT(8); BCOMPUTE(1); PIPE_END();   // kt=13
    PIPE_WAIT(4); BCOMPUTE(2); PIPE_END();   // kt=14
    PIPE_WAIT(0); BCOMPUTE(3);               // kt=15

    // ---- epilogue
    __syncthreads();
    if (t < 128) red[t] = 0.f;
    __syncthreads();
    const float cf = coef[b];
    const int kkc = m0 >> 9;
    float partial[4] = {0.f, 0.f, 0.f, 0.f};
    #pragma unroll
    for (int i = 0; i < 4; ++i) {
        const int m_base = m0 + (w >> 1) * 64 + i * 16 + (l >> 4) * 4;
        const int ci = m_base & 511;
        const int mt = m_base >> 5, mk = m_base & 31;
        float4 sv = *(const float4*)&s[b * CIN + ci];
        #pragma unroll
        for (int j = 0; j < 4; ++j) {
            const int co = co0 + (w & 1) * 64 + j * 16 + (l & 15);
            ushort4 wv = *(const ushort4*)(wgtb + (size_t)co * MM + kkc * 512 + ci);
            float v0 = SCALE_F * (__bfloat162float(*(__hip_bfloat16*)&wv.x) + cf * acc[i][j][0]) * sv.x;
            float v1 = SCALE_F * (__bfloat162float(*(__hip_bfloat16*)&wv.y) + cf * acc[i][j][1]) * sv.y;
            float v2 = SCALE_F * (__bfloat162float(*(__hip_bfloat16*)&wv.z) + cf * acc[i][j][2]) * sv.z;
            float v3 = SCALE_F * (__bfloat162float(*(__hip_bfloat16*)&wv.w) + cf * acc[i][j][3]) * sv.w;
            __hip_bfloat16 vb[4] = {__float2bfloat16(v0), __float2bfloat16(v1),
                                    __float2bfloat16(v2), __float2bfloat16(v3)};
            const int swz = ((co >> 1) & 3) << 3;
            __hip_bfloat16* dst = Wf + (((size_t)b * MT + mt) * COUT + co) * 32 + (mk ^ swz);
            *(ushort4*)dst = *(const ushort4*)vb;
            partial[j] += v0*v0 + v1*v1 + v2*v2 + v3*v3;
        }
    }
    #pragma unroll
    for (int j = 0; j < 4; ++j)
        atomicAdd(&red[(w & 1) * 64 + j * 16 + (l & 15)], partial[j]);
    __syncthreads();
    if (t < 128) atomicAdd(&demodsq[b * COUT + co0 + t], red[t]);
}

// ---------------------------------------------------------------------------
// K_xpose: x [b][ci][y][x] fp32 -> xhwc [b][y+1][x+1][ci] bf16 (halo zeroed)
// ---------------------------------------------------------------------------
__global__ __launch_bounds__(256) void k_xpose(const float* __restrict__ x,
                                               __hip_bfloat16* __restrict__ xh) {
    const int b = blockIdx.x >> 5;
    const int y = blockIdx.x & 31;
    __shared__ __hip_bfloat16 tileT[32][72];
    const int t = threadIdx.x;
    for (int c0 = 0; c0 < CIN; c0 += 64) {
        int ci_l = t >> 2, xq = (t & 3) * 8;
        const float* src = x + (((size_t)(b * CIN + c0 + ci_l)) * HH + y) * WW + xq;
        float4 v0 = *(const float4*)src;
        float4 v1 = *(const float4*)(src + 4);
        __syncthreads();
        tileT[xq+0][ci_l] = __float2bfloat16(v0.x);
        tileT[xq+1][ci_l] = __float2bfloat16(v0.y);
        tileT[xq+2][ci_l] = __float2bfloat16(v0.z);
        tileT[xq+3][ci_l] = __float2bfloat16(v0.w);
        tileT[xq+4][ci_l] = __float2bfloat16(v1.x);
        tileT[xq+5][ci_l] = __float2bfloat16(v1.y);
        tileT[xq+6][ci_l] = __float2bfloat16(v1.z);
        tileT[xq+7][ci_l] = __float2bfloat16(v1.w);
        __syncthreads();
        int x_l = t >> 3, cg = (t & 7) * 8;
        bf16x8 o = *(const bf16x8*)&tileT[x_l][cg];
        *(bf16x8*)&xh[(((size_t)b * 34 + y + 1) * 34 + (x_l + 1)) * CIN + c0 + cg] = o;
    }
}

// ---------------------------------------------------------------------------
// K5: grouped conv as MFMA implicit GEMM. 4-buffer pipeline + XCD swizzle.
// ---------------------------------------------------------------------------
__global__ __launch_bounds__(256) void k_conv_mfma(
        const __hip_bfloat16* __restrict__ Wf,     // [b][mt][co][32] swizzled
        const __hip_bfloat16* __restrict__ xh,     // [b][34][34][512]
        const float* __restrict__ demodsq,
        float* __restrict__ out) {
    const int id  = blockIdx.x;
    const int swb = (id & 7) * 64 + (id >> 3);
    const int p0  = (swb & 7) * 128;
    const int co0 = ((swb >> 3) & 3) * 128;
    const int b   = swb >> 5;
    __shared__ __align__(16) char cLDS[4 * 16384];   // 64 KB
    const int t = threadIdx.x;
    const int w = t >> 6, l = t & 63;

    const char* wsrc0 = (const char*)(Wf + (((size_t)b * MT) * COUT + co0) * 32);
    const int lq = l >> 2;
    const int ls = l & 3;
    const int off0 = t * 16;

    f32x4 acc[4][4];
    #pragma unroll
    for (int i = 0; i < 4; ++i)
        #pragma unroll
        for (int j = 0; j < 4; ++j) acc[i][j] = (f32x4){0.f, 0.f, 0.f, 0.f};

#define CSTAGE(bn, mt) { char* Ab_ = cLDS + (bn) * 16384;                    \
    const char* wa_ = wsrc0 + (size_t)(mt) * (COUT * 32 * 2);                \
    gload_lds16(wa_ + off0,        Ab_ + off0);                              \
    gload_lds16(wa_ + off0 + 4096, Ab_ + off0 + 4096);                       \
    const int kk_  = (mt) >> 4;                                              \
    const int ci0_ = ((mt) & 15) << 5;                                       \
    const int dy_  = kk_ / 3 - 1, dx_ = kk_ % 3 - 1;                         \
    _Pragma("unroll") for (int i_ = 0; i_ < 2; ++i_) {                       \
        int p_l_ = i_ * 64 + w * 16 + lq;                                    \
        int P_   = p0 + p_l_;                                                \
        int yy_  = (P_ >> 5) + dy_ + 1;                                      \
        int xx_  = (P_ & 31) + dx_ + 1;                                      \
        int sg_  = ls ^ ((p_l_ >> 1) & 3);                                   \
        const __hip_bfloat16* src_ =                                         \
            xh + (((size_t)b * 34 + yy_) * 34 + xx_) * CIN + ci0_ + sg_ * 8; \
        gload_lds16(src_, Ab_ + 8192 + i_ * 4096 + w * 1024 + l * 16); } }

#define CCOMPUTE(bn) { const char* Ab_ = cLDS + (bn) * 16384;                \
    const char* Bb_ = Ab_ + 8192;                                            \
    bf16x8 fa[4], fb[4];                                                     \
    const int sl = (l >> 4) << 4;                                            \
    const int ar = (w >> 1) * 64 + (l & 15);                                 \
    const int br = (w & 1) * 64 + (l & 15);                                  \
    _Pragma("unroll") for (int i = 0; i < 4; ++i) {                          \
        int r = ar + i * 16;                                                 \
        fa[i] = *(const bf16x8*)(Ab_ + r * 64 + (sl ^ (((r >> 1) & 3) << 4))); \
        int q = br + i * 16;                                                 \
        fb[i] = *(const bf16x8*)(Bb_ + q * 64 + (sl ^ (((q >> 1) & 3) << 4))); } \
    _Pragma("unroll") for (int i = 0; i < 4; ++i)                            \
        _Pragma("unroll") for (int j = 0; j < 4; ++j)                        \
            acc[i][j] = __builtin_amdgcn_mfma_f32_16x16x32_bf16(fa[i], fb[j], acc[i][j], 0, 0, 0); }

    CSTAGE(0, 0); CSTAGE(1, 1); CSTAGE(2, 2);
    for (int mt = 0; mt < MT - 3; ++mt) {
        CSTAGE((mt + 3) & 3, mt + 3);
        PIPE_WAIT(12);
        CCOMPUTE(mt & 3);
        PIPE_END();
    }
    PIPE_WAIT(8); CCOMPUTE((MT - 3) & 3); PIPE_END();
    PIPE_WAIT(4); CCOMPUTE((MT - 2) & 3); PIPE_END();
    PIPE_WAIT(0); CCOMPUTE((MT - 1) & 3);

    const float* dmrow = demodsq + b * COUT;
    #pragma unroll
    for (int i = 0; i < 4; ++i) {
        int co = co0 + (w >> 1) * 64 + i * 16 + (l >> 4) * 4;
        #pragma unroll
        for (int r = 0; r < 4; ++r) {
            float dm = rsqrtf(dmrow[co + r] + 1e-8f);
            #pragma unroll
            for (int j = 0; j < 4; ++j) {
                int p = p0 + (w & 1) * 64 + j * 16 + (l & 15);
                out[((size_t)b * COUT + co + r) * HW + p] = acc[i][j][r] * dm;
            }
        }
    }
}

// ---------------------------------------------------------------------------
extern "C" void kernel_launch(void* const* d_in, const int* in_sizes, int n_in,
                              void* d_out, int out_size, void* d_ws, size_t ws_size,
                              hipStream_t stream) {
    const float* x         = (const float*)d_in[0];
    const float* style     = (const float*)d_in[1];
    const float* mw        = (const float*)d_in[2];
    const float* mb        = (const float*)d_in[3];
    const float* weight    = (const float*)d_in[4];
    const float* u         = (const float*)d_in[5];
    const float* vh        = (const float*)d_in[6];
    const float* dir_delta = (const float*)d_in[7];
    const float* shifts    = (const float*)d_in[8];
    const int*   dirs      = (const int*)d_in[9];
    float* out = (float*)d_out;

    // ---- compact workspace layout (high-water 94,568,448 B — round-4-proven)
    char* base = (char*)d_ws;
    float* s       = (float*)(base);                    // 32 KB
    float* coef    = (float*)(base + 32768);            // 64 B
    float* normsq  = (float*)(base + 32832);            // 64 B
    float* demodsq = (float*)(base + 33024);            // 32 KB
    // union region X @128KB (18,939,904 B):
    //  phase A: ubf@0 (4.72M) | ubfT@4.72M (4.72M) | Gu@9.44M (1M) | Gv@10.49M (1M) | vhb@11.53M (0.5M)
    //  phase B: ubf@0         | vt@4.72M (8.39M)   | wgtb@13.11M (4.72M)
    //  phase C: xh@0 (18.94M)
    char* X = base + 131072;
    __hip_bfloat16* ubf  = (__hip_bfloat16*)(X);
    __hip_bfloat16* ubfT = (__hip_bfloat16*)(X + 4718592);
    float*          Gu   = (float*)(X + 9437184);
    float*          Gv   = (float*)(X + 10485760);
    __hip_bfloat16* vhb  = (__hip_bfloat16*)(X + 11534336);
    __hip_bfloat16* vt   = (__hip_bfloat16*)(X + 4718592);
    __hip_bfloat16* wgtb = (__hip_bfloat16*)(X + 13107200);
    __hip_bfloat16* xh   = (__hip_bfloat16*)(X);
    __hip_bfloat16* Wf   = (__hip_bfloat16*)(X + 18939904);   // 75.5 MB

    hipMemsetAsync(demodsq, 0, BB * COUT * sizeof(float), stream);
    hipMemsetAsync(normsq, 0, BB * sizeof(float), stream);
    hipMemsetAsync(Gu, 0, 2097152, stream);              // Gu+Gv (atomic targets)
    k_mod       <<<dim3(32),         256, 0, stream>>>(style, mw, mb, s);
    k_prep_u    <<<dim3(1152),       256, 0, stream>>>(u, ubf);
    k_prep_uT   <<<dim3(72, 8),      256, 0, stream>>>(u, ubfT);
    k_prep_u    <<<dim3(128),        256, 0, stream>>>(vh, vhb);
    k_gram2     <<<dim3(8, 8, 11),   256, 0, stream>>>(ubfT, vhb, Gu, Gv);
    k_norm      <<<dim3(BB, 8),      256, 0, stream>>>(Gu, Gv, dir_delta, dirs, normsq);
    k_fin       <<<dim3(1),          64,  0, stream>>>(normsq, shifts, coef);
    // Gu/Gv/ubfT/vhb dead; vt+wgtb overwrite them
    k_prep_vt   <<<dim3(8, 8, BB),   256, 0, stream>>>(vh, dir_delta, dirs, vt);
    k_prep_w    <<<dim3(COUT),       256, 0, stream>>>(weight, wgtb);
    k_build_mfma<<<dim3(36, 4, BB),  256, 0, stream>>>(ubf, vt, wgtb, s, coef, Wf, demodsq);
    // ubf/vt/wgtb dead; xh overwrites region X
    hipMemsetAsync(xh, 0, (size_t)BB * 34 * 34 * CIN * sizeof(__hip_bfloat16), stream);
    k_xpose     <<<dim3(512),        256, 0, stream>>>(x, xh);
    k_conv_mfma <<<dim3(512),        256, 0, stream>>>(Wf, xh, demodsq, out);
}

// Round 8
// 293.775 us; speedup vs baseline: 11.0226x; 1.0056x over previous
//
#include <hip/hip_runtime.h>
#include <hip/hip_bf16.h>

// Problem constants
#define BB   16
#define CIN  512
#define COUT 512
#define KS   3
#define KK   9
#define HH   32
#define WW   32
#define HW   1024
#define SDIM 512
#define RR   512
#define MM   4608               // KK*CIN; m = kk*512 + ci
#define MT   144                // MM/32 k-tiles
#define SCALE_F 0.014731391274719738f  // 1/sqrt(4608)

typedef __attribute__((ext_vector_type(8))) short bf16x8;
typedef __attribute__((ext_vector_type(4))) float f32x4;

__device__ __forceinline__ void gload_lds16(const void* g, void* l) {
    __builtin_amdgcn_global_load_lds(
        (const __attribute__((address_space(1))) unsigned int*)g,
        (__attribute__((address_space(3))) unsigned int*)l,
        16, 0, 0);
}

#define PIPE_WAIT(N) do {                                            \
    asm volatile("s_waitcnt vmcnt(" #N ")" ::: "memory");            \
    __builtin_amdgcn_s_barrier();                                    \
    __builtin_amdgcn_sched_barrier(0); } while (0)
#define PIPE_END() do {                                              \
    __builtin_amdgcn_sched_barrier(0);                               \
    __builtin_amdgcn_s_barrier(); } while (0)

// ---------------------------------------------------------------------------
// K1: s[b,ci] = style[b,:] . modulation_w[ci,:] + modulation_b[ci]
// ---------------------------------------------------------------------------
__global__ __launch_bounds__(256) void k_mod(const float* __restrict__ style,
                                             const float* __restrict__ mw,
                                             const float* __restrict__ mb,
                                             float* __restrict__ s) {
    int idx = blockIdx.x * 256 + threadIdx.x;   // b*CIN + ci
    int b = idx >> 9, ci = idx & 511;
    const float* st = style + (size_t)b * SDIM;
    const float* w  = mw + (size_t)ci * SDIM;
    float acc = 0.f;
    for (int d = 0; d < SDIM; d += 4) {
        acc += st[d] * w[d] + st[d+1] * w[d+1] + st[d+2] * w[d+2] + st[d+3] * w[d+3];
    }
    s[idx] = acc + mb[ci];
}

// ---------------------------------------------------------------------------
// Generic cast: out_bf16 = bf16(in_fp32), 2048 elems/block (used for vhb)
// ---------------------------------------------------------------------------
__global__ __launch_bounds__(256) void k_cast(const float* __restrict__ u,
                                              __hip_bfloat16* __restrict__ ub) {
    size_t i = ((size_t)blockIdx.x * 256 + threadIdx.x) * 8;
    float4 a = *(const float4*)(u + i);
    float4 b = *(const float4*)(u + i + 4);
    __hip_bfloat16 o[8] = {
        __float2bfloat16(a.x), __float2bfloat16(a.y),
        __float2bfloat16(a.z), __float2bfloat16(a.w),
        __float2bfloat16(b.x), __float2bfloat16(b.y),
        __float2bfloat16(b.z), __float2bfloat16(b.w)};
    *(bf16x8*)(ub + i) = *(const bf16x8*)o;
}

// ---------------------------------------------------------------------------
// Prep U (fused): ubf[m][r] = bf16(u[m][r]) AND ubfT[r][m] = bf16(u[m][r])
// grid (72 m-tiles, 8 r-tiles), one read of u
// ---------------------------------------------------------------------------
__global__ __launch_bounds__(256) void k_prep_u2(const float* __restrict__ u,
                                                 __hip_bfloat16* __restrict__ ub,
                                                 __hip_bfloat16* __restrict__ uT) {
    const int m0 = blockIdx.x * 64, r0 = blockIdx.y * 64;
    __shared__ __hip_bfloat16 tile[64][80];   // [r_local][m_local]
    const int t = threadIdx.x;
    const int ml = t >> 4, rl4 = (t & 15) * 4;
    #pragma unroll
    for (int p = 0; p < 4; ++p) {
        int m_l = ml + p * 16;
        float4 v = *(const float4*)&u[(size_t)(m0 + m_l) * RR + r0 + rl4];
        __hip_bfloat16 b4[4] = {__float2bfloat16(v.x), __float2bfloat16(v.y),
                                __float2bfloat16(v.z), __float2bfloat16(v.w)};
        *(ushort4*)&ub[(size_t)(m0 + m_l) * RR + r0 + rl4] = *(const ushort4*)b4;
        tile[rl4+0][m_l] = b4[0];
        tile[rl4+1][m_l] = b4[1];
        tile[rl4+2][m_l] = b4[2];
        tile[rl4+3][m_l] = b4[3];
    }
    __syncthreads();
    const int cl = t >> 2, rg = (t & 3) * 16;
    __hip_bfloat16* dst = uT + (size_t)(r0 + cl) * MM + m0 + rg;
    *(bf16x8*)dst       = *(const bf16x8*)&tile[cl][rg];
    *(bf16x8*)(dst + 8) = *(const bf16x8*)&tile[cl][rg + 8];
}

// ---------------------------------------------------------------------------
// K2: merged Gram kernel. z<9: Gu += uT[:,z*512:+512] NT-GEMM slice.
//     z>=9: Gv += vhb[:,(z-9)*256:+256] slice.
// 64x64 tile, 4 waves (2x2 of 32x32), BK=32, 4-buffer pipeline, atomic epi.
// ---------------------------------------------------------------------------
__global__ __launch_bounds__(256) void k_gram2(
        const __hip_bfloat16* __restrict__ uT,    // [RR][MM]
        const __hip_bfloat16* __restrict__ vhb,   // [RR][COUT]
        float* __restrict__ Gu, float* __restrict__ Gv) {
    const int r0 = blockIdx.x * 64, r1 = blockIdx.y * 64;
    const int z  = blockIdx.z;
    const bool isGu = (z < 9);
    const __hip_bfloat16* src = isGu ? uT : vhb;
    const int ldb   = (isGu ? MM : COUT) * 2;          // row stride bytes
    const int koff  = isGu ? z * 1024 : (z - 9) * 512; // k offset bytes
    const int NT    = isGu ? 16 : 8;
    float* G = isGu ? Gu : Gv;

    __shared__ __align__(16) char gLDS[4 * 8192];      // 32 KB
    const int t = threadIdx.x;
    const int w = t >> 6, l = t & 63;
    const int row = t >> 2, ls = t & 3;
    const int sg = ls ^ ((row >> 1) & 3);

    const char* sa = (const char*)src + (size_t)(r0 + row) * ldb + koff + sg * 16;
    const char* sb = (const char*)src + (size_t)(r1 + row) * ldb + koff + sg * 16;

    f32x4 acc[2][2];
    #pragma unroll
    for (int i = 0; i < 2; ++i)
        #pragma unroll
        for (int j = 0; j < 2; ++j) acc[i][j] = (f32x4){0.f, 0.f, 0.f, 0.f};

#define GSTAGE(bn, kt) { char* Gb_ = gLDS + (bn) * 8192;                     \
    gload_lds16(sa + (kt) * 64, Gb_ + t * 16);                               \
    gload_lds16(sb + (kt) * 64, Gb_ + 4096 + t * 16); }

#define GCOMP(bn) { const char* Ab_ = gLDS + (bn) * 8192;                    \
    const char* Bb_ = Ab_ + 4096;                                            \
    bf16x8 fa[2], fb[2];                                                     \
    const int sl = (l >> 4) << 4;                                            \
    const int ar = (w >> 1) * 32 + (l & 15);                                 \
    const int br = (w & 1) * 32 + (l & 15);                                  \
    _Pragma("unroll") for (int i = 0; i < 2; ++i) {                          \
        int r = ar + i * 16;                                                 \
        fa[i] = *(const bf16x8*)(Ab_ + r * 64 + (sl ^ (((r >> 1) & 3) << 4))); \
        int q = br + i * 16;                                                 \
        fb[i] = *(const bf16x8*)(Bb_ + q * 64 + (sl ^ (((q >> 1) & 3) << 4))); } \
    __builtin_amdgcn_s_setprio(1);                                           \
    _Pragma("unroll") for (int i = 0; i < 2; ++i)                            \
        _Pragma("unroll") for (int j = 0; j < 2; ++j)                        \
            acc[i][j] = __builtin_amdgcn_mfma_f32_16x16x32_bf16(fa[i], fb[j], acc[i][j], 0, 0, 0); \
    __builtin_amdgcn_s_setprio(0); }

    GSTAGE(0, 0); GSTAGE(1, 1); GSTAGE(2, 2);
    for (int kt = 0; kt < NT - 3; ++kt) {
        GSTAGE((kt + 3) & 3, kt + 3);
        PIPE_WAIT(6);
        GCOMP(kt & 3);
        PIPE_END();
    }
    PIPE_WAIT(4); GCOMP((NT - 3) & 3); PIPE_END();
    PIPE_WAIT(2); GCOMP((NT - 2) & 3); PIPE_END();
    PIPE_WAIT(0); GCOMP((NT - 1) & 3);

    #pragma unroll
    for (int i = 0; i < 2; ++i) {
        const int rA = r0 + (w >> 1) * 32 + i * 16 + (l >> 4) * 4;
        #pragma unroll
        for (int j = 0; j < 2; ++j) {
            const int rB = r1 + (w & 1) * 32 + j * 16 + (l & 15);
            #pragma unroll
            for (int rg = 0; rg < 4; ++rg)
                atomicAdd(&G[(size_t)(rA + rg) * RR + rB], acc[i][j][rg]);
        }
    }
}

// ---------------------------------------------------------------------------
// K3a: normsq[b] += slice-sum of ev_r ev_r' Gu[r,r'] Gv[r,r']
// ---------------------------------------------------------------------------
__global__ __launch_bounds__(256) void k_norm(const float* __restrict__ Gu,
                                              const float* __restrict__ Gv,
                                              const float* __restrict__ dd,
                                              const int* __restrict__ dirs,
                                              float* __restrict__ normsq) {
    const int b = blockIdx.x, sl = blockIdx.y;
    __shared__ float evs[RR];
    __shared__ float red[256];
    const int t = threadIdx.x;
    const float* ev = dd + (size_t)dirs[b] * RR;
    for (int i = t; i < RR; i += 256) evs[i] = ev[i];
    __syncthreads();
    float acc = 0.f;
    const int base = sl * (RR * RR / 8);
    for (int p = base + t; p < base + RR * RR / 8; p += 256) {
        int r = p >> 9, r2 = p & 511;
        acc += Gu[p] * Gv[p] * evs[r] * evs[r2];
    }
    red[t] = acc;
    __syncthreads();
    for (int o = 128; o > 0; o >>= 1) {
        if (t < o) red[t] += red[t + o];
        __syncthreads();
    }
    if (t == 0) atomicAdd(&normsq[b], red[0]);
}

// K3b: coef_b = shift_b / max(sqrt(normsq_b), 1e-12)
__global__ __launch_bounds__(64) void k_fin(const float* __restrict__ normsq,
                                            const float* __restrict__ shifts,
                                            float* __restrict__ coef) {
    int t = threadIdx.x;
    if (t < BB) coef[t] = shifts[t] / fmaxf(sqrtf(normsq[t]), 1e-12f);
}

// ---------------------------------------------------------------------------
// Prep B: vt[b][co][r] = bf16(ev_b[r] * vh[r][co])  (transpose + diag fold)
// ---------------------------------------------------------------------------
__global__ __launch_bounds__(256) void k_prep_vt(const float* __restrict__ vh,
                                                 const float* __restrict__ dd,
                                                 const int* __restrict__ dirs,
                                                 __hip_bfloat16* __restrict__ vt) {
    const int co0 = blockIdx.x * 64, r0 = blockIdx.y * 64, b = blockIdx.z;
    const float* ev = dd + (size_t)dirs[b] * RR;
    __shared__ __hip_bfloat16 tile[64][80];
    int t = threadIdx.x;
    int tc4 = (t & 15) * 4, tr = t >> 4;
    #pragma unroll
    for (int pass = 0; pass < 4; ++pass) {
        int r = tr + pass * 16;
        float e = ev[r0 + r];
        float4 v = *(const float4*)&vh[(size_t)(r0 + r) * COUT + co0 + tc4];
        tile[tc4+0][r] = __float2bfloat16(v.x * e);
        tile[tc4+1][r] = __float2bfloat16(v.y * e);
        tile[tc4+2][r] = __float2bfloat16(v.z * e);
        tile[tc4+3][r] = __float2bfloat16(v.w * e);
    }
    __syncthreads();
    int cl = t >> 2, rg = (t & 3) * 16;
    __hip_bfloat16* dst = vt + ((size_t)b * COUT + co0 + cl) * RR + r0 + rg;
    *(bf16x8*)dst       = *(const bf16x8*)&tile[cl][rg];
    *(bf16x8*)(dst + 8) = *(const bf16x8*)&tile[cl][rg + 8];
}

// ---------------------------------------------------------------------------
// Prep W: wgtb[co][kk][ci] = bf16(weight[co][ci][kk])
// ---------------------------------------------------------------------------
__global__ __launch_bounds__(256) void k_prep_w(const float* __restrict__ wgt,
                                                __hip_bfloat16* __restrict__ wgtb) {
    const int co = blockIdx.x;
    __shared__ float lw[MM];
    const int t = threadIdx.x;
    for (int e = t; e < MM; e += 256) lw[e] = wgt[(size_t)co * MM + e];
    __syncthreads();
    for (int e = t; e < MM; e += 256) {
        int kk = e >> 9, ci = e & 511;
        wgtb[(size_t)co * MM + e] = __float2bfloat16(lw[ci * KK + kk]);
    }
}

// ---------------------------------------------------------------------------
// K4: MFMA delta-GEMM + weight build + demod partials.
// 3-buffer ring (48 KB LDS -> 3 blocks/CU), vmcnt(8), setprio.
// ---------------------------------------------------------------------------
__global__ __launch_bounds__(256) void k_build_mfma(
        const __hip_bfloat16* __restrict__ ubf,   // [MM][RR]
        const __hip_bfloat16* __restrict__ vt,    // [B][COUT][RR]
        const __hip_bfloat16* __restrict__ wgtb,  // [COUT][9][512] bf16
        const float* __restrict__ s,              // [B][CIN]
        const float* __restrict__ coef,
        __hip_bfloat16* __restrict__ Wf,          // [B][MT][COUT][32] swizzled
        float* __restrict__ demodsq) {
    const int m0  = blockIdx.x * 128;
    const int co0 = blockIdx.y * 128;
    const int b   = blockIdx.z;
    __shared__ __align__(16) char bLDS[3 * 16384];   // 48 KB: per buf A 8K | B 8K
    __shared__ float red[128];
    const int t = threadIdx.x;
    const int w = t >> 6, l = t & 63;
    const int row = t >> 2, ls = t & 3;
    const int sg  = ls ^ ((row >> 1) & 3);

    const char* ua  = (const char*)(ubf + (size_t)(m0 + row) * RR) + sg * 16;
    const char* ua2 = ua + (size_t)64 * RR * 2;
    const char* va  = (const char*)(vt + ((size_t)b * COUT + co0 + row) * RR) + sg * 16;
    const char* va2 = va + (size_t)64 * RR * 2;
    const int dst0 = t * 16;

    f32x4 acc[4][4];
    #pragma unroll
    for (int i = 0; i < 4; ++i)
        #pragma unroll
        for (int j = 0; j < 4; ++j) acc[i][j] = (f32x4){0.f, 0.f, 0.f, 0.f};

#define BSTAGE(Ab_, kt) { const int rb = (kt) * 64;                          \
    gload_lds16(ua  + rb, (Ab_) + dst0);                                     \
    gload_lds16(ua2 + rb, (Ab_) + dst0 + 4096);                              \
    gload_lds16(va  + rb, (Ab_) + 8192 + dst0);                              \
    gload_lds16(va2 + rb, (Ab_) + 8192 + dst0 + 4096); }

#define BCOMPUTE(Ab_) { const char* Bb_ = (Ab_) + 8192;                      \
    bf16x8 fa[4], fb[4];                                                     \
    const int sl = (l >> 4) << 4;                                            \
    const int ar = (w >> 1) * 64 + (l & 15);                                 \
    const int br = (w & 1) * 64 + (l & 15);                                  \
    _Pragma("unroll") for (int i = 0; i < 4; ++i) {                          \
        int r = ar + i * 16;                                                 \
        fa[i] = *(const bf16x8*)((Ab_) + r * 64 + (sl ^ (((r >> 1) & 3) << 4))); \
        int q = br + i * 16;                                                 \
        fb[i] = *(const bf16x8*)(Bb_ + q * 64 + (sl ^ (((q >> 1) & 3) << 4))); } \
    __builtin_amdgcn_s_setprio(1);                                           \
    _Pragma("unroll") for (int i = 0; i < 4; ++i)                            \
        _Pragma("unroll") for (int j = 0; j < 4; ++j)                        \
            acc[i][j] = __builtin_amdgcn_mfma_f32_16x16x32_bf16(fa[i], fb[j], acc[i][j], 0, 0, 0); \
    __builtin_amdgcn_s_setprio(0); }

    char* cbuf = bLDS;               // compute buffer (kt)
    char* nbuf = bLDS + 16384;       // next (kt+1)
    char* sbuf = bLDS + 32768;       // stage target (kt+2)
    BSTAGE(cbuf, 0); BSTAGE(nbuf, 1);
    for (int kt = 0; kt < 14; ++kt) {
        BSTAGE(sbuf, kt + 2);
        PIPE_WAIT(8);
        BCOMPUTE(cbuf);
        PIPE_END();
        char* tmp = cbuf; cbuf = nbuf; nbuf = sbuf; sbuf = tmp;
    }
    PIPE_WAIT(4); BCOMPUTE(cbuf); PIPE_END();   // kt=14
    PIPE_WAIT(0); BCOMPUTE(nbuf);               // kt=15

    // ---- epilogue
    __syncthreads();
    if (t < 128) red[t] = 0.f;
    __syncthreads();
    const float cf = coef[b];
    const int kkc = m0 >> 9;
    float partial[4] = {0.f, 0.f, 0.f, 0.f};
    #pragma unroll
    for (int i = 0; i < 4; ++i) {
        const int m_base = m0 + (w >> 1) * 64 + i * 16 + (l >> 4) * 4;
        const int ci = m_base & 511;
        const int mt = m_base >> 5, mk = m_base & 31;
        float4 sv = *(const float4*)&s[b * CIN + ci];
        #pragma unroll
        for (int j = 0; j < 4; ++j) {
            const int co = co0 + (w & 1) * 64 + j * 16 + (l & 15);
            ushort4 wv = *(const ushort4*)(wgtb + (size_t)co * MM + kkc * 512 + ci);
            float v0 = SCALE_F * (__bfloat162float(*(__hip_bfloat16*)&wv.x) + cf * acc[i][j][0]) * sv.x;
            float v1 = SCALE_F * (__bfloat162float(*(__hip_bfloat16*)&wv.y) + cf * acc[i][j][1]) * sv.y;
            float v2 = SCALE_F * (__bfloat162float(*(__hip_bfloat16*)&wv.z) + cf * acc[i][j][2]) * sv.z;
            float v3 = SCALE_F * (__bfloat162float(*(__hip_bfloat16*)&wv.w) + cf * acc[i][j][3]) * sv.w;
            __hip_bfloat16 vb[4] = {__float2bfloat16(v0), __float2bfloat16(v1),
                                    __float2bfloat16(v2), __float2bfloat16(v3)};
            const int swz = ((co >> 1) & 3) << 3;
            __hip_bfloat16* dst = Wf + (((size_t)b * MT + mt) * COUT + co) * 32 + (mk ^ swz);
            *(ushort4*)dst = *(const ushort4*)vb;
            partial[j] += v0*v0 + v1*v1 + v2*v2 + v3*v3;
        }
    }
    #pragma unroll
    for (int j = 0; j < 4; ++j)
        atomicAdd(&red[(w & 1) * 64 + j * 16 + (l & 15)], partial[j]);
    __syncthreads();
    if (t < 128) atomicAdd(&demodsq[b * COUT + co0 + t], red[t]);
}

// ---------------------------------------------------------------------------
// K_xpose: x [b][ci][y][x] fp32 -> xhwc [b][y+1][x+1][ci] bf16 (halo zeroed)
// ---------------------------------------------------------------------------
__global__ __launch_bounds__(256) void k_xpose(const float* __restrict__ x,
                                               __hip_bfloat16* __restrict__ xh) {
    const int b = blockIdx.x >> 5;
    const int y = blockIdx.x & 31;
    __shared__ __hip_bfloat16 tileT[32][72];
    const int t = threadIdx.x;
    for (int c0 = 0; c0 < CIN; c0 += 64) {
        int ci_l = t >> 2, xq = (t & 3) * 8;
        const float* src = x + (((size_t)(b * CIN + c0 + ci_l)) * HH + y) * WW + xq;
        float4 v0 = *(const float4*)src;
        float4 v1 = *(const float4*)(src + 4);
        __syncthreads();
        tileT[xq+0][ci_l] = __float2bfloat16(v0.x);
        tileT[xq+1][ci_l] = __float2bfloat16(v0.y);
        tileT[xq+2][ci_l] = __float2bfloat16(v0.z);
        tileT[xq+3][ci_l] = __float2bfloat16(v0.w);
        tileT[xq+4][ci_l] = __float2bfloat16(v1.x);
        tileT[xq+5][ci_l] = __float2bfloat16(v1.y);
        tileT[xq+6][ci_l] = __float2bfloat16(v1.z);
        tileT[xq+7][ci_l] = __float2bfloat16(v1.w);
        __syncthreads();
        int x_l = t >> 3, cg = (t & 7) * 8;
        bf16x8 o = *(const bf16x8*)&tileT[x_l][cg];
        *(bf16x8*)&xh[(((size_t)b * 34 + y + 1) * 34 + (x_l + 1)) * CIN + c0 + cg] = o;
    }
}

// ---------------------------------------------------------------------------
// K5: grouped conv as MFMA implicit GEMM. 4-buffer pipeline + XCD swizzle
// + incremental B-addressing + setprio.
// ---------------------------------------------------------------------------
__global__ __launch_bounds__(256) void k_conv_mfma(
        const __hip_bfloat16* __restrict__ Wf,     // [b][mt][co][32] swizzled
        const __hip_bfloat16* __restrict__ xh,     // [b][34][34][512]
        const float* __restrict__ demodsq,
        float* __restrict__ out) {
    const int id  = blockIdx.x;
    const int swb = (id & 7) * 64 + (id >> 3);
    const int p0  = (swb & 7) * 128;
    const int co0 = ((swb >> 3) & 3) * 128;
    const int b   = swb >> 5;
    __shared__ __align__(16) char cLDS[4 * 16384];   // 64 KB
    const int t = threadIdx.x;
    const int w = t >> 6, l = t & 63;

    const char* wsrc0 = (const char*)(Wf + (((size_t)b * MT) * COUT + co0) * 32);
    const int lq = l >> 2;
    const int ls = l & 3;
    const int off0 = t * 16;

    const __hip_bfloat16* bsrc0;
    const __hip_bfloat16* bsrc1;

    f32x4 acc[4][4];
    #pragma unroll
    for (int i = 0; i < 4; ++i)
        #pragma unroll
        for (int j = 0; j < 4; ++j) acc[i][j] = (f32x4){0.f, 0.f, 0.f, 0.f};

#define CADDR(mt) {                                                          \
    const int kk_ = (mt) >> 4;                                               \
    const int dy_ = kk_ / 3 - 1, dx_ = kk_ % 3 - 1;                          \
    { int p_l_ = w * 16 + lq; int P_ = p0 + p_l_;                            \
      int yy_ = (P_ >> 5) + dy_ + 1; int xx_ = (P_ & 31) + dx_ + 1;          \
      int sg_ = ls ^ ((p_l_ >> 1) & 3);                                      \
      bsrc0 = xh + (((size_t)b * 34 + yy_) * 34 + xx_) * CIN + sg_ * 8; }    \
    { int p_l_ = 64 + w * 16 + lq; int P_ = p0 + p_l_;                       \
      int yy_ = (P_ >> 5) + dy_ + 1; int xx_ = (P_ & 31) + dx_ + 1;          \
      int sg_ = ls ^ ((p_l_ >> 1) & 3);                                      \
      bsrc1 = xh + (((size_t)b * 34 + yy_) * 34 + xx_) * CIN + sg_ * 8; } }

#define CSTAGE(Ab_, mt) {                                                    \
    if (((mt) & 15) == 0) { CADDR(mt); } else { bsrc0 += 32; bsrc1 += 32; }  \
    const char* wa_ = wsrc0 + (size_t)(mt) * (COUT * 32 * 2);                \
    gload_lds16(wa_ + off0,        (Ab_) + off0);                            \
    gload_lds16(wa_ + off0 + 4096, (Ab_) + off0 + 4096);                     \
    gload_lds16(bsrc0, (Ab_) + 8192 + w * 1024 + l * 16);                    \
    gload_lds16(bsrc1, (Ab_) + 8192 + 4096 + w * 1024 + l * 16); }

#define CCOMPUTE(Ab_) { const char* Bb_ = (Ab_) + 8192;                      \
    bf16x8 fa[4], fb[4];                                                     \
    const int sl = (l >> 4) << 4;                                            \
    const int ar = (w >> 1) * 64 + (l & 15);                                 \
    const int br = (w & 1) * 64 + (l & 15);                                  \
    _Pragma("unroll") for (int i = 0; i < 4; ++i) {                          \
        int r = ar + i * 16;                                                 \
        fa[i] = *(const bf16x8*)((Ab_) + r * 64 + (sl ^ (((r >> 1) & 3) << 4))); \
        int q = br + i * 16;                                                 \
        fb[i] = *(const bf16x8*)(Bb_ + q * 64 + (sl ^ (((q >> 1) & 3) << 4))); } \
    __builtin_amdgcn_s_setprio(1);                                           \
    _Pragma("unroll") for (int i = 0; i < 4; ++i)                            \
        _Pragma("unroll") for (int j = 0; j < 4; ++j)                        \
            acc[i][j] = __builtin_amdgcn_mfma_f32_16x16x32_bf16(fa[i], fb[j], acc[i][j], 0, 0, 0); \
    __builtin_amdgcn_s_setprio(0); }

    CSTAGE(cLDS, 0); CSTAGE(cLDS + 16384, 1); CSTAGE(cLDS + 32768, 2);
    for (int mt = 0; mt < MT - 3; ++mt) {
        CSTAGE(cLDS + ((mt + 3) & 3) * 16384, mt + 3);
        PIPE_WAIT(12);
        CCOMPUTE(cLDS + (mt & 3) * 16384);
        PIPE_END();
    }
    PIPE_WAIT(8); CCOMPUTE(cLDS + ((MT - 3) & 3) * 16384); PIPE_END();
    PIPE_WAIT(4); CCOMPUTE(cLDS + ((MT - 2) & 3) * 16384); PIPE_END();
    PIPE_WAIT(0); CCOMPUTE(cLDS + ((MT - 1) & 3) * 16384);

    const float* dmrow = demodsq + b * COUT;
    #pragma unroll
    for (int i = 0; i < 4; ++i) {
        int co = co0 + (w >> 1) * 64 + i * 16 + (l >> 4) * 4;
        #pragma unroll
        for (int r = 0; r < 4; ++r) {
            float dm = rsqrtf(dmrow[co + r] + 1e-8f);
            #pragma unroll
            for (int j = 0; j < 4; ++j) {
                int p = p0 + (w & 1) * 64 + j * 16 + (l & 15);
                out[((size_t)b * COUT + co + r) * HW + p] = acc[i][j][r] * dm;
            }
        }
    }
}

// ---------------------------------------------------------------------------
extern "C" void kernel_launch(void* const* d_in, const int* in_sizes, int n_in,
                              void* d_out, int out_size, void* d_ws, size_t ws_size,
                              hipStream_t stream) {
    const float* x         = (const float*)d_in[0];
    const float* style     = (const float*)d_in[1];
    const float* mw        = (const float*)d_in[2];
    const float* mb        = (const float*)d_in[3];
    const float* weight    = (const float*)d_in[4];
    const float* u         = (const float*)d_in[5];
    const float* vh        = (const float*)d_in[6];
    const float* dir_delta = (const float*)d_in[7];
    const float* shifts    = (const float*)d_in[8];
    const int*   dirs      = (const int*)d_in[9];
    float* out = (float*)d_out;

    // ---- compact workspace layout (high-water 94,568,448 B — round-4-proven)
    char* base = (char*)d_ws;
    float* s       = (float*)(base);                    // 32 KB
    float* coef    = (float*)(base + 32768);            // 64 B
    float* normsq  = (float*)(base + 32832);            // 64 B
    float* demodsq = (float*)(base + 33024);            // 32 KB
    // union region X @128KB (18,939,904 B):
    //  phase A: ubf@0 (4.72M) | ubfT@4.72M (4.72M) | Gu@9.44M (1M) | Gv@10.49M (1M) | vhb@11.53M (0.5M)
    //  phase B: ubf@0         | vt@4.72M (8.39M)   | wgtb@13.11M (4.72M)
    //  phase C: xh@0 (18.94M)
    char* X = base + 131072;
    __hip_bfloat16* ubf  = (__hip_bfloat16*)(X);
    __hip_bfloat16* ubfT = (__hip_bfloat16*)(X + 4718592);
    float*          Gu   = (float*)(X + 9437184);
    float*          Gv   = (float*)(X + 10485760);
    __hip_bfloat16* vhb  = (__hip_bfloat16*)(X + 11534336);
    __hip_bfloat16* vt   = (__hip_bfloat16*)(X + 4718592);
    __hip_bfloat16* wgtb = (__hip_bfloat16*)(X + 13107200);
    __hip_bfloat16* xh   = (__hip_bfloat16*)(X);
    __hip_bfloat16* Wf   = (__hip_bfloat16*)(X + 18939904);   // 75.5 MB

    hipMemsetAsync(demodsq, 0, BB * COUT * sizeof(float), stream);
    hipMemsetAsync(normsq, 0, BB * sizeof(float), stream);
    hipMemsetAsync(Gu, 0, 2097152, stream);              // Gu+Gv (atomic targets)
    k_mod       <<<dim3(32),         256, 0, stream>>>(style, mw, mb, s);
    k_prep_u2   <<<dim3(72, 8),      256, 0, stream>>>(u, ubf, ubfT);
    k_cast      <<<dim3(128),        256, 0, stream>>>(vh, vhb);
    k_gram2     <<<dim3(8, 8, 11),   256, 0, stream>>>(ubfT, vhb, Gu, Gv);
    k_norm      <<<dim3(BB, 8),      256, 0, stream>>>(Gu, Gv, dir_delta, dirs, normsq);
    k_fin       <<<dim3(1),          64,  0, stream>>>(normsq, shifts, coef);
    // Gu/Gv/ubfT/vhb dead; vt+wgtb overwrite them
    k_prep_vt   <<<dim3(8, 8, BB),   256, 0, stream>>>(vh, dir_delta, dirs, vt);
    k_prep_w    <<<dim3(COUT),       256, 0, stream>>>(weight, wgtb);
    k_build_mfma<<<dim3(36, 4, BB),  256, 0, stream>>>(ubf, vt, wgtb, s, coef, Wf, demodsq);
    // ubf/vt/wgtb dead; xh overwrites region X
    hipMemsetAsync(xh, 0, (size_t)BB * 34 * 34 * CIN * sizeof(__hip_bfloat16), stream);
    k_xpose     <<<dim3(512),        256, 0, stream>>>(x, xh);
    k_conv_mfma <<<dim3(512),        256, 0, stream>>>(Wf, xh, demodsq, out);
}

// Round 9
// 263.618 us; speedup vs baseline: 12.2835x; 1.1144x over previous
//
#include <hip/hip_runtime.h>
#include <hip/hip_bf16.h>

// Problem constants
#define BB   16
#define CIN  512
#define COUT 512
#define KS   3
#define KK   9
#define HH   32
#define WW   32
#define HW   1024
#define SDIM 512
#define RR   512
#define MM   4608               // KK*CIN; m = kk*512 + ci
#define MT   144                // MM/32 k-tiles
#define SCALE_F 0.014731391274719738f  // 1/sqrt(4608)

typedef __attribute__((ext_vector_type(8))) short bf16x8;
typedef __attribute__((ext_vector_type(4))) float f32x4;

__device__ __forceinline__ void gload_lds16(const void* g, void* l) {
    __builtin_amdgcn_global_load_lds(
        (const __attribute__((address_space(1))) unsigned int*)g,
        (__attribute__((address_space(3))) unsigned int*)l,
        16, 0, 0);
}

#define PIPE_WAIT(N) do {                                            \
    asm volatile("s_waitcnt vmcnt(" #N ")" ::: "memory");            \
    __builtin_amdgcn_s_barrier();                                    \
    __builtin_amdgcn_sched_barrier(0); } while (0)
#define PIPE_END() do {                                              \
    __builtin_amdgcn_sched_barrier(0);                               \
    __builtin_amdgcn_s_barrier(); } while (0)

// ---------------------------------------------------------------------------
// K_prep_all: one kernel, per-block sections (block-uniform branch):
//  [0,32)    : s[b,ci] = style . mw^T + mb
//  [32,608)  : ubf[m][r]=bf16(u), ubfT[r][m]=bf16(u)  (72x8 tiles)
//  [608,736) : vhb = bf16(vh)
//  [736,741) : zero demodsq+normsq (8208 floats @ base+32768)
//  [741,997) : zero Gu+Gv (524288 floats)
// ---------------------------------------------------------------------------
__global__ __launch_bounds__(256) void k_prep_all(
        const float* __restrict__ style, const float* __restrict__ mw,
        const float* __restrict__ mb, float* __restrict__ s,
        const float* __restrict__ u, __hip_bfloat16* __restrict__ ub,
        __hip_bfloat16* __restrict__ uT,
        const float* __restrict__ vh, __hip_bfloat16* __restrict__ vhb,
        float* __restrict__ zero1,    // demodsq..normsq region
        float* __restrict__ zero2) {  // Gu..Gv region
    const int id = blockIdx.x;
    const int t = threadIdx.x;
    __shared__ __hip_bfloat16 tile[64][80];

    if (id < 32) {
        int idx = id * 256 + t;
        int b = idx >> 9, ci = idx & 511;
        const float* st = style + (size_t)b * SDIM;
        const float* w  = mw + (size_t)ci * SDIM;
        float acc = 0.f;
        for (int d = 0; d < SDIM; d += 4)
            acc += st[d]*w[d] + st[d+1]*w[d+1] + st[d+2]*w[d+2] + st[d+3]*w[d+3];
        s[idx] = acc + mb[ci];
    } else if (id < 608) {
        const int bx = id - 32;
        const int m0 = (bx % 72) * 64, r0 = (bx / 72) * 64;
        const int ml = t >> 4, rl4 = (t & 15) * 4;
        #pragma unroll
        for (int p = 0; p < 4; ++p) {
            int m_l = ml + p * 16;
            float4 v = *(const float4*)&u[(size_t)(m0 + m_l) * RR + r0 + rl4];
            __hip_bfloat16 b4[4] = {__float2bfloat16(v.x), __float2bfloat16(v.y),
                                    __float2bfloat16(v.z), __float2bfloat16(v.w)};
            *(ushort4*)&ub[(size_t)(m0 + m_l) * RR + r0 + rl4] = *(const ushort4*)b4;
            tile[rl4+0][m_l] = b4[0];
            tile[rl4+1][m_l] = b4[1];
            tile[rl4+2][m_l] = b4[2];
            tile[rl4+3][m_l] = b4[3];
        }
        __syncthreads();
        const int cl = t >> 2, rg = (t & 3) * 16;
        __hip_bfloat16* dst = uT + (size_t)(r0 + cl) * MM + m0 + rg;
        *(bf16x8*)dst       = *(const bf16x8*)&tile[cl][rg];
        *(bf16x8*)(dst + 8) = *(const bf16x8*)&tile[cl][rg + 8];
    } else if (id < 736) {
        size_t i = ((size_t)(id - 608) * 256 + t) * 8;
        float4 a = *(const float4*)(vh + i);
        float4 b = *(const float4*)(vh + i + 4);
        __hip_bfloat16 o[8] = {
            __float2bfloat16(a.x), __float2bfloat16(a.y),
            __float2bfloat16(a.z), __float2bfloat16(a.w),
            __float2bfloat16(b.x), __float2bfloat16(b.y),
            __float2bfloat16(b.z), __float2bfloat16(b.w)};
        *(bf16x8*)(vhb + i) = *(const bf16x8*)o;
    } else if (id < 741) {
        int idx = (id - 736) * 2048 + t * 8;
        if (idx < 8208) {
            float4 z = {0.f, 0.f, 0.f, 0.f};
            *(float4*)(zero1 + idx) = z;
            *(float4*)(zero1 + idx + 4) = z;
        }
    } else {
        int idx = (id - 741) * 2048 + t * 8;
        float4 z = {0.f, 0.f, 0.f, 0.f};
        *(float4*)(zero2 + idx) = z;
        *(float4*)(zero2 + idx + 4) = z;
    }
}

// ---------------------------------------------------------------------------
// K2: merged Gram kernel. z<9: Gu += uT[:,z*512:+512] NT-GEMM slice.
//     z>=9: Gv += vhb[:,(z-9)*256:+256] slice.
// 64x64 tile, 4 waves (2x2 of 32x32), BK=32, 4-buffer pipeline, atomic epi.
// ---------------------------------------------------------------------------
__global__ __launch_bounds__(256) void k_gram2(
        const __hip_bfloat16* __restrict__ uT,    // [RR][MM]
        const __hip_bfloat16* __restrict__ vhb,   // [RR][COUT]
        float* __restrict__ Gu, float* __restrict__ Gv) {
    const int r0 = blockIdx.x * 64, r1 = blockIdx.y * 64;
    const int z  = blockIdx.z;
    const bool isGu = (z < 9);
    const __hip_bfloat16* src = isGu ? uT : vhb;
    const int ldb   = (isGu ? MM : COUT) * 2;          // row stride bytes
    const int koff  = isGu ? z * 1024 : (z - 9) * 512; // k offset bytes
    const int NT    = isGu ? 16 : 8;
    float* G = isGu ? Gu : Gv;

    __shared__ __align__(16) char gLDS[4 * 8192];      // 32 KB
    const int t = threadIdx.x;
    const int w = t >> 6, l = t & 63;
    const int row = t >> 2, ls = t & 3;
    const int sg = ls ^ ((row >> 1) & 3);

    const char* sa = (const char*)src + (size_t)(r0 + row) * ldb + koff + sg * 16;
    const char* sb = (const char*)src + (size_t)(r1 + row) * ldb + koff + sg * 16;

    f32x4 acc[2][2];
    #pragma unroll
    for (int i = 0; i < 2; ++i)
        #pragma unroll
        for (int j = 0; j < 2; ++j) acc[i][j] = (f32x4){0.f, 0.f, 0.f, 0.f};

#define GSTAGE(bn, kt) { char* Gb_ = gLDS + (bn) * 8192;                     \
    gload_lds16(sa + (kt) * 64, Gb_ + t * 16);                               \
    gload_lds16(sb + (kt) * 64, Gb_ + 4096 + t * 16); }

#define GCOMP(bn) { const char* Ab_ = gLDS + (bn) * 8192;                    \
    const char* Bb_ = Ab_ + 4096;                                            \
    bf16x8 fa[2], fb[2];                                                     \
    const int sl = (l >> 4) << 4;                                            \
    const int ar = (w >> 1) * 32 + (l & 15);                                 \
    const int br = (w & 1) * 32 + (l & 15);                                  \
    _Pragma("unroll") for (int i = 0; i < 2; ++i) {                          \
        int r = ar + i * 16;                                                 \
        fa[i] = *(const bf16x8*)(Ab_ + r * 64 + (sl ^ (((r >> 1) & 3) << 4))); \
        int q = br + i * 16;                                                 \
        fb[i] = *(const bf16x8*)(Bb_ + q * 64 + (sl ^ (((q >> 1) & 3) << 4))); } \
    __builtin_amdgcn_s_setprio(1);                                           \
    _Pragma("unroll") for (int i = 0; i < 2; ++i)                            \
        _Pragma("unroll") for (int j = 0; j < 2; ++j)                        \
            acc[i][j] = __builtin_amdgcn_mfma_f32_16x16x32_bf16(fa[i], fb[j], acc[i][j], 0, 0, 0); \
    __builtin_amdgcn_s_setprio(0); }

    GSTAGE(0, 0); GSTAGE(1, 1); GSTAGE(2, 2);
    for (int kt = 0; kt < NT - 3; ++kt) {
        GSTAGE((kt + 3) & 3, kt + 3);
        PIPE_WAIT(6);
        GCOMP(kt & 3);
        PIPE_END();
    }
    PIPE_WAIT(4); GCOMP((NT - 3) & 3); PIPE_END();
    PIPE_WAIT(2); GCOMP((NT - 2) & 3); PIPE_END();
    PIPE_WAIT(0); GCOMP((NT - 1) & 3);

    #pragma unroll
    for (int i = 0; i < 2; ++i) {
        const int rA = r0 + (w >> 1) * 32 + i * 16 + (l >> 4) * 4;
        #pragma unroll
        for (int j = 0; j < 2; ++j) {
            const int rB = r1 + (w & 1) * 32 + j * 16 + (l & 15);
            #pragma unroll
            for (int rg = 0; rg < 4; ++rg)
                atomicAdd(&G[(size_t)(rA + rg) * RR + rB], acc[i][j][rg]);
        }
    }
}

// ---------------------------------------------------------------------------
// K3: normsq[b] += slice-sum of ev_r ev_r' Gu[r,r'] Gv[r,r']
// ---------------------------------------------------------------------------
__global__ __launch_bounds__(256) void k_norm(const float* __restrict__ Gu,
                                              const float* __restrict__ Gv,
                                              const float* __restrict__ dd,
                                              const int* __restrict__ dirs,
                                              float* __restrict__ normsq) {
    const int b = blockIdx.x, sl = blockIdx.y;
    __shared__ float evs[RR];
    __shared__ float red[256];
    const int t = threadIdx.x;
    const float* ev = dd + (size_t)dirs[b] * RR;
    for (int i = t; i < RR; i += 256) evs[i] = ev[i];
    __syncthreads();
    float acc = 0.f;
    const int base = sl * (RR * RR / 8);
    for (int p = base + t; p < base + RR * RR / 8; p += 256) {
        int r = p >> 9, r2 = p & 511;
        acc += Gu[p] * Gv[p] * evs[r] * evs[r2];
    }
    red[t] = acc;
    __syncthreads();
    for (int o = 128; o > 0; o >>= 1) {
        if (t < o) red[t] += red[t + o];
        __syncthreads();
    }
    if (t == 0) atomicAdd(&normsq[b], red[0]);
}

// ---------------------------------------------------------------------------
// K_prep_vtw: [0,1024): vt[b][co][r] = bf16(ev_b[r]*vh[r][co]);
//             [1024,1536): wgtb[co][kk][ci] = bf16(weight[co][ci][kk])
// ---------------------------------------------------------------------------
__global__ __launch_bounds__(256) void k_prep_vtw(
        const float* __restrict__ vh, const float* __restrict__ dd,
        const int* __restrict__ dirs, __hip_bfloat16* __restrict__ vt,
        const float* __restrict__ wgt, __hip_bfloat16* __restrict__ wgtb) {
    const int id = blockIdx.x;
    const int t = threadIdx.x;
    __shared__ __align__(16) char shbuf[MM * 4];   // 18.4 KB (union)

    if (id < 1024) {
        __hip_bfloat16 (*tile)[80] = (__hip_bfloat16(*)[80])shbuf;
        const int co0 = (id & 7) * 64, r0 = ((id >> 3) & 7) * 64, b = id >> 6;
        const float* ev = dd + (size_t)dirs[b] * RR;
        int tc4 = (t & 15) * 4, tr = t >> 4;
        #pragma unroll
        for (int pass = 0; pass < 4; ++pass) {
            int r = tr + pass * 16;
            float e = ev[r0 + r];
            float4 v = *(const float4*)&vh[(size_t)(r0 + r) * COUT + co0 + tc4];
            tile[tc4+0][r] = __float2bfloat16(v.x * e);
            tile[tc4+1][r] = __float2bfloat16(v.y * e);
            tile[tc4+2][r] = __float2bfloat16(v.z * e);
            tile[tc4+3][r] = __float2bfloat16(v.w * e);
        }
        __syncthreads();
        int cl = t >> 2, rg = (t & 3) * 16;
        __hip_bfloat16* dst = vt + ((size_t)b * COUT + co0 + cl) * RR + r0 + rg;
        *(bf16x8*)dst       = *(const bf16x8*)&tile[cl][rg];
        *(bf16x8*)(dst + 8) = *(const bf16x8*)&tile[cl][rg + 8];
    } else {
        float* lw = (float*)shbuf;
        const int co = id - 1024;
        for (int e = t; e < MM; e += 256) lw[e] = wgt[(size_t)co * MM + e];
        __syncthreads();
        for (int e = t; e < MM; e += 256) {
            int kk = e >> 9, ci = e & 511;
            wgtb[(size_t)co * MM + e] = __float2bfloat16(lw[ci * KK + kk]);
        }
    }
}

// ---------------------------------------------------------------------------
// K4: MFMA delta-GEMM + weight build + demod partials.
// 1D grid 2304 with XCD swizzle (m fastest within each XCD chunk).
// 3-buffer ring (48 KB LDS), vmcnt(8), setprio. coef computed inline.
// ---------------------------------------------------------------------------
__global__ __launch_bounds__(256) void k_build_mfma(
        const __hip_bfloat16* __restrict__ ubf,   // [MM][RR]
        const __hip_bfloat16* __restrict__ vt,    // [B][COUT][RR]
        const __hip_bfloat16* __restrict__ wgtb,  // [COUT][9][512] bf16
        const float* __restrict__ s,              // [B][CIN]
        const float* __restrict__ normsq,
        const float* __restrict__ shifts,
        __hip_bfloat16* __restrict__ Wf,          // [B][MT][COUT][32] swizzled
        float* __restrict__ demodsq) {
    // XCD-aware: 2304 = 8 x 288; each XCD chunk holds 8 full (co,b) panels
    const int id = blockIdx.x;
    const int sw = (id & 7) * 288 + (id >> 3);
    const int m0  = (sw % 36) * 128;
    const int co0 = ((sw / 36) & 3) * 128;
    const int b   = sw / 144;
    __shared__ __align__(16) char bLDS[3 * 16384];   // 48 KB
    __shared__ float red[128];
    const int t = threadIdx.x;
    const int w = t >> 6, l = t & 63;
    const int row = t >> 2, ls = t & 3;
    const int sg  = ls ^ ((row >> 1) & 3);

    const char* ua  = (const char*)(ubf + (size_t)(m0 + row) * RR) + sg * 16;
    const char* ua2 = ua + (size_t)64 * RR * 2;
    const char* va  = (const char*)(vt + ((size_t)b * COUT + co0 + row) * RR) + sg * 16;
    const char* va2 = va + (size_t)64 * RR * 2;
    const int dst0 = t * 16;

    f32x4 acc[4][4];
    #pragma unroll
    for (int i = 0; i < 4; ++i)
        #pragma unroll
        for (int j = 0; j < 4; ++j) acc[i][j] = (f32x4){0.f, 0.f, 0.f, 0.f};

#define BSTAGE(Ab_, kt) { const int rb = (kt) * 64;                          \
    gload_lds16(ua  + rb, (Ab_) + dst0);                                     \
    gload_lds16(ua2 + rb, (Ab_) + dst0 + 4096);                              \
    gload_lds16(va  + rb, (Ab_) + 8192 + dst0);                              \
    gload_lds16(va2 + rb, (Ab_) + 8192 + dst0 + 4096); }

#define BCOMPUTE(Ab_) { const char* Bb_ = (Ab_) + 8192;                      \
    bf16x8 fa[4], fb[4];                                                     \
    const int sl = (l >> 4) << 4;                                            \
    const int ar = (w >> 1) * 64 + (l & 15);                                 \
    const int br = (w & 1) * 64 + (l & 15);                                  \
    _Pragma("unroll") for (int i = 0; i < 4; ++i) {                          \
        int r = ar + i * 16;                                                 \
        fa[i] = *(const bf16x8*)((Ab_) + r * 64 + (sl ^ (((r >> 1) & 3) << 4))); \
        int q = br + i * 16;                                                 \
        fb[i] = *(const bf16x8*)(Bb_ + q * 64 + (sl ^ (((q >> 1) & 3) << 4))); } \
    __builtin_amdgcn_s_setprio(1);                                           \
    _Pragma("unroll") for (int i = 0; i < 4; ++i)                            \
        _Pragma("unroll") for (int j = 0; j < 4; ++j)                        \
            acc[i][j] = __builtin_amdgcn_mfma_f32_16x16x32_bf16(fa[i], fb[j], acc[i][j], 0, 0, 0); \
    __builtin_amdgcn_s_setprio(0); }

    char* cbuf = bLDS;
    char* nbuf = bLDS + 16384;
    char* sbuf = bLDS + 32768;
    BSTAGE(cbuf, 0); BSTAGE(nbuf, 1);
    for (int kt = 0; kt < 14; ++kt) {
        BSTAGE(sbuf, kt + 2);
        PIPE_WAIT(8);
        BCOMPUTE(cbuf);
        PIPE_END();
        char* tmp = cbuf; cbuf = nbuf; nbuf = sbuf; sbuf = tmp;
    }
    PIPE_WAIT(4); BCOMPUTE(cbuf); PIPE_END();   // kt=14
    PIPE_WAIT(0); BCOMPUTE(nbuf);               // kt=15

    // ---- epilogue
    __syncthreads();
    if (t < 128) red[t] = 0.f;
    __syncthreads();
    const float cf = shifts[b] / fmaxf(sqrtf(normsq[b]), 1e-12f);
    const int kkc = m0 >> 9;
    float partial[4] = {0.f, 0.f, 0.f, 0.f};
    #pragma unroll
    for (int i = 0; i < 4; ++i) {
        const int m_base = m0 + (w >> 1) * 64 + i * 16 + (l >> 4) * 4;
        const int ci = m_base & 511;
        const int mt = m_base >> 5, mk = m_base & 31;
        float4 sv = *(const float4*)&s[b * CIN + ci];
        #pragma unroll
        for (int j = 0; j < 4; ++j) {
            const int co = co0 + (w & 1) * 64 + j * 16 + (l & 15);
            ushort4 wv = *(const ushort4*)(wgtb + (size_t)co * MM + kkc * 512 + ci);
            float v0 = SCALE_F * (__bfloat162float(*(__hip_bfloat16*)&wv.x) + cf * acc[i][j][0]) * sv.x;
            float v1 = SCALE_F * (__bfloat162float(*(__hip_bfloat16*)&wv.y) + cf * acc[i][j][1]) * sv.y;
            float v2 = SCALE_F * (__bfloat162float(*(__hip_bfloat16*)&wv.z) + cf * acc[i][j][2]) * sv.z;
            float v3 = SCALE_F * (__bfloat162float(*(__hip_bfloat16*)&wv.w) + cf * acc[i][j][3]) * sv.w;
            __hip_bfloat16 vb[4] = {__float2bfloat16(v0), __float2bfloat16(v1),
                                    __float2bfloat16(v2), __float2bfloat16(v3)};
            const int swz = ((co >> 1) & 3) << 3;
            __hip_bfloat16* dst = Wf + (((size_t)b * MT + mt) * COUT + co) * 32 + (mk ^ swz);
            *(ushort4*)dst = *(const ushort4*)vb;
            partial[j] += v0*v0 + v1*v1 + v2*v2 + v3*v3;
        }
    }
    #pragma unroll
    for (int j = 0; j < 4; ++j)
        atomicAdd(&red[(w & 1) * 64 + j * 16 + (l & 15)], partial[j]);
    __syncthreads();
    if (t < 128) atomicAdd(&demodsq[b * COUT + co0 + t], red[t]);
}

// ---------------------------------------------------------------------------
// K_xpose: [0,512): x [b][ci][y][x] fp32 -> xh [b][y+1][x+1][ci] bf16 interior
//          [512,528): zero the halo of batch (id-512)
// ---------------------------------------------------------------------------
__global__ __launch_bounds__(256) void k_xpose(const float* __restrict__ x,
                                               __hip_bfloat16* __restrict__ xh) {
    const int t = threadIdx.x;
    if (blockIdx.x >= 512) {
        const int b = blockIdx.x - 512;
        // halo cells: 132 per image, each 512 bf16 = 64 chunks of 8
        for (int c = t; c < 132 * 64; c += 256) {
            int cell = c >> 6, part = c & 63;
            int yy, xx;
            if (cell < 34)      { yy = 0;  xx = cell; }
            else if (cell < 68) { yy = 33; xx = cell - 34; }
            else if (cell < 100){ yy = cell - 68 + 1;  xx = 0; }
            else                { yy = cell - 100 + 1; xx = 33; }
            bf16x8 z = {0,0,0,0,0,0,0,0};
            *(bf16x8*)&xh[(((size_t)b * 34 + yy) * 34 + xx) * CIN + part * 8] = z;
        }
        return;
    }
    const int b = blockIdx.x >> 5;
    const int y = blockIdx.x & 31;
    __shared__ __hip_bfloat16 tileT[32][72];
    for (int c0 = 0; c0 < CIN; c0 += 64) {
        int ci_l = t >> 2, xq = (t & 3) * 8;
        const float* src = x + (((size_t)(b * CIN + c0 + ci_l)) * HH + y) * WW + xq;
        float4 v0 = *(const float4*)src;
        float4 v1 = *(const float4*)(src + 4);
        __syncthreads();
        tileT[xq+0][ci_l] = __float2bfloat16(v0.x);
        tileT[xq+1][ci_l] = __float2bfloat16(v0.y);
        tileT[xq+2][ci_l] = __float2bfloat16(v0.z);
        tileT[xq+3][ci_l] = __float2bfloat16(v0.w);
        tileT[xq+4][ci_l] = __float2bfloat16(v1.x);
        tileT[xq+5][ci_l] = __float2bfloat16(v1.y);
        tileT[xq+6][ci_l] = __float2bfloat16(v1.z);
        tileT[xq+7][ci_l] = __float2bfloat16(v1.w);
        __syncthreads();
        int x_l = t >> 3, cg = (t & 7) * 8;
        bf16x8 o = *(const bf16x8*)&tileT[x_l][cg];
        *(bf16x8*)&xh[(((size_t)b * 34 + y + 1) * 34 + (x_l + 1)) * CIN + c0 + cg] = o;
    }
}

// ---------------------------------------------------------------------------
// K5: grouped conv as MFMA implicit GEMM. 4-buffer pipeline + XCD swizzle
// + incremental B-addressing + setprio.
// ---------------------------------------------------------------------------
__global__ __launch_bounds__(256) void k_conv_mfma(
        const __hip_bfloat16* __restrict__ Wf,     // [b][mt][co][32] swizzled
        const __hip_bfloat16* __restrict__ xh,     // [b][34][34][512]
        const float* __restrict__ demodsq,
        float* __restrict__ out) {
    const int id  = blockIdx.x;
    const int swb = (id & 7) * 64 + (id >> 3);
    const int p0  = (swb & 7) * 128;
    const int co0 = ((swb >> 3) & 3) * 128;
    const int b   = swb >> 5;
    __shared__ __align__(16) char cLDS[4 * 16384];   // 64 KB
    const int t = threadIdx.x;
    const int w = t >> 6, l = t & 63;

    const char* wsrc0 = (const char*)(Wf + (((size_t)b * MT) * COUT + co0) * 32);
    const int lq = l >> 2;
    const int ls = l & 3;
    const int off0 = t * 16;

    const __hip_bfloat16* bsrc0;
    const __hip_bfloat16* bsrc1;

    f32x4 acc[4][4];
    #pragma unroll
    for (int i = 0; i < 4; ++i)
        #pragma unroll
        for (int j = 0; j < 4; ++j) acc[i][j] = (f32x4){0.f, 0.f, 0.f, 0.f};

#define CADDR(mt) {                                                          \
    const int kk_ = (mt) >> 4;                                               \
    const int dy_ = kk_ / 3 - 1, dx_ = kk_ % 3 - 1;                          \
    { int p_l_ = w * 16 + lq; int P_ = p0 + p_l_;                            \
      int yy_ = (P_ >> 5) + dy_ + 1; int xx_ = (P_ & 31) + dx_ + 1;          \
      int sg_ = ls ^ ((p_l_ >> 1) & 3);                                      \
      bsrc0 = xh + (((size_t)b * 34 + yy_) * 34 + xx_) * CIN + sg_ * 8; }    \
    { int p_l_ = 64 + w * 16 + lq; int P_ = p0 + p_l_;                       \
      int yy_ = (P_ >> 5) + dy_ + 1; int xx_ = (P_ & 31) + dx_ + 1;          \
      int sg_ = ls ^ ((p_l_ >> 1) & 3);                                      \
      bsrc1 = xh + (((size_t)b * 34 + yy_) * 34 + xx_) * CIN + sg_ * 8; } }

#define CSTAGE(Ab_, mt) {                                                    \
    if (((mt) & 15) == 0) { CADDR(mt); } else { bsrc0 += 32; bsrc1 += 32; }  \
    const char* wa_ = wsrc0 + (size_t)(mt) * (COUT * 32 * 2);                \
    gload_lds16(wa_ + off0,        (Ab_) + off0);                            \
    gload_lds16(wa_ + off0 + 4096, (Ab_) + off0 + 4096);                     \
    gload_lds16(bsrc0, (Ab_) + 8192 + w * 1024 + l * 16);                    \
    gload_lds16(bsrc1, (Ab_) + 8192 + 4096 + w * 1024 + l * 16); }

#define CCOMPUTE(Ab_) { const char* Bb_ = (Ab_) + 8192;                      \
    bf16x8 fa[4], fb[4];                                                     \
    const int sl = (l >> 4) << 4;                                            \
    const int ar = (w >> 1) * 64 + (l & 15);                                 \
    const int br = (w & 1) * 64 + (l & 15);                                  \
    _Pragma("unroll") for (int i = 0; i < 4; ++i) {                          \
        int r = ar + i * 16;                                                 \
        fa[i] = *(const bf16x8*)((Ab_) + r * 64 + (sl ^ (((r >> 1) & 3) << 4))); \
        int q = br + i * 16;                                                 \
        fb[i] = *(const bf16x8*)(Bb_ + q * 64 + (sl ^ (((q >> 1) & 3) << 4))); } \
    __builtin_amdgcn_s_setprio(1);                                           \
    _Pragma("unroll") for (int i = 0; i < 4; ++i)                            \
        _Pragma("unroll") for (int j = 0; j < 4; ++j)                        \
            acc[i][j] = __builtin_amdgcn_mfma_f32_16x16x32_bf16(fa[i], fb[j], acc[i][j], 0, 0, 0); \
    __builtin_amdgcn_s_setprio(0); }

    CSTAGE(cLDS, 0); CSTAGE(cLDS + 16384, 1); CSTAGE(cLDS + 32768, 2);
    for (int mt = 0; mt < MT - 3; ++mt) {
        CSTAGE(cLDS + ((mt + 3) & 3) * 16384, mt + 3);
        PIPE_WAIT(12);
        CCOMPUTE(cLDS + (mt & 3) * 16384);
        PIPE_END();
    }
    PIPE_WAIT(8); CCOMPUTE(cLDS + ((MT - 3) & 3) * 16384); PIPE_END();
    PIPE_WAIT(4); CCOMPUTE(cLDS + ((MT - 2) & 3) * 16384); PIPE_END();
    PIPE_WAIT(0); CCOMPUTE(cLDS + ((MT - 1) & 3) * 16384);

    const float* dmrow = demodsq + b * COUT;
    #pragma unroll
    for (int i = 0; i < 4; ++i) {
        int co = co0 + (w >> 1) * 64 + i * 16 + (l >> 4) * 4;
        #pragma unroll
        for (int r = 0; r < 4; ++r) {
            float dm = rsqrtf(dmrow[co + r] + 1e-8f);
            #pragma unroll
            for (int j = 0; j < 4; ++j) {
                int p = p0 + (w & 1) * 64 + j * 16 + (l & 15);
                out[((size_t)b * COUT + co + r) * HW + p] = acc[i][j][r] * dm;
            }
        }
    }
}

// ---------------------------------------------------------------------------
extern "C" void kernel_launch(void* const* d_in, const int* in_sizes, int n_in,
                              void* d_out, int out_size, void* d_ws, size_t ws_size,
                              hipStream_t stream) {
    const float* x         = (const float*)d_in[0];
    const float* style     = (const float*)d_in[1];
    const float* mw        = (const float*)d_in[2];
    const float* mb        = (const float*)d_in[3];
    const float* weight    = (const float*)d_in[4];
    const float* u         = (const float*)d_in[5];
    const float* vh        = (const float*)d_in[6];
    const float* dir_delta = (const float*)d_in[7];
    const float* shifts    = (const float*)d_in[8];
    const int*   dirs      = (const int*)d_in[9];
    float* out = (float*)d_out;

    // ---- compact workspace layout (high-water 94,568,448 B — round-4-proven)
    char* base = (char*)d_ws;
    float* s       = (float*)(base);                    // 32 KB
    float* demodsq = (float*)(base + 32768);            // 32 KB
    float* normsq  = (float*)(base + 65536);            // 64 B
    // union region X @128KB (18,939,904 B):
    //  phase A: ubf@0 (4.72M) | ubfT@4.72M (4.72M) | Gu@9.44M (1M) | Gv@10.49M (1M) | vhb@11.53M (0.5M)
    //  phase B: ubf@0         | vt@4.72M (8.39M)   | wgtb@13.11M (4.72M)
    //  phase C: xh@0 (18.94M)
    char* X = base + 131072;
    __hip_bfloat16* ubf  = (__hip_bfloat16*)(X);
    __hip_bfloat16* ubfT = (__hip_bfloat16*)(X + 4718592);
    float*          Gu   = (float*)(X + 9437184);
    float*          Gv   = (float*)(X + 10485760);
    __hip_bfloat16* vhb  = (__hip_bfloat16*)(X + 11534336);
    __hip_bfloat16* vt   = (__hip_bfloat16*)(X + 4718592);
    __hip_bfloat16* wgtb = (__hip_bfloat16*)(X + 13107200);
    __hip_bfloat16* xh   = (__hip_bfloat16*)(X);
    __hip_bfloat16* Wf   = (__hip_bfloat16*)(X + 18939904);   // 75.5 MB

    k_prep_all  <<<dim3(997),      256, 0, stream>>>(style, mw, mb, s,
                                                     u, ubf, ubfT, vh, vhb,
                                                     demodsq, Gu);
    k_gram2     <<<dim3(8, 8, 11), 256, 0, stream>>>(ubfT, vhb, Gu, Gv);
    k_norm      <<<dim3(BB, 8),    256, 0, stream>>>(Gu, Gv, dir_delta, dirs, normsq);
    k_prep_vtw  <<<dim3(1536),     256, 0, stream>>>(vh, dir_delta, dirs, vt, weight, wgtb);
    k_build_mfma<<<dim3(2304),     256, 0, stream>>>(ubf, vt, wgtb, s, normsq, shifts, Wf, demodsq);
    k_xpose     <<<dim3(528),      256, 0, stream>>>(x, xh);
    k_conv_mfma <<<dim3(512),      256, 0, stream>>>(Wf, xh, demodsq, out);
}

// Round 10
// 253.779 us; speedup vs baseline: 12.7598x; 1.0388x over previous
//
#include <hip/hip_runtime.h>
#include <hip/hip_bf16.h>

// Problem constants
#define BB   16
#define CIN  512
#define COUT 512
#define KS   3
#define KK   9
#define HH   32
#define WW   32
#define HW   1024
#define SDIM 512
#define RR   512
#define MM   4608               // KK*CIN; m = kk*512 + ci
#define MT   144                // MM/32 k-tiles
#define SCALE_F 0.014731391274719738f  // 1/sqrt(4608)

typedef __attribute__((ext_vector_type(8))) short bf16x8;
typedef __attribute__((ext_vector_type(4))) float f32x4;

__device__ __forceinline__ void gload_lds16(const void* g, void* l) {
    __builtin_amdgcn_global_load_lds(
        (const __attribute__((address_space(1))) unsigned int*)g,
        (__attribute__((address_space(3))) unsigned int*)l,
        16, 0, 0);
}

#define PIPE_WAIT(N) do {                                            \
    asm volatile("s_waitcnt vmcnt(" #N ")" ::: "memory");            \
    __builtin_amdgcn_s_barrier();                                    \
    __builtin_amdgcn_sched_barrier(0); } while (0)
#define PIPE_END() do {                                              \
    __builtin_amdgcn_sched_barrier(0);                               \
    __builtin_amdgcn_s_barrier(); } while (0)

// ---------------------------------------------------------------------------
// K_prep_all: one kernel, per-block sections (block-uniform branch):
//  [0,32)    : s[b,ci] = style . mw^T + mb
//  [32,608)  : ubf[m][r]=bf16(u), ubfT[r][m]=bf16(u)  (72x8 tiles)
//  [608,736) : vhb = bf16(vh)
//  [736,741) : zero demodsq+normsq (8208 floats @ base+32768)
//  [741,997) : zero Gu+Gv (524288 floats)
// ---------------------------------------------------------------------------
__global__ __launch_bounds__(256) void k_prep_all(
        const float* __restrict__ style, const float* __restrict__ mw,
        const float* __restrict__ mb, float* __restrict__ s,
        const float* __restrict__ u, __hip_bfloat16* __restrict__ ub,
        __hip_bfloat16* __restrict__ uT,
        const float* __restrict__ vh, __hip_bfloat16* __restrict__ vhb,
        float* __restrict__ zero1,    // demodsq..normsq region
        float* __restrict__ zero2) {  // Gu..Gv region
    const int id = blockIdx.x;
    const int t = threadIdx.x;
    __shared__ __hip_bfloat16 tile[64][80];

    if (id < 32) {
        int idx = id * 256 + t;
        int b = idx >> 9, ci = idx & 511;
        const float* st = style + (size_t)b * SDIM;
        const float* w  = mw + (size_t)ci * SDIM;
        float acc = 0.f;
        for (int d = 0; d < SDIM; d += 4)
            acc += st[d]*w[d] + st[d+1]*w[d+1] + st[d+2]*w[d+2] + st[d+3]*w[d+3];
        s[idx] = acc + mb[ci];
    } else if (id < 608) {
        const int bx = id - 32;
        const int m0 = (bx % 72) * 64, r0 = (bx / 72) * 64;
        const int ml = t >> 4, rl4 = (t & 15) * 4;
        #pragma unroll
        for (int p = 0; p < 4; ++p) {
            int m_l = ml + p * 16;
            float4 v = *(const float4*)&u[(size_t)(m0 + m_l) * RR + r0 + rl4];
            __hip_bfloat16 b4[4] = {__float2bfloat16(v.x), __float2bfloat16(v.y),
                                    __float2bfloat16(v.z), __float2bfloat16(v.w)};
            *(ushort4*)&ub[(size_t)(m0 + m_l) * RR + r0 + rl4] = *(const ushort4*)b4;
            tile[rl4+0][m_l] = b4[0];
            tile[rl4+1][m_l] = b4[1];
            tile[rl4+2][m_l] = b4[2];
            tile[rl4+3][m_l] = b4[3];
        }
        __syncthreads();
        const int cl = t >> 2, rg = (t & 3) * 16;
        __hip_bfloat16* dst = uT + (size_t)(r0 + cl) * MM + m0 + rg;
        *(bf16x8*)dst       = *(const bf16x8*)&tile[cl][rg];
        *(bf16x8*)(dst + 8) = *(const bf16x8*)&tile[cl][rg + 8];
    } else if (id < 736) {
        size_t i = ((size_t)(id - 608) * 256 + t) * 8;
        float4 a = *(const float4*)(vh + i);
        float4 b = *(const float4*)(vh + i + 4);
        __hip_bfloat16 o[8] = {
            __float2bfloat16(a.x), __float2bfloat16(a.y),
            __float2bfloat16(a.z), __float2bfloat16(a.w),
            __float2bfloat16(b.x), __float2bfloat16(b.y),
            __float2bfloat16(b.z), __float2bfloat16(b.w)};
        *(bf16x8*)(vhb + i) = *(const bf16x8*)o;
    } else if (id < 741) {
        int idx = (id - 736) * 2048 + t * 8;
        if (idx < 8208) {
            float4 z = {0.f, 0.f, 0.f, 0.f};
            *(float4*)(zero1 + idx) = z;
            *(float4*)(zero1 + idx + 4) = z;
        }
    } else {
        int idx = (id - 741) * 2048 + t * 8;
        float4 z = {0.f, 0.f, 0.f, 0.f};
        *(float4*)(zero2 + idx) = z;
        *(float4*)(zero2 + idx + 4) = z;
    }
}

// ---------------------------------------------------------------------------
// K2: merged Gram kernel. z<9: Gu += uT[:,z*512:+512] NT-GEMM slice.
//     z>=9: Gv += vhb[:,(z-9)*256:+256] slice.
// 64x64 tile, 4 waves (2x2 of 32x32), BK=32, 4-buffer pipeline, atomic epi.
// ---------------------------------------------------------------------------
__global__ __launch_bounds__(256) void k_gram2(
        const __hip_bfloat16* __restrict__ uT,    // [RR][MM]
        const __hip_bfloat16* __restrict__ vhb,   // [RR][COUT]
        float* __restrict__ Gu, float* __restrict__ Gv) {
    const int r0 = blockIdx.x * 64, r1 = blockIdx.y * 64;
    const int z  = blockIdx.z;
    const bool isGu = (z < 9);
    const __hip_bfloat16* src = isGu ? uT : vhb;
    const int ldb   = (isGu ? MM : COUT) * 2;          // row stride bytes
    const int koff  = isGu ? z * 1024 : (z - 9) * 512; // k offset bytes
    const int NT    = isGu ? 16 : 8;
    float* G = isGu ? Gu : Gv;

    __shared__ __align__(16) char gLDS[4 * 8192];      // 32 KB
    const int t = threadIdx.x;
    const int w = t >> 6, l = t & 63;
    const int row = t >> 2, ls = t & 3;
    const int sg = ls ^ ((row >> 1) & 3);

    const char* sa = (const char*)src + (size_t)(r0 + row) * ldb + koff + sg * 16;
    const char* sb = (const char*)src + (size_t)(r1 + row) * ldb + koff + sg * 16;

    f32x4 acc[2][2];
    #pragma unroll
    for (int i = 0; i < 2; ++i)
        #pragma unroll
        for (int j = 0; j < 2; ++j) acc[i][j] = (f32x4){0.f, 0.f, 0.f, 0.f};

#define GSTAGE(bn, kt) { char* Gb_ = gLDS + (bn) * 8192;                     \
    gload_lds16(sa + (kt) * 64, Gb_ + t * 16);                               \
    gload_lds16(sb + (kt) * 64, Gb_ + 4096 + t * 16); }

#define GCOMP(bn) { const char* Ab_ = gLDS + (bn) * 8192;                    \
    const char* Bb_ = Ab_ + 4096;                                            \
    bf16x8 fa[2], fb[2];                                                     \
    const int sl = (l >> 4) << 4;                                            \
    const int ar = (w >> 1) * 32 + (l & 15);                                 \
    const int br = (w & 1) * 32 + (l & 15);                                  \
    _Pragma("unroll") for (int i = 0; i < 2; ++i) {                          \
        int r = ar + i * 16;                                                 \
        fa[i] = *(const bf16x8*)(Ab_ + r * 64 + (sl ^ (((r >> 1) & 3) << 4))); \
        int q = br + i * 16;                                                 \
        fb[i] = *(const bf16x8*)(Bb_ + q * 64 + (sl ^ (((q >> 1) & 3) << 4))); } \
    __builtin_amdgcn_s_setprio(1);                                           \
    _Pragma("unroll") for (int i = 0; i < 2; ++i)                            \
        _Pragma("unroll") for (int j = 0; j < 2; ++j)                        \
            acc[i][j] = __builtin_amdgcn_mfma_f32_16x16x32_bf16(fa[i], fb[j], acc[i][j], 0, 0, 0); \
    __builtin_amdgcn_s_setprio(0); }

    GSTAGE(0, 0); GSTAGE(1, 1); GSTAGE(2, 2);
    for (int kt = 0; kt < NT - 3; ++kt) {
        GSTAGE((kt + 3) & 3, kt + 3);
        PIPE_WAIT(6);
        GCOMP(kt & 3);
        PIPE_END();
    }
    PIPE_WAIT(4); GCOMP((NT - 3) & 3); PIPE_END();
    PIPE_WAIT(2); GCOMP((NT - 2) & 3); PIPE_END();
    PIPE_WAIT(0); GCOMP((NT - 1) & 3);

    #pragma unroll
    for (int i = 0; i < 2; ++i) {
        const int rA = r0 + (w >> 1) * 32 + i * 16 + (l >> 4) * 4;
        #pragma unroll
        for (int j = 0; j < 2; ++j) {
            const int rB = r1 + (w & 1) * 32 + j * 16 + (l & 15);
            #pragma unroll
            for (int rg = 0; rg < 4; ++rg)
                atomicAdd(&G[(size_t)(rA + rg) * RR + rB], acc[i][j][rg]);
        }
    }
}

// ---------------------------------------------------------------------------
// K3: normsq[b] += slice-sum of ev_r ev_r' Gu[r,r'] Gv[r,r']
// ---------------------------------------------------------------------------
__global__ __launch_bounds__(256) void k_norm(const float* __restrict__ Gu,
                                              const float* __restrict__ Gv,
                                              const float* __restrict__ dd,
                                              const int* __restrict__ dirs,
                                              float* __restrict__ normsq) {
    const int b = blockIdx.x, sl = blockIdx.y;
    __shared__ float evs[RR];
    __shared__ float red[256];
    const int t = threadIdx.x;
    const float* ev = dd + (size_t)dirs[b] * RR;
    for (int i = t; i < RR; i += 256) evs[i] = ev[i];
    __syncthreads();
    float acc = 0.f;
    const int base = sl * (RR * RR / 8);
    for (int p = base + t; p < base + RR * RR / 8; p += 256) {
        int r = p >> 9, r2 = p & 511;
        acc += Gu[p] * Gv[p] * evs[r] * evs[r2];
    }
    red[t] = acc;
    __syncthreads();
    for (int o = 128; o > 0; o >>= 1) {
        if (t < o) red[t] += red[t + o];
        __syncthreads();
    }
    if (t == 0) atomicAdd(&normsq[b], red[0]);
}

// ---------------------------------------------------------------------------
// K_prep_vtw: [0,1024): vt[b][co][r] = bf16(ev_b[r]*vh[r][co]);
//             [1024,1536): wgtb[co][kk][ci] = bf16(weight[co][ci][kk])
// ---------------------------------------------------------------------------
__global__ __launch_bounds__(256) void k_prep_vtw(
        const float* __restrict__ vh, const float* __restrict__ dd,
        const int* __restrict__ dirs, __hip_bfloat16* __restrict__ vt,
        const float* __restrict__ wgt, __hip_bfloat16* __restrict__ wgtb) {
    const int id = blockIdx.x;
    const int t = threadIdx.x;
    __shared__ __align__(16) char shbuf[MM * 4];   // 18.4 KB (union)

    if (id < 1024) {
        __hip_bfloat16 (*tile)[80] = (__hip_bfloat16(*)[80])shbuf;
        const int co0 = (id & 7) * 64, r0 = ((id >> 3) & 7) * 64, b = id >> 6;
        const float* ev = dd + (size_t)dirs[b] * RR;
        int tc4 = (t & 15) * 4, tr = t >> 4;
        #pragma unroll
        for (int pass = 0; pass < 4; ++pass) {
            int r = tr + pass * 16;
            float e = ev[r0 + r];
            float4 v = *(const float4*)&vh[(size_t)(r0 + r) * COUT + co0 + tc4];
            tile[tc4+0][r] = __float2bfloat16(v.x * e);
            tile[tc4+1][r] = __float2bfloat16(v.y * e);
            tile[tc4+2][r] = __float2bfloat16(v.z * e);
            tile[tc4+3][r] = __float2bfloat16(v.w * e);
        }
        __syncthreads();
        int cl = t >> 2, rg = (t & 3) * 16;
        __hip_bfloat16* dst = vt + ((size_t)b * COUT + co0 + cl) * RR + r0 + rg;
        *(bf16x8*)dst       = *(const bf16x8*)&tile[cl][rg];
        *(bf16x8*)(dst + 8) = *(const bf16x8*)&tile[cl][rg + 8];
    } else {
        float* lw = (float*)shbuf;
        const int co = id - 1024;
        for (int e = t; e < MM; e += 256) lw[e] = wgt[(size_t)co * MM + e];
        __syncthreads();
        for (int e = t; e < MM; e += 256) {
            int kk = e >> 9, ci = e & 511;
            wgtb[(size_t)co * MM + e] = __float2bfloat16(lw[ci * KK + kk]);
        }
    }
}

// ---------------------------------------------------------------------------
// K4: MFMA delta-GEMM + weight build + demod partials.
// Natural 3D grid (round-8-proven L2 locality). 3-buffer ring (48 KB),
// vmcnt(8), setprio. Epilogue: LDS-bounce -> coalesced wgtb/s reads and
// dense 16B/lane Wf stores (256B-contiguous per lane-quad).
// ---------------------------------------------------------------------------
__global__ __launch_bounds__(256) void k_build_mfma(
        const __hip_bfloat16* __restrict__ ubf,   // [MM][RR]
        const __hip_bfloat16* __restrict__ vt,    // [B][COUT][RR]
        const __hip_bfloat16* __restrict__ wgtb,  // [COUT][9][512] bf16
        const float* __restrict__ s,              // [B][CIN]
        const float* __restrict__ normsq,
        const float* __restrict__ shifts,
        __hip_bfloat16* __restrict__ Wf,          // [B][MT][COUT][32] swizzled
        float* __restrict__ demodsq) {
    const int m0  = blockIdx.x * 128;
    const int co0 = blockIdx.y * 128;
    const int b   = blockIdx.z;
    __shared__ __align__(16) char bLDS[3 * 16384];   // 48 KB (ring; reused by epilogue)
    const int t = threadIdx.x;
    const int w = t >> 6, l = t & 63;
    const int row = t >> 2, ls = t & 3;
    const int sg  = ls ^ ((row >> 1) & 3);

    const char* ua  = (const char*)(ubf + (size_t)(m0 + row) * RR) + sg * 16;
    const char* ua2 = ua + (size_t)64 * RR * 2;
    const char* va  = (const char*)(vt + ((size_t)b * COUT + co0 + row) * RR) + sg * 16;
    const char* va2 = va + (size_t)64 * RR * 2;
    const int dst0 = t * 16;

    f32x4 acc[4][4];
    #pragma unroll
    for (int i = 0; i < 4; ++i)
        #pragma unroll
        for (int j = 0; j < 4; ++j) acc[i][j] = (f32x4){0.f, 0.f, 0.f, 0.f};

#define BSTAGE(Ab_, kt) { const int rb = (kt) * 64;                          \
    gload_lds16(ua  + rb, (Ab_) + dst0);                                     \
    gload_lds16(ua2 + rb, (Ab_) + dst0 + 4096);                              \
    gload_lds16(va  + rb, (Ab_) + 8192 + dst0);                              \
    gload_lds16(va2 + rb, (Ab_) + 8192 + dst0 + 4096); }

#define BCOMPUTE(Ab_) { const char* Bb_ = (Ab_) + 8192;                      \
    bf16x8 fa[4], fb[4];                                                     \
    const int sl = (l >> 4) << 4;                                            \
    const int ar = (w >> 1) * 64 + (l & 15);                                 \
    const int br = (w & 1) * 64 + (l & 15);                                  \
    _Pragma("unroll") for (int i = 0; i < 4; ++i) {                          \
        int r = ar + i * 16;                                                 \
        fa[i] = *(const bf16x8*)((Ab_) + r * 64 + (sl ^ (((r >> 1) & 3) << 4))); \
        int q = br + i * 16;                                                 \
        fb[i] = *(const bf16x8*)(Bb_ + q * 64 + (sl ^ (((q >> 1) & 3) << 4))); } \
    __builtin_amdgcn_s_setprio(1);                                           \
    _Pragma("unroll") for (int i = 0; i < 4; ++i)                            \
        _Pragma("unroll") for (int j = 0; j < 4; ++j)                        \
            acc[i][j] = __builtin_amdgcn_mfma_f32_16x16x32_bf16(fa[i], fb[j], acc[i][j], 0, 0, 0); \
    __builtin_amdgcn_s_setprio(0); }

    char* cbuf = bLDS;
    char* nbuf = bLDS + 16384;
    char* sbuf = bLDS + 32768;
    BSTAGE(cbuf, 0); BSTAGE(nbuf, 1);
    for (int kt = 0; kt < 14; ++kt) {
        BSTAGE(sbuf, kt + 2);
        PIPE_WAIT(8);
        BCOMPUTE(cbuf);
        PIPE_END();
        char* tmp = cbuf; cbuf = nbuf; nbuf = sbuf; sbuf = tmp;
    }
    PIPE_WAIT(4); BCOMPUTE(cbuf); PIPE_END();   // kt=14
    PIPE_WAIT(0); BCOMPUTE(nbuf);               // kt=15

    // ---- epilogue: LDS-bounce (pipeline LDS now free)
    __syncthreads();
    {
        __hip_bfloat16* D = (__hip_bfloat16*)bLDS;    // [128 co][136 m-slots]
        float* red = (float*)(bLDS + 34816);          // 128 floats
        const int co_l0 = (w & 1) * 64 + (l & 15);
        const int m_l0  = (w >> 1) * 64 + (l >> 4) * 4;
        #pragma unroll
        for (int i = 0; i < 4; ++i) {
            #pragma unroll
            for (int j = 0; j < 4; ++j) {
                __hip_bfloat16 d4[4] = {
                    __float2bfloat16(acc[i][j][0]), __float2bfloat16(acc[i][j][1]),
                    __float2bfloat16(acc[i][j][2]), __float2bfloat16(acc[i][j][3])};
                *(ushort4*)&D[(co_l0 + j * 16) * 136 + m_l0 + i * 16] = *(const ushort4*)d4;
            }
        }
        if (t < 128) red[t] = 0.f;
        __syncthreads();
        const float cf = shifts[b] / fmaxf(sqrtf(normsq[b]), 1e-12f);
        const int kkc = m0 >> 9;
        const int mt0 = m0 >> 5;
        const int ci0 = m0 & 511;
        #pragma unroll
        for (int p = 0; p < 8; ++p) {
            const int idx  = p * 256 + t;
            const int oct  = idx & 3;
            const int mtl  = (idx >> 2) & 3;
            const int co_l = idx >> 4;
            const int co   = co0 + co_l;
            const int swz  = ((co >> 1) & 3) << 3;
            const int m_l  = mtl * 32 + ((oct * 8) ^ swz);
            bf16x8 dv = *(const bf16x8*)&D[co_l * 136 + m_l];
            const int ci = ci0 + m_l;
            bf16x8 wv = *(const bf16x8*)&wgtb[((size_t)co * KK + kkc) * 512 + ci];
            float4 s0 = *(const float4*)&s[b * CIN + ci];
            float4 s1 = *(const float4*)&s[b * CIN + ci + 4];
            float sv[8] = {s0.x, s0.y, s0.z, s0.w, s1.x, s1.y, s1.z, s1.w};
            __hip_bfloat16 vb[8];
            float psum = 0.f;
            #pragma unroll
            for (int e = 0; e < 8; ++e) {
                short sd = dv[e], sw = wv[e];
                float dd = __bfloat162float(*(__hip_bfloat16*)&sd);
                float ww = __bfloat162float(*(__hip_bfloat16*)&sw);
                float v = SCALE_F * (ww + cf * dd) * sv[e];
                vb[e] = __float2bfloat16(v);
                psum += v * v;
            }
            *(bf16x8*)&Wf[(((size_t)b * MT + mt0 + mtl) * COUT + co) * 32 + oct * 8]
                = *(const bf16x8*)vb;
            atomicAdd(&red[co_l], psum);
        }
        __syncthreads();
        if (t < 128) atomicAdd(&demodsq[b * COUT + co0 + t], red[t]);
    }
}

// ---------------------------------------------------------------------------
// K_xpose: [0,512): x [b][ci][y][x] fp32 -> xh [b][y+1][x+1][ci] bf16 interior
//          [512,528): zero the halo of batch (id-512)
// ---------------------------------------------------------------------------
__global__ __launch_bounds__(256) void k_xpose(const float* __restrict__ x,
                                               __hip_bfloat16* __restrict__ xh) {
    const int t = threadIdx.x;
    if (blockIdx.x >= 512) {
        const int b = blockIdx.x - 512;
        for (int c = t; c < 132 * 64; c += 256) {
            int cell = c >> 6, part = c & 63;
            int yy, xx;
            if (cell < 34)      { yy = 0;  xx = cell; }
            else if (cell < 68) { yy = 33; xx = cell - 34; }
            else if (cell < 100){ yy = cell - 68 + 1;  xx = 0; }
            else                { yy = cell - 100 + 1; xx = 33; }
            bf16x8 z = {0,0,0,0,0,0,0,0};
            *(bf16x8*)&xh[(((size_t)b * 34 + yy) * 34 + xx) * CIN + part * 8] = z;
        }
        return;
    }
    const int b = blockIdx.x >> 5;
    const int y = blockIdx.x & 31;
    __shared__ __hip_bfloat16 tileT[32][72];
    for (int c0 = 0; c0 < CIN; c0 += 64) {
        int ci_l = t >> 2, xq = (t & 3) * 8;
        const float* src = x + (((size_t)(b * CIN + c0 + ci_l)) * HH + y) * WW + xq;
        float4 v0 = *(const float4*)src;
        float4 v1 = *(const float4*)(src + 4);
        __syncthreads();
        tileT[xq+0][ci_l] = __float2bfloat16(v0.x);
        tileT[xq+1][ci_l] = __float2bfloat16(v0.y);
        tileT[xq+2][ci_l] = __float2bfloat16(v0.z);
        tileT[xq+3][ci_l] = __float2bfloat16(v0.w);
        tileT[xq+4][ci_l] = __float2bfloat16(v1.x);
        tileT[xq+5][ci_l] = __float2bfloat16(v1.y);
        tileT[xq+6][ci_l] = __float2bfloat16(v1.z);
        tileT[xq+7][ci_l] = __float2bfloat16(v1.w);
        __syncthreads();
        int x_l = t >> 3, cg = (t & 7) * 8;
        bf16x8 o = *(const bf16x8*)&tileT[x_l][cg];
        *(bf16x8*)&xh[(((size_t)b * 34 + y + 1) * 34 + (x_l + 1)) * CIN + c0 + cg] = o;
    }
}

// ---------------------------------------------------------------------------
// K5: grouped conv as MFMA implicit GEMM. 4-buffer pipeline + XCD swizzle
// + incremental B-addressing + setprio.
// ---------------------------------------------------------------------------
__global__ __launch_bounds__(256) void k_conv_mfma(
        const __hip_bfloat16* __restrict__ Wf,     // [b][mt][co][32] swizzled
        const __hip_bfloat16* __restrict__ xh,     // [b][34][34][512]
        const float* __restrict__ demodsq,
        float* __restrict__ out) {
    const int id  = blockIdx.x;
    const int swb = (id & 7) * 64 + (id >> 3);
    const int p0  = (swb & 7) * 128;
    const int co0 = ((swb >> 3) & 3) * 128;
    const int b   = swb >> 5;
    __shared__ __align__(16) char cLDS[4 * 16384];   // 64 KB
    const int t = threadIdx.x;
    const int w = t >> 6, l = t & 63;

    const char* wsrc0 = (const char*)(Wf + (((size_t)b * MT) * COUT + co0) * 32);
    const int lq = l >> 2;
    const int ls = l & 3;
    const int off0 = t * 16;

    const __hip_bfloat16* bsrc0;
    const __hip_bfloat16* bsrc1;

    f32x4 acc[4][4];
    #pragma unroll
    for (int i = 0; i < 4; ++i)
        #pragma unroll
        for (int j = 0; j < 4; ++j) acc[i][j] = (f32x4){0.f, 0.f, 0.f, 0.f};

#define CADDR(mt) {                                                          \
    const int kk_ = (mt) >> 4;                                               \
    const int dy_ = kk_ / 3 - 1, dx_ = kk_ % 3 - 1;                          \
    { int p_l_ = w * 16 + lq; int P_ = p0 + p_l_;                            \
      int yy_ = (P_ >> 5) + dy_ + 1; int xx_ = (P_ & 31) + dx_ + 1;          \
      int sg_ = ls ^ ((p_l_ >> 1) & 3);                                      \
      bsrc0 = xh + (((size_t)b * 34 + yy_) * 34 + xx_) * CIN + sg_ * 8; }    \
    { int p_l_ = 64 + w * 16 + lq; int P_ = p0 + p_l_;                       \
      int yy_ = (P_ >> 5) + dy_ + 1; int xx_ = (P_ & 31) + dx_ + 1;          \
      int sg_ = ls ^ ((p_l_ >> 1) & 3);                                      \
      bsrc1 = xh + (((size_t)b * 34 + yy_) * 34 + xx_) * CIN + sg_ * 8; } }

#define CSTAGE(Ab_, mt) {                                                    \
    if (((mt) & 15) == 0) { CADDR(mt); } else { bsrc0 += 32; bsrc1 += 32; }  \
    const char* wa_ = wsrc0 + (size_t)(mt) * (COUT * 32 * 2);                \
    gload_lds16(wa_ + off0,        (Ab_) + off0);                            \
    gload_lds16(wa_ + off0 + 4096, (Ab_) + off0 + 4096);                     \
    gload_lds16(bsrc0, (Ab_) + 8192 + w * 1024 + l * 16);                    \
    gload_lds16(bsrc1, (Ab_) + 8192 + 4096 + w * 1024 + l * 16); }

#define CCOMPUTE(Ab_) { const char* Bb_ = (Ab_) + 8192;                      \
    bf16x8 fa[4], fb[4];                                                     \
    const int sl = (l >> 4) << 4;                                            \
    const int ar = (w >> 1) * 64 + (l & 15);                                 \
    const int br = (w & 1) * 64 + (l & 15);                                  \
    _Pragma("unroll") for (int i = 0; i < 4; ++i) {                          \
        int r = ar + i * 16;                                                 \
        fa[i] = *(const bf16x8*)((Ab_) + r * 64 + (sl ^ (((r >> 1) & 3) << 4))); \
        int q = br + i * 16;                                                 \
        fb[i] = *(const bf16x8*)(Bb_ + q * 64 + (sl ^ (((q >> 1) & 3) << 4))); } \
    __builtin_amdgcn_s_setprio(1);                                           \
    _Pragma("unroll") for (int i = 0; i < 4; ++i)                            \
        _Pragma("unroll") for (int j = 0; j < 4; ++j)                        \
            acc[i][j] = __builtin_amdgcn_mfma_f32_16x16x32_bf16(fa[i], fb[j], acc[i][j], 0, 0, 0); \
    __builtin_amdgcn_s_setprio(0); }

    CSTAGE(cLDS, 0); CSTAGE(cLDS + 16384, 1); CSTAGE(cLDS + 32768, 2);
    for (int mt = 0; mt < MT - 3; ++mt) {
        CSTAGE(cLDS + ((mt + 3) & 3) * 16384, mt + 3);
        PIPE_WAIT(12);
        CCOMPUTE(cLDS + (mt & 3) * 16384);
        PIPE_END();
    }
    PIPE_WAIT(8); CCOMPUTE(cLDS + ((MT - 3) & 3) * 16384); PIPE_END();
    PIPE_WAIT(4); CCOMPUTE(cLDS + ((MT - 2) & 3) * 16384); PIPE_END();
    PIPE_WAIT(0); CCOMPUTE(cLDS + ((MT - 1) & 3) * 16384);

    const float* dmrow = demodsq + b * COUT;
    #pragma unroll
    for (int i = 0; i < 4; ++i) {
        int co = co0 + (w >> 1) * 64 + i * 16 + (l >> 4) * 4;
        #pragma unroll
        for (int r = 0; r < 4; ++r) {
            float dm = rsqrtf(dmrow[co + r] + 1e-8f);
            #pragma unroll
            for (int j = 0; j < 4; ++j) {
                int p = p0 + (w & 1) * 64 + j * 16 + (l & 15);
                out[((size_t)b * COUT + co + r) * HW + p] = acc[i][j][r] * dm;
            }
        }
    }
}

// ---------------------------------------------------------------------------
extern "C" void kernel_launch(void* const* d_in, const int* in_sizes, int n_in,
                              void* d_out, int out_size, void* d_ws, size_t ws_size,
                              hipStream_t stream) {
    const float* x         = (const float*)d_in[0];
    const float* style     = (const float*)d_in[1];
    const float* mw        = (const float*)d_in[2];
    const float* mb        = (const float*)d_in[3];
    const float* weight    = (const float*)d_in[4];
    const float* u         = (const float*)d_in[5];
    const float* vh        = (const float*)d_in[6];
    const float* dir_delta = (const float*)d_in[7];
    const float* shifts    = (const float*)d_in[8];
    const int*   dirs      = (const int*)d_in[9];
    float* out = (float*)d_out;

    // ---- compact workspace layout (high-water 94,568,448 B — round-4-proven)
    char* base = (char*)d_ws;
    float* s       = (float*)(base);                    // 32 KB
    float* demodsq = (float*)(base + 32768);            // 32 KB
    float* normsq  = (float*)(base + 65536);            // 64 B
    // union region X @128KB (18,939,904 B):
    //  phase A: ubf@0 (4.72M) | ubfT@4.72M (4.72M) | Gu@9.44M (1M) | Gv@10.49M (1M) | vhb@11.53M (0.5M)
    //  phase B: ubf@0         | vt@4.72M (8.39M)   | wgtb@13.11M (4.72M)
    //  phase C: xh@0 (18.94M)
    char* X = base + 131072;
    __hip_bfloat16* ubf  = (__hip_bfloat16*)(X);
    __hip_bfloat16* ubfT = (__hip_bfloat16*)(X + 4718592);
    float*          Gu   = (float*)(X + 9437184);
    float*          Gv   = (float*)(X + 10485760);
    __hip_bfloat16* vhb  = (__hip_bfloat16*)(X + 11534336);
    __hip_bfloat16* vt   = (__hip_bfloat16*)(X + 4718592);
    __hip_bfloat16* wgtb = (__hip_bfloat16*)(X + 13107200);
    __hip_bfloat16* xh   = (__hip_bfloat16*)(X);
    __hip_bfloat16* Wf   = (__hip_bfloat16*)(X + 18939904);   // 75.5 MB

    k_prep_all  <<<dim3(997),       256, 0, stream>>>(style, mw, mb, s,
                                                      u, ubf, ubfT, vh, vhb,
                                                      demodsq, Gu);
    k_gram2     <<<dim3(8, 8, 11),  256, 0, stream>>>(ubfT, vhb, Gu, Gv);
    k_norm      <<<dim3(BB, 8),     256, 0, stream>>>(Gu, Gv, dir_delta, dirs, normsq);
    k_prep_vtw  <<<dim3(1536),      256, 0, stream>>>(vh, dir_delta, dirs, vt, weight, wgtb);
    k_build_mfma<<<dim3(36, 4, BB), 256, 0, stream>>>(ubf, vt, wgtb, s, normsq, shifts, Wf, demodsq);
    k_xpose     <<<dim3(528),       256, 0, stream>>>(x, xh);
    k_conv_mfma <<<dim3(512),       256, 0, stream>>>(Wf, xh, demodsq, out);
}

// Round 11
// 231.384 us; speedup vs baseline: 13.9947x; 1.0968x over previous
//
#include <hip/hip_runtime.h>
#include <hip/hip_bf16.h>

// Problem constants
#define BB   16
#define CIN  512
#define COUT 512
#define KS   3
#define KK   9
#define HH   32
#define WW   32
#define HW   1024
#define SDIM 512
#define RR   512
#define MM   4608               // KK*CIN; m = kk*512 + ci
#define MT   144                // MM/32 k-tiles
#define SCALE_F 0.014731391274719738f  // 1/sqrt(4608)

typedef __attribute__((ext_vector_type(8))) short bf16x8;
typedef __attribute__((ext_vector_type(4))) float f32x4;

__device__ __forceinline__ void gload_lds16(const void* g, void* l) {
    __builtin_amdgcn_global_load_lds(
        (const __attribute__((address_space(1))) unsigned int*)g,
        (__attribute__((address_space(3))) unsigned int*)l,
        16, 0, 0);
}

#define PIPE_WAIT(N) do {                                            \
    asm volatile("s_waitcnt vmcnt(" #N ")" ::: "memory");            \
    __builtin_amdgcn_s_barrier();                                    \
    __builtin_amdgcn_sched_barrier(0); } while (0)
#define PIPE_END() do {                                              \
    __builtin_amdgcn_sched_barrier(0);                               \
    __builtin_amdgcn_s_barrier(); } while (0)

// ---------------------------------------------------------------------------
// K_prep: ONE kernel for every input-only transform (block-uniform sections).
//  [0,32)      : s[b,ci] = style . mw^T + mb
//  [32,608)    : ubf[m][r]=bf16(u), ubfT[r][m]=bf16(u)   (72x8 tiles)
//  [608,736)   : vhb = bf16(vh)
//  [736,1760)  : vt[b][co][r] = bf16(ev_b[r]*vh[r][co])
//  [1760,2272) : wgtb[co][kk][ci] = bf16(weight[co][ci][kk])
//  [2272,2784) : xpose interior (x -> xh NHWC bf16)
//  [2784,2800) : xh halo zero (one block per b)
//  [2800,2805) : zero demodsq+normsq (8208 floats)
//  [2805,3061) : zero Gu+Gv (524288 floats)
// ---------------------------------------------------------------------------
__global__ __launch_bounds__(256) void k_prep(
        const float* __restrict__ style, const float* __restrict__ mw,
        const float* __restrict__ mb, float* __restrict__ s,
        const float* __restrict__ u, __hip_bfloat16* __restrict__ ub,
        __hip_bfloat16* __restrict__ uT,
        const float* __restrict__ vh, __hip_bfloat16* __restrict__ vhb,
        const float* __restrict__ dd, const int* __restrict__ dirs,
        __hip_bfloat16* __restrict__ vt,
        const float* __restrict__ wgt, __hip_bfloat16* __restrict__ wgtb,
        const float* __restrict__ x, __hip_bfloat16* __restrict__ xh,
        float* __restrict__ zero1, float* __restrict__ zero2) {
    const int id = blockIdx.x;
    const int t = threadIdx.x;
    __shared__ __align__(16) char shbuf[18432];

    if (id < 32) {
        int idx = id * 256 + t;
        int b = idx >> 9, ci = idx & 511;
        const float* st = style + (size_t)b * SDIM;
        const float* w  = mw + (size_t)ci * SDIM;
        float acc = 0.f;
        for (int d = 0; d < SDIM; d += 4)
            acc += st[d]*w[d] + st[d+1]*w[d+1] + st[d+2]*w[d+2] + st[d+3]*w[d+3];
        s[idx] = acc + mb[ci];
    } else if (id < 608) {
        __hip_bfloat16 (*tile)[80] = (__hip_bfloat16(*)[80])shbuf;
        const int bx = id - 32;
        const int m0 = (bx % 72) * 64, r0 = (bx / 72) * 64;
        const int ml = t >> 4, rl4 = (t & 15) * 4;
        #pragma unroll
        for (int p = 0; p < 4; ++p) {
            int m_l = ml + p * 16;
            float4 v = *(const float4*)&u[(size_t)(m0 + m_l) * RR + r0 + rl4];
            __hip_bfloat16 b4[4] = {__float2bfloat16(v.x), __float2bfloat16(v.y),
                                    __float2bfloat16(v.z), __float2bfloat16(v.w)};
            *(ushort4*)&ub[(size_t)(m0 + m_l) * RR + r0 + rl4] = *(const ushort4*)b4;
            tile[rl4+0][m_l] = b4[0];
            tile[rl4+1][m_l] = b4[1];
            tile[rl4+2][m_l] = b4[2];
            tile[rl4+3][m_l] = b4[3];
        }
        __syncthreads();
        const int cl = t >> 2, rg = (t & 3) * 16;
        __hip_bfloat16* dst = uT + (size_t)(r0 + cl) * MM + m0 + rg;
        *(bf16x8*)dst       = *(const bf16x8*)&tile[cl][rg];
        *(bf16x8*)(dst + 8) = *(const bf16x8*)&tile[cl][rg + 8];
    } else if (id < 736) {
        size_t i = ((size_t)(id - 608) * 256 + t) * 8;
        float4 a = *(const float4*)(vh + i);
        float4 b = *(const float4*)(vh + i + 4);
        __hip_bfloat16 o[8] = {
            __float2bfloat16(a.x), __float2bfloat16(a.y),
            __float2bfloat16(a.z), __float2bfloat16(a.w),
            __float2bfloat16(b.x), __float2bfloat16(b.y),
            __float2bfloat16(b.z), __float2bfloat16(b.w)};
        *(bf16x8*)(vhb + i) = *(const bf16x8*)o;
    } else if (id < 1760) {
        __hip_bfloat16 (*tile)[80] = (__hip_bfloat16(*)[80])shbuf;
        const int vid = id - 736;
        const int co0 = (vid & 7) * 64, r0 = ((vid >> 3) & 7) * 64, b = vid >> 6;
        const float* ev = dd + (size_t)dirs[b] * RR;
        int tc4 = (t & 15) * 4, tr = t >> 4;
        #pragma unroll
        for (int pass = 0; pass < 4; ++pass) {
            int r = tr + pass * 16;
            float e = ev[r0 + r];
            float4 v = *(const float4*)&vh[(size_t)(r0 + r) * COUT + co0 + tc4];
            tile[tc4+0][r] = __float2bfloat16(v.x * e);
            tile[tc4+1][r] = __float2bfloat16(v.y * e);
            tile[tc4+2][r] = __float2bfloat16(v.z * e);
            tile[tc4+3][r] = __float2bfloat16(v.w * e);
        }
        __syncthreads();
        int cl = t >> 2, rg = (t & 3) * 16;
        __hip_bfloat16* dst = vt + ((size_t)b * COUT + co0 + cl) * RR + r0 + rg;
        *(bf16x8*)dst       = *(const bf16x8*)&tile[cl][rg];
        *(bf16x8*)(dst + 8) = *(const bf16x8*)&tile[cl][rg + 8];
    } else if (id < 2272) {
        float* lw = (float*)shbuf;
        const int co = id - 1760;
        for (int e = t; e < MM; e += 256) lw[e] = wgt[(size_t)co * MM + e];
        __syncthreads();
        for (int e = t; e < MM; e += 256) {
            int kk = e >> 9, ci = e & 511;
            wgtb[(size_t)co * MM + e] = __float2bfloat16(lw[ci * KK + kk]);
        }
    } else if (id < 2784) {
        __hip_bfloat16 (*tileT)[72] = (__hip_bfloat16(*)[72])shbuf;
        const int xid = id - 2272;
        const int b = xid >> 5;
        const int y = xid & 31;
        for (int c0 = 0; c0 < CIN; c0 += 64) {
            int ci_l = t >> 2, xq = (t & 3) * 8;
            const float* src = x + (((size_t)(b * CIN + c0 + ci_l)) * HH + y) * WW + xq;
            float4 v0 = *(const float4*)src;
            float4 v1 = *(const float4*)(src + 4);
            __syncthreads();
            tileT[xq+0][ci_l] = __float2bfloat16(v0.x);
            tileT[xq+1][ci_l] = __float2bfloat16(v0.y);
            tileT[xq+2][ci_l] = __float2bfloat16(v0.z);
            tileT[xq+3][ci_l] = __float2bfloat16(v0.w);
            tileT[xq+4][ci_l] = __float2bfloat16(v1.x);
            tileT[xq+5][ci_l] = __float2bfloat16(v1.y);
            tileT[xq+6][ci_l] = __float2bfloat16(v1.z);
            tileT[xq+7][ci_l] = __float2bfloat16(v1.w);
            __syncthreads();
            int x_l = t >> 3, cg = (t & 7) * 8;
            bf16x8 o = *(const bf16x8*)&tileT[x_l][cg];
            *(bf16x8*)&xh[(((size_t)b * 34 + y + 1) * 34 + (x_l + 1)) * CIN + c0 + cg] = o;
        }
    } else if (id < 2800) {
        const int b = id - 2784;
        for (int c = t; c < 132 * 64; c += 256) {
            int cell = c >> 6, part = c & 63;
            int yy, xx;
            if (cell < 34)      { yy = 0;  xx = cell; }
            else if (cell < 68) { yy = 33; xx = cell - 34; }
            else if (cell < 100){ yy = cell - 68 + 1;  xx = 0; }
            else                { yy = cell - 100 + 1; xx = 33; }
            bf16x8 z = {0,0,0,0,0,0,0,0};
            *(bf16x8*)&xh[(((size_t)b * 34 + yy) * 34 + xx) * CIN + part * 8] = z;
        }
    } else if (id < 2805) {
        int idx = (id - 2800) * 2048 + t * 8;
        if (idx < 8208) {
            float4 z = {0.f, 0.f, 0.f, 0.f};
            *(float4*)(zero1 + idx) = z;
            *(float4*)(zero1 + idx + 4) = z;
        }
    } else {
        int idx = (id - 2805) * 2048 + t * 8;
        float4 z = {0.f, 0.f, 0.f, 0.f};
        *(float4*)(zero2 + idx) = z;
        *(float4*)(zero2 + idx + 4) = z;
    }
}

// ---------------------------------------------------------------------------
// K2: merged Gram kernel. z<9: Gu += uT[:,z*512:+512] NT-GEMM slice.
//     z>=9: Gv += vhb[:,(z-9)*256:+256] slice.
// 64x64 tile, 4 waves (2x2 of 32x32), BK=32, 4-buffer pipeline, atomic epi.
// ---------------------------------------------------------------------------
__global__ __launch_bounds__(256) void k_gram2(
        const __hip_bfloat16* __restrict__ uT,    // [RR][MM]
        const __hip_bfloat16* __restrict__ vhb,   // [RR][COUT]
        float* __restrict__ Gu, float* __restrict__ Gv) {
    const int r0 = blockIdx.x * 64, r1 = blockIdx.y * 64;
    const int z  = blockIdx.z;
    const bool isGu = (z < 9);
    const __hip_bfloat16* src = isGu ? uT : vhb;
    const int ldb   = (isGu ? MM : COUT) * 2;          // row stride bytes
    const int koff  = isGu ? z * 1024 : (z - 9) * 512; // k offset bytes
    const int NT    = isGu ? 16 : 8;
    float* G = isGu ? Gu : Gv;

    __shared__ __align__(16) char gLDS[4 * 8192];      // 32 KB
    const int t = threadIdx.x;
    const int w = t >> 6, l = t & 63;
    const int row = t >> 2, ls = t & 3;
    const int sg = ls ^ ((row >> 1) & 3);

    const char* sa = (const char*)src + (size_t)(r0 + row) * ldb + koff + sg * 16;
    const char* sb = (const char*)src + (size_t)(r1 + row) * ldb + koff + sg * 16;

    f32x4 acc[2][2];
    #pragma unroll
    for (int i = 0; i < 2; ++i)
        #pragma unroll
        for (int j = 0; j < 2; ++j) acc[i][j] = (f32x4){0.f, 0.f, 0.f, 0.f};

#define GSTAGE(bn, kt) { char* Gb_ = gLDS + (bn) * 8192;                     \
    gload_lds16(sa + (kt) * 64, Gb_ + t * 16);                               \
    gload_lds16(sb + (kt) * 64, Gb_ + 4096 + t * 16); }

#define GCOMP(bn) { const char* Ab_ = gLDS + (bn) * 8192;                    \
    const char* Bb_ = Ab_ + 4096;                                            \
    bf16x8 fa[2], fb[2];                                                     \
    const int sl = (l >> 4) << 4;                                            \
    const int ar = (w >> 1) * 32 + (l & 15);                                 \
    const int br = (w & 1) * 32 + (l & 15);                                  \
    _Pragma("unroll") for (int i = 0; i < 2; ++i) {                          \
        int r = ar + i * 16;                                                 \
        fa[i] = *(const bf16x8*)(Ab_ + r * 64 + (sl ^ (((r >> 1) & 3) << 4))); \
        int q = br + i * 16;                                                 \
        fb[i] = *(const bf16x8*)(Bb_ + q * 64 + (sl ^ (((q >> 1) & 3) << 4))); } \
    __builtin_amdgcn_s_setprio(1);                                           \
    _Pragma("unroll") for (int i = 0; i < 2; ++i)                            \
        _Pragma("unroll") for (int j = 0; j < 2; ++j)                        \
            acc[i][j] = __builtin_amdgcn_mfma_f32_16x16x32_bf16(fa[i], fb[j], acc[i][j], 0, 0, 0); \
    __builtin_amdgcn_s_setprio(0); }

    GSTAGE(0, 0); GSTAGE(1, 1); GSTAGE(2, 2);
    for (int kt = 0; kt < NT - 3; ++kt) {
        GSTAGE((kt + 3) & 3, kt + 3);
        PIPE_WAIT(6);
        GCOMP(kt & 3);
        PIPE_END();
    }
    PIPE_WAIT(4); GCOMP((NT - 3) & 3); PIPE_END();
    PIPE_WAIT(2); GCOMP((NT - 2) & 3); PIPE_END();
    PIPE_WAIT(0); GCOMP((NT - 1) & 3);

    #pragma unroll
    for (int i = 0; i < 2; ++i) {
        const int rA = r0 + (w >> 1) * 32 + i * 16 + (l >> 4) * 4;
        #pragma unroll
        for (int j = 0; j < 2; ++j) {
            const int rB = r1 + (w & 1) * 32 + j * 16 + (l & 15);
            #pragma unroll
            for (int rg = 0; rg < 4; ++rg)
                atomicAdd(&G[(size_t)(rA + rg) * RR + rB], acc[i][j][rg]);
        }
    }
}

// ---------------------------------------------------------------------------
// K3: normsq[b] += slice-sum of ev_r ev_r' Gu[r,r'] Gv[r,r']
// ---------------------------------------------------------------------------
__global__ __launch_bounds__(256) void k_norm(const float* __restrict__ Gu,
                                              const float* __restrict__ Gv,
                                              const float* __restrict__ dd,
                                              const int* __restrict__ dirs,
                                              float* __restrict__ normsq) {
    const int b = blockIdx.x, sl = blockIdx.y;
    __shared__ float evs[RR];
    __shared__ float red[256];
    const int t = threadIdx.x;
    const float* ev = dd + (size_t)dirs[b] * RR;
    for (int i = t; i < RR; i += 256) evs[i] = ev[i];
    __syncthreads();
    float acc = 0.f;
    const int base = sl * (RR * RR / 8);
    for (int p = base + t; p < base + RR * RR / 8; p += 256) {
        int r = p >> 9, r2 = p & 511;
        acc += Gu[p] * Gv[p] * evs[r] * evs[r2];
    }
    red[t] = acc;
    __syncthreads();
    for (int o = 128; o > 0; o >>= 1) {
        if (t < o) red[t] += red[t + o];
        __syncthreads();
    }
    if (t == 0) atomicAdd(&normsq[b], red[0]);
}

// ---------------------------------------------------------------------------
// K4: MFMA delta-GEMM + weight build + demod partials.
// Natural 3D grid. 3-buffer ring (48 KB), vmcnt(8), setprio.
// Epilogue: LDS-bounce -> coalesced wgtb/s reads, dense 16B/lane Wf stores.
// ---------------------------------------------------------------------------
__global__ __launch_bounds__(256) void k_build_mfma(
        const __hip_bfloat16* __restrict__ ubf,   // [MM][RR]
        const __hip_bfloat16* __restrict__ vt,    // [B][COUT][RR]
        const __hip_bfloat16* __restrict__ wgtb,  // [COUT][9][512] bf16
        const float* __restrict__ s,              // [B][CIN]
        const float* __restrict__ normsq,
        const float* __restrict__ shifts,
        __hip_bfloat16* __restrict__ Wf,          // [B][MT][COUT][32] swizzled
        float* __restrict__ demodsq) {
    const int m0  = blockIdx.x * 128;
    const int co0 = blockIdx.y * 128;
    const int b   = blockIdx.z;
    __shared__ __align__(16) char bLDS[3 * 16384];   // 48 KB (ring; reused by epilogue)
    const int t = threadIdx.x;
    const int w = t >> 6, l = t & 63;
    const int row = t >> 2, ls = t & 3;
    const int sg  = ls ^ ((row >> 1) & 3);

    const char* ua  = (const char*)(ubf + (size_t)(m0 + row) * RR) + sg * 16;
    const char* ua2 = ua + (size_t)64 * RR * 2;
    const char* va  = (const char*)(vt + ((size_t)b * COUT + co0 + row) * RR) + sg * 16;
    const char* va2 = va + (size_t)64 * RR * 2;
    const int dst0 = t * 16;

    f32x4 acc[4][4];
    #pragma unroll
    for (int i = 0; i < 4; ++i)
        #pragma unroll
        for (int j = 0; j < 4; ++j) acc[i][j] = (f32x4){0.f, 0.f, 0.f, 0.f};

#define BSTAGE(Ab_, kt) { const int rb = (kt) * 64;                          \
    gload_lds16(ua  + rb, (Ab_) + dst0);                                     \
    gload_lds16(ua2 + rb, (Ab_) + dst0 + 4096);                              \
    gload_lds16(va  + rb, (Ab_) + 8192 + dst0);                              \
    gload_lds16(va2 + rb, (Ab_) + 8192 + dst0 + 4096); }

#define BCOMPUTE(Ab_) { const char* Bb_ = (Ab_) + 8192;                      \
    bf16x8 fa[4], fb[4];                                                     \
    const int sl = (l >> 4) << 4;                                            \
    const int ar = (w >> 1) * 64 + (l & 15);                                 \
    const int br = (w & 1) * 64 + (l & 15);                                  \
    _Pragma("unroll") for (int i = 0; i < 4; ++i) {                          \
        int r = ar + i * 16;                                                 \
        fa[i] = *(const bf16x8*)((Ab_) + r * 64 + (sl ^ (((r >> 1) & 3) << 4))); \
        int q = br + i * 16;                                                 \
        fb[i] = *(const bf16x8*)(Bb_ + q * 64 + (sl ^ (((q >> 1) & 3) << 4))); } \
    __builtin_amdgcn_s_setprio(1);                                           \
    _Pragma("unroll") for (int i = 0; i < 4; ++i)                            \
        _Pragma("unroll") for (int j = 0; j < 4; ++j)                        \
            acc[i][j] = __builtin_amdgcn_mfma_f32_16x16x32_bf16(fa[i], fb[j], acc[i][j], 0, 0, 0); \
    __builtin_amdgcn_s_setprio(0); }

    char* cbuf = bLDS;
    char* nbuf = bLDS + 16384;
    char* sbuf = bLDS + 32768;
    BSTAGE(cbuf, 0); BSTAGE(nbuf, 1);
    for (int kt = 0; kt < 14; ++kt) {
        BSTAGE(sbuf, kt + 2);
        PIPE_WAIT(8);
        BCOMPUTE(cbuf);
        PIPE_END();
        char* tmp = cbuf; cbuf = nbuf; nbuf = sbuf; sbuf = tmp;
    }
    PIPE_WAIT(4); BCOMPUTE(cbuf); PIPE_END();   // kt=14
    PIPE_WAIT(0); BCOMPUTE(nbuf);               // kt=15

    // ---- epilogue: LDS-bounce (pipeline LDS now free)
    __syncthreads();
    {
        __hip_bfloat16* D = (__hip_bfloat16*)bLDS;    // [128 co][136 m-slots]
        float* red = (float*)(bLDS + 34816);          // 128 floats
        const int co_l0 = (w & 1) * 64 + (l & 15);
        const int m_l0  = (w >> 1) * 64 + (l >> 4) * 4;
        #pragma unroll
        for (int i = 0; i < 4; ++i) {
            #pragma unroll
            for (int j = 0; j < 4; ++j) {
                __hip_bfloat16 d4[4] = {
                    __float2bfloat16(acc[i][j][0]), __float2bfloat16(acc[i][j][1]),
                    __float2bfloat16(acc[i][j][2]), __float2bfloat16(acc[i][j][3])};
                *(ushort4*)&D[(co_l0 + j * 16) * 136 + m_l0 + i * 16] = *(const ushort4*)d4;
            }
        }
        if (t < 128) red[t] = 0.f;
        __syncthreads();
        const float cf = shifts[b] / fmaxf(sqrtf(normsq[b]), 1e-12f);
        const int kkc = m0 >> 9;
        const int mt0 = m0 >> 5;
        const int ci0 = m0 & 511;
        #pragma unroll
        for (int p = 0; p < 8; ++p) {
            const int idx  = p * 256 + t;
            const int oct  = idx & 3;
            const int mtl  = (idx >> 2) & 3;
            const int co_l = idx >> 4;
            const int co   = co0 + co_l;
            const int swz  = ((co >> 1) & 3) << 3;
            const int m_l  = mtl * 32 + ((oct * 8) ^ swz);
            bf16x8 dv = *(const bf16x8*)&D[co_l * 136 + m_l];
            const int ci = ci0 + m_l;
            bf16x8 wv = *(const bf16x8*)&wgtb[((size_t)co * KK + kkc) * 512 + ci];
            float4 s0 = *(const float4*)&s[b * CIN + ci];
            float4 s1 = *(const float4*)&s[b * CIN + ci + 4];
            float sv[8] = {s0.x, s0.y, s0.z, s0.w, s1.x, s1.y, s1.z, s1.w};
            __hip_bfloat16 vb[8];
            float psum = 0.f;
            #pragma unroll
            for (int e = 0; e < 8; ++e) {
                short sd = dv[e], sw = wv[e];
                float dd = __bfloat162float(*(__hip_bfloat16*)&sd);
                float ww = __bfloat162float(*(__hip_bfloat16*)&sw);
                float v = SCALE_F * (ww + cf * dd) * sv[e];
                vb[e] = __float2bfloat16(v);
                psum += v * v;
            }
            *(bf16x8*)&Wf[(((size_t)b * MT + mt0 + mtl) * COUT + co) * 32 + oct * 8]
                = *(const bf16x8*)vb;
            atomicAdd(&red[co_l], psum);
        }
        __syncthreads();
        if (t < 128) atomicAdd(&demodsq[b * COUT + co0 + t], red[t]);
    }
}

// ---------------------------------------------------------------------------
// K5: grouped conv as MFMA implicit GEMM. 4-buffer pipeline + XCD swizzle
// + incremental B-addressing + setprio.
// ---------------------------------------------------------------------------
__global__ __launch_bounds__(256) void k_conv_mfma(
        const __hip_bfloat16* __restrict__ Wf,     // [b][mt][co][32] swizzled
        const __hip_bfloat16* __restrict__ xh,     // [b][34][34][512]
        const float* __restrict__ demodsq,
        float* __restrict__ out) {
    const int id  = blockIdx.x;
    const int swb = (id & 7) * 64 + (id >> 3);
    const int p0  = (swb & 7) * 128;
    const int co0 = ((swb >> 3) & 3) * 128;
    const int b   = swb >> 5;
    __shared__ __align__(16) char cLDS[4 * 16384];   // 64 KB
    const int t = threadIdx.x;
    const int w = t >> 6, l = t & 63;

    const char* wsrc0 = (const char*)(Wf + (((size_t)b * MT) * COUT + co0) * 32);
    const int lq = l >> 2;
    const int ls = l & 3;
    const int off0 = t * 16;

    const __hip_bfloat16* bsrc0;
    const __hip_bfloat16* bsrc1;

    f32x4 acc[4][4];
    #pragma unroll
    for (int i = 0; i < 4; ++i)
        #pragma unroll
        for (int j = 0; j < 4; ++j) acc[i][j] = (f32x4){0.f, 0.f, 0.f, 0.f};

#define CADDR(mt) {                                                          \
    const int kk_ = (mt) >> 4;                                               \
    const int dy_ = kk_ / 3 - 1, dx_ = kk_ % 3 - 1;                          \
    { int p_l_ = w * 16 + lq; int P_ = p0 + p_l_;                            \
      int yy_ = (P_ >> 5) + dy_ + 1; int xx_ = (P_ & 31) + dx_ + 1;          \
      int sg_ = ls ^ ((p_l_ >> 1) & 3);                                      \
      bsrc0 = xh + (((size_t)b * 34 + yy_) * 34 + xx_) * CIN + sg_ * 8; }    \
    { int p_l_ = 64 + w * 16 + lq; int P_ = p0 + p_l_;                       \
      int yy_ = (P_ >> 5) + dy_ + 1; int xx_ = (P_ & 31) + dx_ + 1;          \
      int sg_ = ls ^ ((p_l_ >> 1) & 3);                                      \
      bsrc1 = xh + (((size_t)b * 34 + yy_) * 34 + xx_) * CIN + sg_ * 8; } }

#define CSTAGE(Ab_, mt) {                                                    \
    if (((mt) & 15) == 0) { CADDR(mt); } else { bsrc0 += 32; bsrc1 += 32; }  \
    const char* wa_ = wsrc0 + (size_t)(mt) * (COUT * 32 * 2);                \
    gload_lds16(wa_ + off0,        (Ab_) + off0);                            \
    gload_lds16(wa_ + off0 + 4096, (Ab_) + off0 + 4096);                     \
    gload_lds16(bsrc0, (Ab_) + 8192 + w * 1024 + l * 16);                    \
    gload_lds16(bsrc1, (Ab_) + 8192 + 4096 + w * 1024 + l * 16); }

#define CCOMPUTE(Ab_) { const char* Bb_ = (Ab_) + 8192;                      \
    bf16x8 fa[4], fb[4];                                                     \
    const int sl = (l >> 4) << 4;                                            \
    const int ar = (w >> 1) * 64 + (l & 15);                                 \
    const int br = (w & 1) * 64 + (l & 15);                                  \
    _Pragma("unroll") for (int i = 0; i < 4; ++i) {                          \
        int r = ar + i * 16;                                                 \
        fa[i] = *(const bf16x8*)((Ab_) + r * 64 + (sl ^ (((r >> 1) & 3) << 4))); \
        int q = br + i * 16;                                                 \
        fb[i] = *(const bf16x8*)(Bb_ + q * 64 + (sl ^ (((q >> 1) & 3) << 4))); } \
    __builtin_amdgcn_s_setprio(1);                                           \
    _Pragma("unroll") for (int i = 0; i < 4; ++i)                            \
        _Pragma("unroll") for (int j = 0; j < 4; ++j)                        \
            acc[i][j] = __builtin_amdgcn_mfma_f32_16x16x32_bf16(fa[i], fb[j], acc[i][j], 0, 0, 0); \
    __builtin_amdgcn_s_setprio(0); }

    CSTAGE(cLDS, 0); CSTAGE(cLDS + 16384, 1); CSTAGE(cLDS + 32768, 2);
    for (int mt = 0; mt < MT - 3; ++mt) {
        CSTAGE(cLDS + ((mt + 3) & 3) * 16384, mt + 3);
        PIPE_WAIT(12);
        CCOMPUTE(cLDS + (mt & 3) * 16384);
        PIPE_END();
    }
    PIPE_WAIT(8); CCOMPUTE(cLDS + ((MT - 3) & 3) * 16384); PIPE_END();
    PIPE_WAIT(4); CCOMPUTE(cLDS + ((MT - 2) & 3) * 16384); PIPE_END();
    PIPE_WAIT(0); CCOMPUTE(cLDS + ((MT - 1) & 3) * 16384);

    const float* dmrow = demodsq + b * COUT;
    #pragma unroll
    for (int i = 0; i < 4; ++i) {
        int co = co0 + (w >> 1) * 64 + i * 16 + (l >> 4) * 4;
        #pragma unroll
        for (int r = 0; r < 4; ++r) {
            float dm = rsqrtf(dmrow[co + r] + 1e-8f);
            #pragma unroll
            for (int j = 0; j < 4; ++j) {
                int p = p0 + (w & 1) * 64 + j * 16 + (l & 15);
                out[((size_t)b * COUT + co + r) * HW + p] = acc[i][j][r] * dm;
            }
        }
    }
}

// ---------------------------------------------------------------------------
extern "C" void kernel_launch(void* const* d_in, const int* in_sizes, int n_in,
                              void* d_out, int out_size, void* d_ws, size_t ws_size,
                              hipStream_t stream) {
    const float* x         = (const float*)d_in[0];
    const float* style     = (const float*)d_in[1];
    const float* mw        = (const float*)d_in[2];
    const float* mb        = (const float*)d_in[3];
    const float* weight    = (const float*)d_in[4];
    const float* u         = (const float*)d_in[5];
    const float* vh        = (const float*)d_in[6];
    const float* dir_delta = (const float*)d_in[7];
    const float* shifts    = (const float*)d_in[8];
    const int*   dirs      = (const int*)d_in[9];
    float* out = (float*)d_out;

    // ---- ws layout (high-water 94,568,448 B — round-4-proven offsets kept)
    char* base = (char*)d_ws;
    float* s       = (float*)(base);                    // 32 KB
    float* demodsq = (float*)(base + 32768);            // 32 KB
    float* normsq  = (float*)(base + 65536);            // 64 B (zero1 spans both)
    char* X = base + 131072;
    __hip_bfloat16* xh = (__hip_bfloat16*)(X);                 // 18.94 MB
    __hip_bfloat16* Wf = (__hip_bfloat16*)(X + 18939904);      // 75.5 MB

    // ---- pre-conv scratch lives in d_out (25.2 MB of 33.55 MB; all dead
    // before k_conv_mfma, which overwrites every byte of d_out each call)
    char* O = (char*)d_out;
    __hip_bfloat16* ubf  = (__hip_bfloat16*)(O);               // 4.72 MB
    __hip_bfloat16* ubfT = (__hip_bfloat16*)(O + 4718592);     // 4.72 MB
    __hip_bfloat16* vt   = (__hip_bfloat16*)(O + 9437184);     // 8.39 MB
    __hip_bfloat16* wgtb = (__hip_bfloat16*)(O + 17825792);    // 4.72 MB
    __hip_bfloat16* vhb  = (__hip_bfloat16*)(O + 22544384);    // 0.52 MB
    float*          Gu   = (float*)(O + 23068672);             // 1 MB
    float*          Gv   = (float*)(O + 24117248);             // 1 MB

    k_prep      <<<dim3(3061),      256, 0, stream>>>(style, mw, mb, s,
                                                      u, ubf, ubfT, vh, vhb,
                                                      dir_delta, dirs, vt,
                                                      weight, wgtb, x, xh,
                                                      demodsq, Gu);
    k_gram2     <<<dim3(8, 8, 11),  256, 0, stream>>>(ubfT, vhb, Gu, Gv);
    k_norm      <<<dim3(BB, 8),     256, 0, stream>>>(Gu, Gv, dir_delta, dirs, normsq);
    k_build_mfma<<<dim3(36, 4, BB), 256, 0, stream>>>(ubf, vt, wgtb, s, normsq, shifts, Wf, demodsq);
    k_conv_mfma <<<dim3(512),       256, 0, stream>>>(Wf, xh, demodsq, out);
}